// Round 1
// baseline (1260.419 us; speedup 1.0000x reference)
//
#include <hip/hip_runtime.h>
#include <math.h>

#define NN 2048
#define BB 8
#define HD 64

static __device__ __forceinline__ float wsum64(float v) {
#pragma unroll
    for (int off = 32; off >= 1; off >>= 1) v += __shfl_xor(v, off);
    return v;
}
static __device__ __forceinline__ float wmax64(float v) {
#pragma unroll
    for (int off = 32; off >= 1; off >>= 1) v = fmaxf(v, __shfl_xor(v, off));
    return v;
}

// ---------------- Wc = ffw2 @ ffw1  [64,64], bc = ffw2@ffb1 + ffb2 ----------------
__global__ void k_wc(const float* __restrict__ ffw1, const float* __restrict__ ffb1,
                     const float* __restrict__ ffw2, const float* __restrict__ ffb2,
                     float* __restrict__ Wc, float* __restrict__ bc) {
    int idx = blockIdx.x * 256 + threadIdx.x;
    if (idx < 4096) {
        int o = idx >> 6, c = idx & 63;
        float s = 0.f;
        for (int j = 0; j < 384; ++j) s += ffw2[o * 384 + j] * ffw1[j * 64 + c];
        Wc[idx] = s;
    }
    if (idx < 64) {
        float s = ffb2[idx];
        for (int j = 0; j < 384; ++j) s += ffw2[idx * 384 + j] * ffb1[j];
        bc[idx] = s;
    }
}

// ---------------- Qcat[n][b*64+c] = query[b][n][c]; Qsum[n][c] = sum_b ----------------
__global__ __launch_bounds__(256) void k_qprep(const float* __restrict__ q,
                                               float* __restrict__ Qcat,
                                               float* __restrict__ Qsum) {
    int idx = blockIdx.x * 256 + threadIdx.x;   // 0..131071
    int n = idx >> 6, c = idx & 63;
    float s = 0.f;
#pragma unroll
    for (int b = 0; b < BB; ++b) {
        float v = q[((size_t)b * NN + n) * 64 + c];
        s += v;
        Qcat[(size_t)n * 512 + b * 64 + c] = v;
    }
    Qsum[idx] = s;
}

// ---------------- Rsum[n][h] = Qsum[n] . Wc[h] + 8*bc[h] ----------------
__global__ __launch_bounds__(256) void k_rsum(const float* __restrict__ Qsum,
                                              const float* __restrict__ Wc,
                                              const float* __restrict__ bc,
                                              float* __restrict__ Rsum) {
    __shared__ float W[64][65];
    int tid = threadIdx.x;
    for (int i = tid; i < 4096; i += 256) W[i >> 6][i & 63] = Wc[i];
    __syncthreads();
    int idx = blockIdx.x * 256 + tid;
    int n = idx >> 6, h = idx & 63;
    const float* qs = &Qsum[n * 64];
    float s = 8.f * bc[h];
    for (int c = 0; c < 64; ++c) s += qs[c] * W[h][c];
    Rsum[idx] = s;
}

// ---------------- A[n][m] = Rsum[n] . Rsum[m] ----------------
__global__ __launch_bounds__(256) void k_amat(const float* __restrict__ R, float* __restrict__ A) {
    __shared__ float Rn[64][65];
    __shared__ float Rm[64][65];
    int n0 = blockIdx.y * 64, m0 = blockIdx.x * 64;
    int tid = threadIdx.x;
    for (int i = tid; i < 4096; i += 256) {
        int r = i >> 6, c = i & 63;
        Rn[r][c] = R[(n0 + r) * 64 + c];
        Rm[r][c] = R[(m0 + r) * 64 + c];
    }
    __syncthreads();
    int tx = tid & 15, ty = tid >> 4;
    float acc[4][4] = {};
    for (int k = 0; k < 64; ++k) {
        float a[4], b[4];
#pragma unroll
        for (int i = 0; i < 4; ++i) a[i] = Rn[ty * 4 + i][k];
#pragma unroll
        for (int j = 0; j < 4; ++j) b[j] = Rm[tx * 4 + j][k];
#pragma unroll
        for (int i = 0; i < 4; ++i)
#pragma unroll
            for (int j = 0; j < 4; ++j) acc[i][j] += a[i] * b[j];
    }
#pragma unroll
    for (int i = 0; i < 4; ++i)
#pragma unroll
        for (int j = 0; j < 4; ++j)
            A[(size_t)(n0 + ty * 4 + i) * NN + m0 + tx * 4 + j] = acc[i][j];
}

// ---------------- in-place row softmax + identity: Rm = softmax(A,-1) + I ----------------
__global__ __launch_bounds__(256) void k_softmax(float* __restrict__ A) {
    __shared__ float red[8];
    int n = blockIdx.x, tid = threadIdx.x;
    float4* row = (float4*)&A[(size_t)n * NN];
    float4 a = row[tid * 2], b = row[tid * 2 + 1];
    float v[8] = {a.x, a.y, a.z, a.w, b.x, b.y, b.z, b.w};
    float mx = v[0];
#pragma unroll
    for (int i = 1; i < 8; ++i) mx = fmaxf(mx, v[i]);
    mx = wmax64(mx);
    int wid = tid >> 6, lane = tid & 63;
    if (lane == 0) red[wid] = mx;
    __syncthreads();
    mx = fmaxf(fmaxf(red[0], red[1]), fmaxf(red[2], red[3]));
    float s = 0.f;
#pragma unroll
    for (int i = 0; i < 8; ++i) { v[i] = exp2f((v[i] - mx) * 1.44269504f); s += v[i]; }
    s = wsum64(s);
    if (lane == 0) red[4 + wid] = s;
    __syncthreads();
    s = red[4] + red[5] + red[6] + red[7];
    float inv = 1.f / s;
    int col = tid * 8;
#pragma unroll
    for (int i = 0; i < 8; ++i) v[i] = v[i] * inv + ((col + i) == n ? 1.f : 0.f);
    row[tid * 2]     = make_float4(v[0], v[1], v[2], v[3]);
    row[tid * 2 + 1] = make_float4(v[4], v[5], v[6], v[7]);
}

// ---------------- Y[m][j] = sum_n G[n][m] * X[n][j]  (G: 2048x2048, X: 2048x512) ----------------
__global__ __launch_bounds__(256) void gemm_gt(const float* __restrict__ G,
                                               const float* __restrict__ X,
                                               float* __restrict__ Y) {
    __shared__ __align__(16) float Gs[32][64];
    __shared__ __align__(16) float Xs[32][64];
    int m0 = blockIdx.y * 64;
    int j0 = blockIdx.x * 64;
    int tid = threadIdx.x;
    int tx = tid & 15, ty = tid >> 4;
    int lrow = tid >> 3;
    int lcol = (tid & 7) * 8;
    float acc[4][4] = {};
    for (int k0 = 0; k0 < NN; k0 += 32) {
        const float4* gp = (const float4*)&G[(size_t)(k0 + lrow) * NN + m0 + lcol];
        const float4* xp = (const float4*)&X[(size_t)(k0 + lrow) * 512 + j0 + lcol];
        float4 g0 = gp[0], g1 = gp[1];
        float4 x0 = xp[0], x1 = xp[1];
        __syncthreads();
        *(float4*)&Gs[lrow][lcol]     = g0;
        *(float4*)&Gs[lrow][lcol + 4] = g1;
        *(float4*)&Xs[lrow][lcol]     = x0;
        *(float4*)&Xs[lrow][lcol + 4] = x1;
        __syncthreads();
#pragma unroll
        for (int k = 0; k < 32; ++k) {
            float4 av = *(const float4*)&Gs[k][ty * 4];
            float4 bv = *(const float4*)&Xs[k][tx * 4];
            acc[0][0] += av.x * bv.x; acc[0][1] += av.x * bv.y; acc[0][2] += av.x * bv.z; acc[0][3] += av.x * bv.w;
            acc[1][0] += av.y * bv.x; acc[1][1] += av.y * bv.y; acc[1][2] += av.y * bv.z; acc[1][3] += av.y * bv.w;
            acc[2][0] += av.z * bv.x; acc[2][1] += av.z * bv.y; acc[2][2] += av.z * bv.z; acc[2][3] += av.z * bv.w;
            acc[3][0] += av.w * bv.x; acc[3][1] += av.w * bv.y; acc[3][2] += av.w * bv.z; acc[3][3] += av.w * bv.w;
        }
    }
#pragma unroll
    for (int i = 0; i < 4; ++i) {
        float4 o = make_float4(acc[i][0], acc[i][1], acc[i][2], acc[i][3]);
        *(float4*)&Y[(size_t)(m0 + ty * 4 + i) * 512 + j0 + tx * 4] = o;
    }
}

// ---------------- GCN output conv for one branch: out[b][n][o] ----------------
__global__ __launch_bounds__(512) void k_gcn_out(const float* __restrict__ Qcat,
                                                 const float* __restrict__ X1,
                                                 const float* __restrict__ X2,
                                                 const float* __restrict__ W,
                                                 const float* __restrict__ bias,
                                                 float* __restrict__ out) {
    __shared__ float Ws[64][193];
    __shared__ float rows[3][512];
    int n = blockIdx.x;
    int tid = threadIdx.x;
    for (int i = tid; i < 64 * 192; i += 512) Ws[i / 192][i % 192] = W[i];
    rows[0][tid] = Qcat[(size_t)n * 512 + tid];
    rows[1][tid] = X1[(size_t)n * 512 + tid];
    rows[2][tid] = X2[(size_t)n * 512 + tid];
    __syncthreads();
    int b = tid >> 6, o = tid & 63;
    const float* r0 = &rows[0][b * 64];
    const float* r1 = &rows[1][b * 64];
    const float* r2 = &rows[2][b * 64];
    float acc = bias[o];
    for (int c = 0; c < 64; ++c)
        acc += r0[c] * Ws[o][c] + r1[c] * Ws[o][64 + c] + r2[c] * Ws[o][128 + c];
    out[((size_t)b * NN + n) * 64 + o] = acc;
}

// ---------------- gated fusion ----------------
__global__ __launch_bounds__(256) void k_gate(const float* __restrict__ XF,
                                              const float* __restrict__ XD,
                                              float* __restrict__ XDF) {
    int i = blockIdx.x * 256 + threadIdx.x;
    float f = XF[i], d = XD[i];
    XDF[i] = tanhf(d) * (1.f / (1.f + expf(-f)));
}

// ---------------- q,k,v projections into [B][h][N][16] ----------------
__global__ __launch_bounds__(256) void k_qkv(const float* __restrict__ XDF,
                                             const float* __restrict__ wq,
                                             const float* __restrict__ wk,
                                             const float* __restrict__ wv,
                                             float* __restrict__ qb,
                                             float* __restrict__ kb,
                                             float* __restrict__ vb) {
    __shared__ float Ws[192][65];
    __shared__ float xs[16][64];
    int tid = threadIdx.x;
    for (int i = tid; i < 4096; i += 256) {
        int r = i >> 6, c = i & 63;
        Ws[r][c] = wq[i];
        Ws[64 + r][c] = wk[i];
        Ws[128 + r][c] = wv[i];
    }
    int row0 = blockIdx.x * 16;
    for (int i = tid; i < 1024; i += 256) xs[i >> 6][i & 63] = XDF[(size_t)row0 * 64 + i];
    __syncthreads();
#pragma unroll
    for (int it = 0; it < 12; ++it) {
        int oi = it * 256 + tid;
        int r = oi / 192, o = oi % 192;
        const float* x = xs[r];
        float acc = 0.f;
        for (int c = 0; c < 64; ++c) acc += x[c] * Ws[o][c];
        int row = row0 + r;
        int b = row >> 11, nn2 = row & 2047;
        int kind = o >> 6, hh = (o & 63) >> 4, d = o & 15;
        float* dst = kind == 0 ? qb : (kind == 1 ? kb : vb);
        dst[(((size_t)b * 4 + hh) * NN + nn2) * 16 + d] = acc;
    }
}

// ---------------- attention: per (b,h), softmax(q k^T / 4) @ v ----------------
__global__ __launch_bounds__(256) void k_attn(const float* __restrict__ qb,
                                              const float* __restrict__ kb,
                                              const float* __restrict__ vb,
                                              float* __restrict__ ctx) {
    __shared__ __align__(16) float ks[64][16];
    __shared__ __align__(16) float vs[64][16];
    int bh = blockIdx.y;
    int n = blockIdx.x * 256 + threadIdx.x;
    const float4* qr = (const float4*)&qb[((size_t)bh * NN + n) * 16];
    float4 q0 = qr[0], q1 = qr[1], q2 = qr[2], q3 = qr[3];
    const float* K = &kb[(size_t)bh * NN * 16];
    const float* V = &vb[(size_t)bh * NN * 16];
    float4 a0 = make_float4(0, 0, 0, 0), a1 = a0, a2 = a0, a3 = a0;
    float ssum = 0.f;
    const float SCL = 0.36067376022224085f;   // log2e/4
    const float SH  = -11.541560327111707f;   // -8*log2e
    for (int m0 = 0; m0 < NN; m0 += 64) {
        __syncthreads();
        ((float4*)ks)[threadIdx.x] = ((const float4*)&K[(size_t)m0 * 16])[threadIdx.x];
        ((float4*)vs)[threadIdx.x] = ((const float4*)&V[(size_t)m0 * 16])[threadIdx.x];
        __syncthreads();
#pragma unroll 4
        for (int mm = 0; mm < 64; ++mm) {
            const float4* kr = (const float4*)ks[mm];
            float4 k0 = kr[0], k1 = kr[1], k2 = kr[2], k3 = kr[3];
            float s = q0.x * k0.x + q0.y * k0.y + q0.z * k0.z + q0.w * k0.w
                    + q1.x * k1.x + q1.y * k1.y + q1.z * k1.z + q1.w * k1.w
                    + q2.x * k2.x + q2.y * k2.y + q2.z * k2.z + q2.w * k2.w
                    + q3.x * k3.x + q3.y * k3.y + q3.z * k3.z + q3.w * k3.w;
            float p = exp2f(s * SCL + SH);
            ssum += p;
            const float4* vr = (const float4*)vs[mm];
            float4 v0 = vr[0], v1 = vr[1], v2 = vr[2], v3 = vr[3];
            a0.x += p * v0.x; a0.y += p * v0.y; a0.z += p * v0.z; a0.w += p * v0.w;
            a1.x += p * v1.x; a1.y += p * v1.y; a1.z += p * v1.z; a1.w += p * v1.w;
            a2.x += p * v2.x; a2.y += p * v2.y; a2.z += p * v2.z; a2.w += p * v2.w;
            a3.x += p * v3.x; a3.y += p * v3.y; a3.z += p * v3.z; a3.w += p * v3.w;
        }
    }
    float inv = 1.f / ssum;
    int b = bh >> 2, hh = bh & 3;
    float4* dst = (float4*)&ctx[((size_t)b * NN + n) * 64 + hh * 16];
    dst[0] = make_float4(a0.x * inv, a0.y * inv, a0.z * inv, a0.w * inv);
    dst[1] = make_float4(a1.x * inv, a1.y * inv, a1.z * inv, a1.w * inv);
    dst[2] = make_float4(a2.x * inv, a2.y * inv, a2.z * inv, a2.w * inv);
    dst[3] = make_float4(a3.x * inv, a3.y * inv, a3.z * inv, a3.w * inv);
}

// ---------------- att_out = ctx@wo^T + bo; x = LN(att_out + XDF; g2,be2) ----------------
__global__ __launch_bounds__(256) void k_post1(const float* __restrict__ ctx,
                                               const float* __restrict__ XDF,
                                               const float* __restrict__ wo,
                                               const float* __restrict__ bo,
                                               const float* __restrict__ g2,
                                               const float* __restrict__ be2,
                                               float* __restrict__ xout) {
    __shared__ float W[64][65];
    __shared__ float xs[4][64];
    int tid = threadIdx.x;
    for (int i = tid; i < 4096; i += 256) W[i >> 6][i & 63] = wo[i];
    int row0 = blockIdx.x * 4;
    xs[tid >> 6][tid & 63] = ctx[(size_t)row0 * 64 + tid];
    __syncthreads();
    int r = tid >> 6, o = tid & 63;
    int row = row0 + r;
    const float* x = xs[r];
    float y = bo[o];
    for (int c = 0; c < 64; ++c) y += x[c] * W[o][c];
    y += XDF[(size_t)row * 64 + o];
    float mean = wsum64(y) * (1.f / 64.f);
    float d = y - mean;
    float var = wsum64(d * d) * (1.f / 64.f);
    float rstd = rsqrtf(var + 1e-5f);
    xout[(size_t)row * 64 + o] = d * rstd * g2[o] + be2[o];
}

// ---------------- t = relu(x @ f1w^T + f1b)  [rows][256] ----------------
__global__ __launch_bounds__(256) void k_ffn1(const float* __restrict__ x,
                                              const float* __restrict__ f1w,
                                              const float* __restrict__ f1b,
                                              float* __restrict__ t) {
    __shared__ float W[256 * 64];   // swizzled
    int tid = threadIdx.x;
    for (int i = tid; i < 16384; i += 256) {
        int j = i >> 6, c = i & 63;
        W[(j << 6) | (c ^ (j & 31))] = f1w[i];
    }
    __syncthreads();
    int j = tid;
    float bj = f1b[j];
    const float* Wj = &W[j << 6];
    int jx = j & 31;
    int row0 = blockIdx.x * 32;
    for (int rr = 0; rr < 32; ++rr) {
        int row = row0 + rr;
        const float* xr = &x[(size_t)row * 64];
        float acc = bj;
        for (int c = 0; c < 64; ++c) acc += xr[c] * Wj[c ^ jx];
        t[(size_t)row * 256 + j] = fmaxf(acc, 0.f);
    }
}

// ---------------- y = t @ f2w^T + f2b; out = LN(y + x; g3,be3) ----------------
__global__ __launch_bounds__(256) void k_ffn2(const float* __restrict__ t,
                                              const float* __restrict__ x,
                                              const float* __restrict__ f2w,
                                              const float* __restrict__ f2b,
                                              const float* __restrict__ g3,
                                              const float* __restrict__ be3,
                                              float* __restrict__ out) {
    __shared__ float W[64 * 256];   // swizzled
    int tid = threadIdx.x;
    for (int i = tid; i < 16384; i += 256) {
        int o = i >> 8, c = i & 255;
        W[(o << 8) | (c ^ (o & 31))] = f2w[i];
    }
    __syncthreads();
    int r = tid >> 6, o = tid & 63;
    int ox = o & 31;
    const float* Wo = &W[o << 8];
    int row0 = blockIdx.x * 16;
    for (int rr = 0; rr < 4; ++rr) {
        int row = row0 + rr * 4 + r;
        const float* tr = &t[(size_t)row * 256];
        float y = f2b[o];
        for (int j = 0; j < 256; ++j) y += tr[j] * Wo[j ^ ox];
        y += x[(size_t)row * 64 + o];
        float mean = wsum64(y) * (1.f / 64.f);
        float d = y - mean;
        float var = wsum64(d * d) * (1.f / 64.f);
        float rstd = rsqrtf(var + 1e-5f);
        out[(size_t)row * 64 + o] = d * rstd * g3[o] + be3[o];
    }
}

extern "C" void kernel_launch(void* const* d_in, const int* in_sizes, int n_in,
                              void* d_out, int out_size, void* d_ws, size_t ws_size,
                              hipStream_t stream) {
    const float* query = (const float*)d_in[0];
    const float* adj   = (const float*)d_in[1];
    const float* WF    = (const float*)d_in[2];
    const float* bF    = (const float*)d_in[3];
    const float* WD    = (const float*)d_in[4];
    const float* bD    = (const float*)d_in[5];
    const float* ffw1  = (const float*)d_in[6];
    const float* ffb1  = (const float*)d_in[7];
    const float* ffw2  = (const float*)d_in[8];
    const float* ffb2  = (const float*)d_in[9];
    const float* wq    = (const float*)d_in[10];
    const float* wk    = (const float*)d_in[11];
    const float* wv    = (const float*)d_in[12];
    const float* wo    = (const float*)d_in[13];
    const float* bo    = (const float*)d_in[14];
    const float* g2    = (const float*)d_in[15];
    const float* be2   = (const float*)d_in[16];
    const float* g3    = (const float*)d_in[17];
    const float* be3   = (const float*)d_in[18];
    const float* f1w   = (const float*)d_in[19];
    const float* f1b   = (const float*)d_in[20];
    const float* f2w   = (const float*)d_in[21];
    const float* f2b   = (const float*)d_in[22];
    float* out = (float*)d_out;

    float* w = (float*)d_ws;
    size_t off = 0;
    float* Qcat = w + off; off += 1048576;            // [N][512]
    float* Qsum = w + off; off += 131072;             // [N][64]
    float* Wc   = w + off; off += 4096;
    float* bc   = w + off; off += 256;
    float* Rsum = w + off; off += 131072;             // [N][64]
    float* Amat = w + off; off += 4194304;            // [N][N]  (later reused as FFN t-buffer)
    float* X1F  = w + off; off += 1048576;            // (later qb)
    float* X2F  = w + off; off += 1048576;            // (later kb)
    float* X1D  = w + off; off += 1048576;            // (later ctx)
    float* X2D  = w + off; off += 1048576;            // (later x post-LN1)
    float* XFo  = w + off; off += 1048576;
    float* XDo  = w + off; off += 1048576;
    float* XDF  = w + off; off += 1048576;
    float* qb = X1F, *kb = X2F, *vb = Qcat;
    float* ctxb = X1D;
    float* x1 = X2D;
    float* tbuf = Amat;

    k_wc<<<16, 256, 0, stream>>>(ffw1, ffb1, ffw2, ffb2, Wc, bc);
    k_qprep<<<512, 256, 0, stream>>>(query, Qcat, Qsum);
    k_rsum<<<512, 256, 0, stream>>>(Qsum, Wc, bc, Rsum);
    k_amat<<<dim3(32, 32), 256, 0, stream>>>(Rsum, Amat);
    k_softmax<<<2048, 256, 0, stream>>>(Amat);

    gemm_gt<<<dim3(8, 32), 256, 0, stream>>>(adj, Qcat, X1F);
    gemm_gt<<<dim3(8, 32), 256, 0, stream>>>(adj, X1F, X2F);
    gemm_gt<<<dim3(8, 32), 256, 0, stream>>>(Amat, Qcat, X1D);
    gemm_gt<<<dim3(8, 32), 256, 0, stream>>>(Amat, X1D, X2D);

    k_gcn_out<<<2048, 512, 0, stream>>>(Qcat, X1F, X2F, WF, bF, XFo);
    k_gcn_out<<<2048, 512, 0, stream>>>(Qcat, X1D, X2D, WD, bD, XDo);
    k_gate<<<4096, 256, 0, stream>>>(XFo, XDo, XDF);

    k_qkv<<<1024, 256, 0, stream>>>(XDF, wq, wk, wv, qb, kb, vb);
    k_attn<<<dim3(8, 32), 256, 0, stream>>>(qb, kb, vb, ctxb);
    k_post1<<<4096, 256, 0, stream>>>(ctxb, XDF, wo, bo, g2, be2, x1);
    k_ffn1<<<512, 256, 0, stream>>>(x1, f1w, f1b, tbuf);
    k_ffn2<<<1024, 256, 0, stream>>>(tbuf, x1, f2w, f2b, g3, be3, out);
}

// Round 2
// 834.595 us; speedup vs baseline: 1.5102x; 1.5102x over previous
//
#include <hip/hip_runtime.h>
#include <math.h>

#define NN 2048
#define BB 8
#define HD 64

static __device__ __forceinline__ float wsum64(float v) {
#pragma unroll
    for (int off = 32; off >= 1; off >>= 1) v += __shfl_xor(v, off);
    return v;
}
static __device__ __forceinline__ float wmax64(float v) {
#pragma unroll
    for (int off = 32; off >= 1; off >>= 1) v = fmaxf(v, __shfl_xor(v, off));
    return v;
}

// ---------------- Wc = ffw2 @ ffw1  [64,64], bc = ffw2@ffb1 + ffb2 ----------------
__global__ void k_wc(const float* __restrict__ ffw1, const float* __restrict__ ffb1,
                     const float* __restrict__ ffw2, const float* __restrict__ ffb2,
                     float* __restrict__ Wc, float* __restrict__ bc) {
    int idx = blockIdx.x * 256 + threadIdx.x;
    if (idx < 4096) {
        int o = idx >> 6, c = idx & 63;
        float s = 0.f;
        for (int j = 0; j < 384; ++j) s += ffw2[o * 384 + j] * ffw1[j * 64 + c];
        Wc[idx] = s;
    }
    if (idx < 64) {
        float s = ffb2[idx];
        for (int j = 0; j < 384; ++j) s += ffw2[idx * 384 + j] * ffb1[j];
        bc[idx] = s;
    }
}

// ---------------- Qcat[n][b*64+c] = query[b][n][c]; Qsum[n][c] = sum_b ----------------
__global__ __launch_bounds__(256) void k_qprep(const float* __restrict__ q,
                                               float* __restrict__ Qcat,
                                               float* __restrict__ Qsum) {
    int idx = blockIdx.x * 256 + threadIdx.x;   // 0..131071
    int n = idx >> 6, c = idx & 63;
    float s = 0.f;
#pragma unroll
    for (int b = 0; b < BB; ++b) {
        float v = q[((size_t)b * NN + n) * 64 + c];
        s += v;
        Qcat[(size_t)n * 512 + b * 64 + c] = v;
    }
    Qsum[idx] = s;
}

// ---------------- Rsum[n][h] = Qsum[n] . Wc[h] + 8*bc[h] ----------------
__global__ __launch_bounds__(256) void k_rsum(const float* __restrict__ Qsum,
                                              const float* __restrict__ Wc,
                                              const float* __restrict__ bc,
                                              float* __restrict__ Rsum) {
    __shared__ float W[64][65];
    int tid = threadIdx.x;
    for (int i = tid; i < 4096; i += 256) W[i >> 6][i & 63] = Wc[i];
    __syncthreads();
    int idx = blockIdx.x * 256 + tid;
    int n = idx >> 6, h = idx & 63;
    const float* qs = &Qsum[n * 64];
    float s = 8.f * bc[h];
    for (int c = 0; c < 64; ++c) s += qs[c] * W[h][c];
    Rsum[idx] = s;
}

// ---------------- A[n][m] = Rsum[n] . Rsum[m] ----------------
__global__ __launch_bounds__(256) void k_amat(const float* __restrict__ R, float* __restrict__ A) {
    __shared__ float Rn[64][65];
    __shared__ float Rm[64][65];
    int n0 = blockIdx.y * 64, m0 = blockIdx.x * 64;
    int tid = threadIdx.x;
    for (int i = tid; i < 4096; i += 256) {
        int r = i >> 6, c = i & 63;
        Rn[r][c] = R[(n0 + r) * 64 + c];
        Rm[r][c] = R[(m0 + r) * 64 + c];
    }
    __syncthreads();
    int tx = tid & 15, ty = tid >> 4;
    float acc[4][4] = {};
    for (int k = 0; k < 64; ++k) {
        float a[4], b[4];
#pragma unroll
        for (int i = 0; i < 4; ++i) a[i] = Rn[ty * 4 + i][k];
#pragma unroll
        for (int j = 0; j < 4; ++j) b[j] = Rm[tx * 4 + j][k];
#pragma unroll
        for (int i = 0; i < 4; ++i)
#pragma unroll
            for (int j = 0; j < 4; ++j) acc[i][j] += a[i] * b[j];
    }
#pragma unroll
    for (int i = 0; i < 4; ++i)
#pragma unroll
        for (int j = 0; j < 4; ++j)
            A[(size_t)(n0 + ty * 4 + i) * NN + m0 + tx * 4 + j] = acc[i][j];
}

// ---------------- in-place row softmax + identity: Rm = softmax(A,-1) + I ----------------
__global__ __launch_bounds__(256) void k_softmax(float* __restrict__ A) {
    __shared__ float red[8];
    int n = blockIdx.x, tid = threadIdx.x;
    float4* row = (float4*)&A[(size_t)n * NN];
    float4 a = row[tid * 2], b = row[tid * 2 + 1];
    float v[8] = {a.x, a.y, a.z, a.w, b.x, b.y, b.z, b.w};
    float mx = v[0];
#pragma unroll
    for (int i = 1; i < 8; ++i) mx = fmaxf(mx, v[i]);
    mx = wmax64(mx);
    int wid = tid >> 6, lane = tid & 63;
    if (lane == 0) red[wid] = mx;
    __syncthreads();
    mx = fmaxf(fmaxf(red[0], red[1]), fmaxf(red[2], red[3]));
    float s = 0.f;
#pragma unroll
    for (int i = 0; i < 8; ++i) { v[i] = exp2f((v[i] - mx) * 1.44269504f); s += v[i]; }
    s = wsum64(s);
    if (lane == 0) red[4 + wid] = s;
    __syncthreads();
    s = red[4] + red[5] + red[6] + red[7];
    float inv = 1.f / s;
    int col = tid * 8;
#pragma unroll
    for (int i = 0; i < 8; ++i) v[i] = v[i] * inv + ((col + i) == n ? 1.f : 0.f);
    row[tid * 2]     = make_float4(v[0], v[1], v[2], v[3]);
    row[tid * 2 + 1] = make_float4(v[4], v[5], v[6], v[7]);
}

// ---------------- propagation hop: Y[m][j] = sum_k G[k][m] * X[k][j] ----------------
// blockIdx.z selects (branch, ksplit-half). X can be a sum of two partial buffers.
__global__ __launch_bounds__(256) void gemm_hop(const float* __restrict__ G0,
                                                const float* __restrict__ G1,
                                                const float* __restrict__ xa0,
                                                const float* __restrict__ xb0,
                                                const float* __restrict__ xa1,
                                                const float* __restrict__ xb1,
                                                float* __restrict__ y0, float* __restrict__ y1,
                                                float* __restrict__ y2, float* __restrict__ y3,
                                                int ksplit) {
    __shared__ __align__(16) float Gs[32][64];
    __shared__ __align__(16) float Xs[32][64];
    int z = blockIdx.z;
    int branch, split;
    if (ksplit == 2) { branch = z >> 1; split = z & 1; }
    else             { branch = z;      split = 0;     }
    const float* G  = branch ? G1 : G0;
    const float* Xa = branch ? xa1 : xa0;
    const float* Xb = branch ? xb1 : xb0;
    float* Y = branch ? (split ? y3 : y2) : (split ? y1 : y0);
    int klen = NN / ksplit;
    int kb = split * klen, ke = kb + klen;

    int m0 = blockIdx.y * 64;
    int j0 = blockIdx.x * 64;
    int tid = threadIdx.x;
    int tx = tid & 15, ty = tid >> 4;
    int r = tid >> 4;               // 0..15
    int c4 = (tid & 15) * 4;        // 0..60
    float acc[4][4] = {};
    for (int k0 = kb; k0 < ke; k0 += 32) {
        const float* gp = &G[(size_t)(k0 + r) * NN + m0 + c4];
        float4 g0 = *(const float4*)gp;
        float4 g1 = *(const float4*)(gp + (size_t)16 * NN);
        const float* xp = &Xa[(size_t)(k0 + r) * 512 + j0 + c4];
        float4 x0 = *(const float4*)xp;
        float4 x1 = *(const float4*)(xp + 16 * 512);
        if (Xb) {
            const float* xq = &Xb[(size_t)(k0 + r) * 512 + j0 + c4];
            float4 e0 = *(const float4*)xq;
            float4 e1 = *(const float4*)(xq + 16 * 512);
            x0.x += e0.x; x0.y += e0.y; x0.z += e0.z; x0.w += e0.w;
            x1.x += e1.x; x1.y += e1.y; x1.z += e1.z; x1.w += e1.w;
        }
        __syncthreads();
        ((float4*)Gs)[tid]       = g0;   // linear contiguous: conflict-free
        ((float4*)Gs)[256 + tid] = g1;
        ((float4*)Xs)[tid]       = x0;
        ((float4*)Xs)[256 + tid] = x1;
        __syncthreads();
#pragma unroll
        for (int k = 0; k < 32; ++k) {
            float4 av = *(const float4*)&Gs[k][ty * 4];
            float4 bv = *(const float4*)&Xs[k][tx * 4];
            acc[0][0] += av.x * bv.x; acc[0][1] += av.x * bv.y; acc[0][2] += av.x * bv.z; acc[0][3] += av.x * bv.w;
            acc[1][0] += av.y * bv.x; acc[1][1] += av.y * bv.y; acc[1][2] += av.y * bv.z; acc[1][3] += av.y * bv.w;
            acc[2][0] += av.z * bv.x; acc[2][1] += av.z * bv.y; acc[2][2] += av.z * bv.z; acc[2][3] += av.z * bv.w;
            acc[3][0] += av.w * bv.x; acc[3][1] += av.w * bv.y; acc[3][2] += av.w * bv.z; acc[3][3] += av.w * bv.w;
        }
    }
#pragma unroll
    for (int i = 0; i < 4; ++i) {
        float4 o = make_float4(acc[i][0], acc[i][1], acc[i][2], acc[i][3]);
        *(float4*)&Y[(size_t)(m0 + ty * 4 + i) * 512 + j0 + tx * 4] = o;
    }
}

// ---------------- GCN output conv for one branch (x1 may be split pair) ----------------
__global__ __launch_bounds__(512) void k_gcn_out(const float* __restrict__ Qcat,
                                                 const float* __restrict__ x1a,
                                                 const float* __restrict__ x1b,
                                                 const float* __restrict__ x2,
                                                 const float* __restrict__ W,
                                                 const float* __restrict__ bias,
                                                 float* __restrict__ out) {
    __shared__ float Ws[64][193];
    __shared__ float rows[3][512];
    int n = blockIdx.x;
    int tid = threadIdx.x;
    for (int i = tid; i < 64 * 192; i += 512) Ws[i / 192][i % 192] = W[i];
    rows[0][tid] = Qcat[(size_t)n * 512 + tid];
    float v1 = x1a[(size_t)n * 512 + tid];
    if (x1b) v1 += x1b[(size_t)n * 512 + tid];
    rows[1][tid] = v1;
    rows[2][tid] = x2[(size_t)n * 512 + tid];
    __syncthreads();
    int b = tid >> 6, o = tid & 63;
    const float* r0 = &rows[0][b * 64];
    const float* r1 = &rows[1][b * 64];
    const float* r2 = &rows[2][b * 64];
    float acc = bias[o];
    for (int c = 0; c < 64; ++c)
        acc += r0[c] * Ws[o][c] + r1[c] * Ws[o][64 + c] + r2[c] * Ws[o][128 + c];
    out[((size_t)b * NN + n) * 64 + o] = acc;
}

// ---------------- gated fusion ----------------
__global__ __launch_bounds__(256) void k_gate(const float* __restrict__ XF,
                                              const float* __restrict__ XD,
                                              float* __restrict__ XDF) {
    int i = blockIdx.x * 256 + threadIdx.x;
    float f = XF[i], d = XD[i];
    XDF[i] = tanhf(d) * (1.f / (1.f + expf(-f)));
}

// ---------------- q,k,v projections into [B][h][N][16] ----------------
__global__ __launch_bounds__(256) void k_qkv(const float* __restrict__ XDF,
                                             const float* __restrict__ wq,
                                             const float* __restrict__ wk,
                                             const float* __restrict__ wv,
                                             float* __restrict__ qb,
                                             float* __restrict__ kb,
                                             float* __restrict__ vb) {
    __shared__ float Ws[192][65];
    __shared__ float xs[16][64];
    int tid = threadIdx.x;
    for (int i = tid; i < 4096; i += 256) {
        int r = i >> 6, c = i & 63;
        Ws[r][c] = wq[i];
        Ws[64 + r][c] = wk[i];
        Ws[128 + r][c] = wv[i];
    }
    int row0 = blockIdx.x * 16;
    for (int i = tid; i < 1024; i += 256) xs[i >> 6][i & 63] = XDF[(size_t)row0 * 64 + i];
    __syncthreads();
#pragma unroll
    for (int it = 0; it < 12; ++it) {
        int oi = it * 256 + tid;
        int r = oi / 192, o = oi % 192;
        const float* x = xs[r];
        float acc = 0.f;
        for (int c = 0; c < 64; ++c) acc += x[c] * Ws[o][c];
        int row = row0 + r;
        int b = row >> 11, nn2 = row & 2047;
        int kind = o >> 6, hh = (o & 63) >> 4, d = o & 15;
        float* dst = kind == 0 ? qb : (kind == 1 ? kb : vb);
        dst[(((size_t)b * 4 + hh) * NN + nn2) * 16 + d] = acc;
    }
}

// ---------------- attention with KV split-K: partial exp-sums per split ----------------
#define KS 4
__global__ __launch_bounds__(256) void k_attn_sk(const float* __restrict__ qb,
                                                 const float* __restrict__ kb,
                                                 const float* __restrict__ vb,
                                                 float* __restrict__ Pacc,
                                                 float* __restrict__ Pssum) {
    __shared__ __align__(16) float4 ks[256];   // 64 rows x 16 floats
    __shared__ __align__(16) float4 vs[256];
    int bh = blockIdx.y;
    int sp = blockIdx.z;
    int n = blockIdx.x * 256 + threadIdx.x;
    const float4* qr = (const float4*)&qb[((size_t)bh * NN + n) * 16];
    float4 q0 = qr[0], q1 = qr[1], q2 = qr[2], q3 = qr[3];
    const float4* K = (const float4*)&kb[((size_t)bh * NN + sp * (NN / KS)) * 16];
    const float4* V = (const float4*)&vb[((size_t)bh * NN + sp * (NN / KS)) * 16];
    float4 a0 = make_float4(0, 0, 0, 0), a1 = a0, a2 = a0, a3 = a0;
    float ssum = 0.f;
    const float SCL = 0.36067376022224085f;   // log2e/4
    const float SH  = -11.541560327111707f;   // -8*log2e
    for (int m0 = 0; m0 < NN / KS; m0 += 64) {
        __syncthreads();
        ks[threadIdx.x] = K[m0 * 4 + threadIdx.x];
        vs[threadIdx.x] = V[m0 * 4 + threadIdx.x];
        __syncthreads();
#pragma unroll 4
        for (int mm = 0; mm < 64; ++mm) {
            float4 k0 = ks[mm * 4], k1 = ks[mm * 4 + 1], k2 = ks[mm * 4 + 2], k3 = ks[mm * 4 + 3];
            float d0 = q0.x * k0.x + q0.y * k0.y + q0.z * k0.z + q0.w * k0.w;
            float d1 = q1.x * k1.x + q1.y * k1.y + q1.z * k1.z + q1.w * k1.w;
            float d2 = q2.x * k2.x + q2.y * k2.y + q2.z * k2.z + q2.w * k2.w;
            float d3 = q3.x * k3.x + q3.y * k3.y + q3.z * k3.z + q3.w * k3.w;
            float s = (d0 + d1) + (d2 + d3);
            float p = exp2f(fmaf(s, SCL, SH));
            ssum += p;
            float4 v0 = vs[mm * 4], v1 = vs[mm * 4 + 1], v2 = vs[mm * 4 + 2], v3 = vs[mm * 4 + 3];
            a0.x += p * v0.x; a0.y += p * v0.y; a0.z += p * v0.z; a0.w += p * v0.w;
            a1.x += p * v1.x; a1.y += p * v1.y; a1.z += p * v1.z; a1.w += p * v1.w;
            a2.x += p * v2.x; a2.y += p * v2.y; a2.z += p * v2.z; a2.w += p * v2.w;
            a3.x += p * v3.x; a3.y += p * v3.y; a3.z += p * v3.z; a3.w += p * v3.w;
        }
    }
    float4* dst = (float4*)&Pacc[(((size_t)bh * KS + sp) * NN + n) * 16];
    dst[0] = a0; dst[1] = a1; dst[2] = a2; dst[3] = a3;
    Pssum[((size_t)bh * KS + sp) * NN + n] = ssum;
}

// ---------------- combine attention splits -> ctx[b][n][64] ----------------
__global__ __launch_bounds__(256) void k_attn_red(const float* __restrict__ Pacc,
                                                  const float* __restrict__ Pssum,
                                                  float* __restrict__ ctx) {
    int bh = blockIdx.y;
    int i = blockIdx.x * 256 + threadIdx.x;   // 0..32767
    int n = i >> 4, d = i & 15;
    float a = 0.f, ss = 0.f;
#pragma unroll
    for (int s = 0; s < KS; ++s) {
        a  += Pacc[(((size_t)bh * KS + s) * NN + n) * 16 + d];
        ss += Pssum[((size_t)bh * KS + s) * NN + n];
    }
    int b = bh >> 2, h = bh & 3;
    ctx[((size_t)b * NN + n) * 64 + h * 16 + d] = a / ss;
}

// ---------------- att_out = ctx@wo^T + bo; x = LN(att_out + XDF; g2,be2) ----------------
__global__ __launch_bounds__(256) void k_post1(const float* __restrict__ ctx,
                                               const float* __restrict__ XDF,
                                               const float* __restrict__ wo,
                                               const float* __restrict__ bo,
                                               const float* __restrict__ g2,
                                               const float* __restrict__ be2,
                                               float* __restrict__ xout) {
    __shared__ float W[64][65];
    __shared__ float xs[4][64];
    int tid = threadIdx.x;
    for (int i = tid; i < 4096; i += 256) W[i >> 6][i & 63] = wo[i];
    int row0 = blockIdx.x * 4;
    xs[tid >> 6][tid & 63] = ctx[(size_t)row0 * 64 + tid];
    __syncthreads();
    int r = tid >> 6, o = tid & 63;
    int row = row0 + r;
    const float* x = xs[r];
    float y = bo[o];
    for (int c = 0; c < 64; ++c) y += x[c] * W[o][c];
    y += XDF[(size_t)row * 64 + o];
    float mean = wsum64(y) * (1.f / 64.f);
    float d = y - mean;
    float var = wsum64(d * d) * (1.f / 64.f);
    float rstd = rsqrtf(var + 1e-5f);
    xout[(size_t)row * 64 + o] = d * rstd * g2[o] + be2[o];
}

// ---------------- t = relu(x @ f1w^T + f1b)  [rows][256] ----------------
__global__ __launch_bounds__(256) void k_ffn1(const float* __restrict__ x,
                                              const float* __restrict__ f1w,
                                              const float* __restrict__ f1b,
                                              float* __restrict__ t) {
    __shared__ float W[256 * 64];   // swizzled
    int tid = threadIdx.x;
    for (int i = tid; i < 16384; i += 256) {
        int j = i >> 6, c = i & 63;
        W[(j << 6) | (c ^ (j & 31))] = f1w[i];
    }
    __syncthreads();
    int j = tid;
    float bj = f1b[j];
    const float* Wj = &W[j << 6];
    int jx = j & 31;
    int row0 = blockIdx.x * 32;
    for (int rr = 0; rr < 32; ++rr) {
        int row = row0 + rr;
        const float* xr = &x[(size_t)row * 64];
        float acc = bj;
        for (int c = 0; c < 64; ++c) acc += xr[c] * Wj[c ^ jx];
        t[(size_t)row * 256 + j] = fmaxf(acc, 0.f);
    }
}

// ---------------- y = t @ f2w^T + f2b; out = LN(y + x; g3,be3) ----------------
__global__ __launch_bounds__(256) void k_ffn2(const float* __restrict__ t,
                                              const float* __restrict__ x,
                                              const float* __restrict__ f2w,
                                              const float* __restrict__ f2b,
                                              const float* __restrict__ g3,
                                              const float* __restrict__ be3,
                                              float* __restrict__ out) {
    __shared__ float W[64 * 256];   // swizzled
    int tid = threadIdx.x;
    for (int i = tid; i < 16384; i += 256) {
        int o = i >> 8, c = i & 255;
        W[(o << 8) | (c ^ (o & 31))] = f2w[i];
    }
    __syncthreads();
    int r = tid >> 6, o = tid & 63;
    int ox = o & 31;
    const float* Wo = &W[o << 8];
    int row0 = blockIdx.x * 16;
    for (int rr = 0; rr < 4; ++rr) {
        int row = row0 + rr * 4 + r;
        const float* tr = &t[(size_t)row * 256];
        float y = f2b[o];
        for (int j = 0; j < 256; ++j) y += tr[j] * Wo[j ^ ox];
        y += x[(size_t)row * 64 + o];
        float mean = wsum64(y) * (1.f / 64.f);
        float d = y - mean;
        float var = wsum64(d * d) * (1.f / 64.f);
        float rstd = rsqrtf(var + 1e-5f);
        out[(size_t)row * 64 + o] = d * rstd * g3[o] + be3[o];
    }
}

extern "C" void kernel_launch(void* const* d_in, const int* in_sizes, int n_in,
                              void* d_out, int out_size, void* d_ws, size_t ws_size,
                              hipStream_t stream) {
    const float* query = (const float*)d_in[0];
    const float* adj   = (const float*)d_in[1];
    const float* WF    = (const float*)d_in[2];
    const float* bF    = (const float*)d_in[3];
    const float* WD    = (const float*)d_in[4];
    const float* bD    = (const float*)d_in[5];
    const float* ffw1  = (const float*)d_in[6];
    const float* ffb1  = (const float*)d_in[7];
    const float* ffw2  = (const float*)d_in[8];
    const float* ffb2  = (const float*)d_in[9];
    const float* wq    = (const float*)d_in[10];
    const float* wk    = (const float*)d_in[11];
    const float* wv    = (const float*)d_in[12];
    const float* wo    = (const float*)d_in[13];
    const float* bo    = (const float*)d_in[14];
    const float* g2    = (const float*)d_in[15];
    const float* be2   = (const float*)d_in[16];
    const float* g3    = (const float*)d_in[17];
    const float* be3   = (const float*)d_in[18];
    const float* f1w   = (const float*)d_in[19];
    const float* f1b   = (const float*)d_in[20];
    const float* f2w   = (const float*)d_in[21];
    const float* f2b   = (const float*)d_in[22];
    float* out = (float*)d_out;

    // big layout needs 14,946,560 floats (~59.8 MB); fall back to proven 51.4 MB layout.
    bool big = ws_size >= (size_t)14946560 * sizeof(float);

    float* w = (float*)d_ws;
    size_t off = 0;
    auto alloc = [&](size_t n) { float* p = w + off; off += n; return p; };
    float* Qcat = alloc(1048576);               // [N][512]; later vb
    float* Qsum = alloc(131072);
    float* Wc   = alloc(4096);
    float* bc   = alloc(256);
    float* Rsum = alloc(131072);
    float* Amat = alloc(4194304);               // Rm; later Pacc; later FFN t-buffer
    float* PF0  = alloc(1048576);               // hop1 F (partial 0); later qb
    float* PF1  = big ? alloc(1048576) : nullptr;
    float* PD0  = alloc(1048576);               // hop1 D (partial 0)
    float* PD1  = big ? alloc(1048576) : nullptr;
    float* X2F  = alloc(1048576);               // later kb
    float* X2D  = alloc(1048576);               // later x (post-LN1)
    float* XFo  = alloc(1048576);               // later Pssum
    float* XDo  = alloc(1048576);               // later ctx
    float* XDF  = alloc(1048576);

    float* qb = PF0, *kb = X2F, *vb = Qcat;
    float* Pacc = Amat, *Pssum = XFo;
    float* ctxb = XDo;
    float* x1 = X2D;
    float* tbuf = Amat;

    k_wc<<<16, 256, 0, stream>>>(ffw1, ffb1, ffw2, ffb2, Wc, bc);
    k_qprep<<<512, 256, 0, stream>>>(query, Qcat, Qsum);
    k_rsum<<<512, 256, 0, stream>>>(Qsum, Wc, bc, Rsum);
    k_amat<<<dim3(32, 32), 256, 0, stream>>>(Rsum, Amat);
    k_softmax<<<2048, 256, 0, stream>>>(Amat);

    if (big) {
        gemm_hop<<<dim3(8, 32, 4), 256, 0, stream>>>(adj, Amat, Qcat, nullptr, Qcat, nullptr,
                                                     PF0, PF1, PD0, PD1, 2);
        gemm_hop<<<dim3(8, 32, 2), 256, 0, stream>>>(adj, Amat, PF0, PF1, PD0, PD1,
                                                     X2F, nullptr, X2D, nullptr, 1);
    } else {
        gemm_hop<<<dim3(8, 32, 2), 256, 0, stream>>>(adj, Amat, Qcat, nullptr, Qcat, nullptr,
                                                     PF0, nullptr, PD0, nullptr, 1);
        gemm_hop<<<dim3(8, 32, 2), 256, 0, stream>>>(adj, Amat, PF0, nullptr, PD0, nullptr,
                                                     X2F, nullptr, X2D, nullptr, 1);
    }

    k_gcn_out<<<2048, 512, 0, stream>>>(Qcat, PF0, PF1, X2F, WF, bF, XFo);
    k_gcn_out<<<2048, 512, 0, stream>>>(Qcat, PD0, PD1, X2D, WD, bD, XDo);
    k_gate<<<4096, 256, 0, stream>>>(XFo, XDo, XDF);

    k_qkv<<<1024, 256, 0, stream>>>(XDF, wq, wk, wv, qb, kb, vb);
    k_attn_sk<<<dim3(8, 32, KS), 256, 0, stream>>>(qb, kb, vb, Pacc, Pssum);
    k_attn_red<<<dim3(128, 32), 256, 0, stream>>>(Pacc, Pssum, ctxb);
    k_post1<<<4096, 256, 0, stream>>>(ctxb, XDF, wo, bo, g2, be2, x1);
    k_ffn1<<<512, 256, 0, stream>>>(x1, f1w, f1b, tbuf);
    k_ffn2<<<1024, 256, 0, stream>>>(tbuf, x1, f2w, f2b, g3, be3, out);
}

// Round 3
// 652.881 us; speedup vs baseline: 1.9305x; 1.2783x over previous
//
#include <hip/hip_runtime.h>
#include <math.h>

#define NN 2048
#define BB 8
#define HD 64

typedef __attribute__((ext_vector_type(8))) short bf16x8;
typedef __attribute__((ext_vector_type(4))) float f32x4;
typedef __attribute__((ext_vector_type(4))) unsigned short ushortx4;
typedef unsigned short ushort_t;

static __device__ __forceinline__ float wsum64(float v) {
#pragma unroll
    for (int off = 32; off >= 1; off >>= 1) v += __shfl_xor(v, off);
    return v;
}
static __device__ __forceinline__ float wmax64(float v) {
#pragma unroll
    for (int off = 32; off >= 1; off >>= 1) v = fmaxf(v, __shfl_xor(v, off));
    return v;
}
static __device__ __forceinline__ unsigned short brne(float x) {
    unsigned u = __float_as_uint(x);
    return (unsigned short)((u + 0x7fffu + ((u >> 16) & 1u)) >> 16);
}

// ---------------- Wc = ffw2 @ ffw1  [64,64], bc = ffw2@ffb1 + ffb2 ----------------
__global__ void k_wc(const float* __restrict__ ffw1, const float* __restrict__ ffb1,
                     const float* __restrict__ ffw2, const float* __restrict__ ffb2,
                     float* __restrict__ Wc, float* __restrict__ bc) {
    int idx = blockIdx.x * 256 + threadIdx.x;
    if (idx < 4096) {
        int o = idx >> 6, c = idx & 63;
        float s = 0.f;
        for (int j = 0; j < 384; ++j) s += ffw2[o * 384 + j] * ffw1[j * 64 + c];
        Wc[idx] = s;
    }
    if (idx < 64) {
        float s = ffb2[idx];
        for (int j = 0; j < 384; ++j) s += ffw2[idx * 384 + j] * ffb1[j];
        bc[idx] = s;
    }
}

// ---------------- Qcat[n][b*64+c] = query[b][n][c]; Qsum[n][c] = sum_b ----------------
__global__ __launch_bounds__(256) void k_qprep(const float* __restrict__ q,
                                               float* __restrict__ Qcat,
                                               float* __restrict__ Qsum) {
    int idx = blockIdx.x * 256 + threadIdx.x;   // 0..131071
    int n = idx >> 6, c = idx & 63;
    float s = 0.f;
#pragma unroll
    for (int b = 0; b < BB; ++b) {
        float v = q[((size_t)b * NN + n) * 64 + c];
        s += v;
        Qcat[(size_t)n * 512 + b * 64 + c] = v;
    }
    Qsum[idx] = s;
}

// ---------------- Rsum[n][h] = Qsum[n] . Wc[h] + 8*bc[h] ----------------
__global__ __launch_bounds__(256) void k_rsum(const float* __restrict__ Qsum,
                                              const float* __restrict__ Wc,
                                              const float* __restrict__ bc,
                                              float* __restrict__ Rsum) {
    __shared__ float W[64][65];
    int tid = threadIdx.x;
    for (int i = tid; i < 4096; i += 256) W[i >> 6][i & 63] = Wc[i];
    __syncthreads();
    int idx = blockIdx.x * 256 + tid;
    int n = idx >> 6, h = idx & 63;
    const float* qs = &Qsum[n * 64];
    float s = 8.f * bc[h];
    for (int c = 0; c < 64; ++c) s += qs[c] * W[h][c];
    Rsum[idx] = s;
}

// ---------------- A[n][m] = Rsum[n] . Rsum[m] ----------------
__global__ __launch_bounds__(256) void k_amat(const float* __restrict__ R, float* __restrict__ A) {
    __shared__ float Rn[64][65];
    __shared__ float Rm[64][65];
    int n0 = blockIdx.y * 64, m0 = blockIdx.x * 64;
    int tid = threadIdx.x;
    for (int i = tid; i < 4096; i += 256) {
        int r = i >> 6, c = i & 63;
        Rn[r][c] = R[(n0 + r) * 64 + c];
        Rm[r][c] = R[(m0 + r) * 64 + c];
    }
    __syncthreads();
    int tx = tid & 15, ty = tid >> 4;
    float acc[4][4] = {};
    for (int k = 0; k < 64; ++k) {
        float a[4], b[4];
#pragma unroll
        for (int i = 0; i < 4; ++i) a[i] = Rn[ty * 4 + i][k];
#pragma unroll
        for (int j = 0; j < 4; ++j) b[j] = Rm[tx * 4 + j][k];
#pragma unroll
        for (int i = 0; i < 4; ++i)
#pragma unroll
            for (int j = 0; j < 4; ++j) acc[i][j] += a[i] * b[j];
    }
#pragma unroll
    for (int i = 0; i < 4; ++i)
#pragma unroll
        for (int j = 0; j < 4; ++j)
            A[(size_t)(n0 + ty * 4 + i) * NN + m0 + tx * 4 + j] = acc[i][j];
}

// ---------------- in-place row softmax + identity: Rm = softmax(A,-1) + I ----------------
__global__ __launch_bounds__(256) void k_softmax(float* __restrict__ A) {
    __shared__ float red[8];
    int n = blockIdx.x, tid = threadIdx.x;
    float4* row = (float4*)&A[(size_t)n * NN];
    float4 a = row[tid * 2], b = row[tid * 2 + 1];
    float v[8] = {a.x, a.y, a.z, a.w, b.x, b.y, b.z, b.w};
    float mx = v[0];
#pragma unroll
    for (int i = 1; i < 8; ++i) mx = fmaxf(mx, v[i]);
    mx = wmax64(mx);
    int wid = tid >> 6, lane = tid & 63;
    if (lane == 0) red[wid] = mx;
    __syncthreads();
    mx = fmaxf(fmaxf(red[0], red[1]), fmaxf(red[2], red[3]));
    float s = 0.f;
#pragma unroll
    for (int i = 0; i < 8; ++i) { v[i] = exp2f((v[i] - mx) * 1.44269504f); s += v[i]; }
    s = wsum64(s);
    if (lane == 0) red[4 + wid] = s;
    __syncthreads();
    s = red[4] + red[5] + red[6] + red[7];
    float inv = 1.f / s;
    int col = tid * 8;
#pragma unroll
    for (int i = 0; i < 8; ++i) v[i] = v[i] * inv + ((col + i) == n ? 1.f : 0.f);
    row[tid * 2]     = make_float4(v[0], v[1], v[2], v[3]);
    row[tid * 2 + 1] = make_float4(v[4], v[5], v[6], v[7]);
}

// ---------------- transpose + fp32->bf16: out[c][r] = bf16(in[r][c]) ----------------
__global__ __launch_bounds__(256) void k_t32to16(const float* __restrict__ in,
                                                 ushort_t* __restrict__ out,
                                                 int R, int C) {
    __shared__ float tile[64][65];
    int r0 = blockIdx.y * 64, c0 = blockIdx.x * 64;
    int t = threadIdx.x;
    int tr = t >> 6, tc = t & 63;
#pragma unroll
    for (int i = 0; i < 16; ++i) {
        int r = tr + i * 4;
        tile[r][tc] = in[(size_t)(r0 + r) * C + c0 + tc];
    }
    __syncthreads();
#pragma unroll
    for (int i = 0; i < 16; ++i) {
        int cc = tr + i * 4;
        out[(size_t)(c0 + cc) * R + r0 + tc] = brne(tile[tc][cc]);
    }
}

// ---------------- MFMA propagation hop ----------------
// Y[m][j] = sum_k G[k][m] * X[k][j], using Gt[m][k] bf16 and Xt[j][k] bf16.
// Optionally writes Tt[j][m] = bf16(Y[m][j]) for the next hop.
__global__ __launch_bounds__(256) void k_hop(const ushort_t* __restrict__ G0t,
                                             const ushort_t* __restrict__ G1t,
                                             const ushort_t* __restrict__ B0t,
                                             const ushort_t* __restrict__ B1t,
                                             float* __restrict__ Y0, float* __restrict__ Y1,
                                             ushort_t* __restrict__ T0, ushort_t* __restrict__ T1) {
    __shared__ __align__(16) ushort_t As[4096];   // [64 m][64 k] swizzled, 8KB
    __shared__ __align__(16) ushort_t Bs[4096];   // [64 j][64 k] swizzled
    int z = blockIdx.z;
    const ushort_t* Gt = z ? G1t : G0t;
    const ushort_t* Xt = z ? B1t : B0t;
    float* Y = z ? Y1 : Y0;
    ushort_t* T = z ? T1 : T0;
    int m0 = blockIdx.y * 64, j0 = blockIdx.x * 64;
    int t = threadIdx.x;
    int srow = t >> 2, scb = (t & 3) * 2;         // staging: row 0..63, chunk pair
    int sw = srow & 7;
    const int lane = t & 63, w = t >> 6;
    const int wm = w >> 1, wj = w & 1;
    const int lg = lane >> 4, lr = lane & 15;
    const int ma = wm * 32 + lr, mb = ma + 16;    // A rows (same &7)
    const int ja = wj * 32 + lr, jb = ja + 16;    // B rows
    const int swa = ma & 7, swb = ja & 7;
    f32x4 acc00 = {}, acc01 = {}, acc10 = {}, acc11 = {};
    const size_t gbase = (size_t)(m0 + srow) * NN;
    const size_t xbase = (size_t)(j0 + srow) * NN;
    for (int k0 = 0; k0 < NN; k0 += 64) {
        bf16x8 g0 = *(const bf16x8*)(Gt + gbase + k0 + scb * 8);
        bf16x8 g1 = *(const bf16x8*)(Gt + gbase + k0 + scb * 8 + 8);
        bf16x8 x0 = *(const bf16x8*)(Xt + xbase + k0 + scb * 8);
        bf16x8 x1 = *(const bf16x8*)(Xt + xbase + k0 + scb * 8 + 8);
        __syncthreads();
        *(bf16x8*)&As[srow * 64 + ((scb    ) ^ sw) * 8] = g0;
        *(bf16x8*)&As[srow * 64 + ((scb + 1) ^ sw) * 8] = g1;
        *(bf16x8*)&Bs[srow * 64 + ((scb    ) ^ sw) * 8] = x0;
        *(bf16x8*)&Bs[srow * 64 + ((scb + 1) ^ sw) * 8] = x1;
        __syncthreads();
#pragma unroll
        for (int kk = 0; kk < 2; ++kk) {
            int c = kk * 4 + lg;
            bf16x8 a0 = *(const bf16x8*)&As[ma * 64 + (c ^ swa) * 8];
            bf16x8 a1 = *(const bf16x8*)&As[mb * 64 + (c ^ swa) * 8];
            bf16x8 b0 = *(const bf16x8*)&Bs[ja * 64 + (c ^ swb) * 8];
            bf16x8 b1 = *(const bf16x8*)&Bs[jb * 64 + (c ^ swb) * 8];
            acc00 = __builtin_amdgcn_mfma_f32_16x16x32_bf16(a0, b0, acc00, 0, 0, 0);
            acc01 = __builtin_amdgcn_mfma_f32_16x16x32_bf16(a0, b1, acc01, 0, 0, 0);
            acc10 = __builtin_amdgcn_mfma_f32_16x16x32_bf16(a1, b0, acc10, 0, 0, 0);
            acc11 = __builtin_amdgcn_mfma_f32_16x16x32_bf16(a1, b1, acc11, 0, 0, 0);
        }
    }
    // D layout: col(j) = lane&15, row(m) = lg*4 + r  [measured m89/m91]
    int jA = j0 + wj * 32 + lr;
    int mA = m0 + wm * 32 + lg * 4;
#pragma unroll
    for (int r = 0; r < 4; ++r) {
        Y[(size_t)(mA + r) * 512 + jA]           = acc00[r];
        Y[(size_t)(mA + r) * 512 + jA + 16]      = acc01[r];
        Y[(size_t)(mA + 16 + r) * 512 + jA]      = acc10[r];
        Y[(size_t)(mA + 16 + r) * 512 + jA + 16] = acc11[r];
    }
    if (T) {
        ushortx4 p0, p1, p2, p3;
#pragma unroll
        for (int r = 0; r < 4; ++r) {
            p0[r] = brne(acc00[r]);
            p1[r] = brne(acc01[r]);
            p2[r] = brne(acc10[r]);
            p3[r] = brne(acc11[r]);
        }
        *(ushortx4*)&T[(size_t)jA * NN + mA]            = p0;
        *(ushortx4*)&T[(size_t)(jA + 16) * NN + mA]     = p1;
        *(ushortx4*)&T[(size_t)jA * NN + mA + 16]       = p2;
        *(ushortx4*)&T[(size_t)(jA + 16) * NN + mA + 16] = p3;
    }
}

// ---------------- GCN output conv for one branch ----------------
__global__ __launch_bounds__(512) void k_gcn_out(const float* __restrict__ Qcat,
                                                 const float* __restrict__ x1a,
                                                 const float* __restrict__ x1b,
                                                 const float* __restrict__ x2,
                                                 const float* __restrict__ W,
                                                 const float* __restrict__ bias,
                                                 float* __restrict__ out) {
    __shared__ float Ws[64][193];
    __shared__ float rows[3][512];
    int n = blockIdx.x;
    int tid = threadIdx.x;
    for (int i = tid; i < 64 * 192; i += 512) Ws[i / 192][i % 192] = W[i];
    rows[0][tid] = Qcat[(size_t)n * 512 + tid];
    float v1 = x1a[(size_t)n * 512 + tid];
    if (x1b) v1 += x1b[(size_t)n * 512 + tid];
    rows[1][tid] = v1;
    rows[2][tid] = x2[(size_t)n * 512 + tid];
    __syncthreads();
    int b = tid >> 6, o = tid & 63;
    const float* r0 = &rows[0][b * 64];
    const float* r1 = &rows[1][b * 64];
    const float* r2 = &rows[2][b * 64];
    float acc = bias[o];
    for (int c = 0; c < 64; ++c)
        acc += r0[c] * Ws[o][c] + r1[c] * Ws[o][64 + c] + r2[c] * Ws[o][128 + c];
    out[((size_t)b * NN + n) * 64 + o] = acc;
}

// ---------------- gated fusion ----------------
__global__ __launch_bounds__(256) void k_gate(const float* __restrict__ XF,
                                              const float* __restrict__ XD,
                                              float* __restrict__ XDF) {
    int i = blockIdx.x * 256 + threadIdx.x;
    float f = XF[i], d = XD[i];
    XDF[i] = tanhf(d) * (1.f / (1.f + expf(-f)));
}

// ---------------- q,k,v projections into [B][h][N][16] ----------------
__global__ __launch_bounds__(256) void k_qkv(const float* __restrict__ XDF,
                                             const float* __restrict__ wq,
                                             const float* __restrict__ wk,
                                             const float* __restrict__ wv,
                                             float* __restrict__ qb,
                                             float* __restrict__ kb,
                                             float* __restrict__ vb) {
    __shared__ float Ws[192][65];
    __shared__ float xs[16][64];
    int tid = threadIdx.x;
    for (int i = tid; i < 4096; i += 256) {
        int r = i >> 6, c = i & 63;
        Ws[r][c] = wq[i];
        Ws[64 + r][c] = wk[i];
        Ws[128 + r][c] = wv[i];
    }
    int row0 = blockIdx.x * 16;
    for (int i = tid; i < 1024; i += 256) xs[i >> 6][i & 63] = XDF[(size_t)row0 * 64 + i];
    __syncthreads();
#pragma unroll
    for (int it = 0; it < 12; ++it) {
        int oi = it * 256 + tid;
        int r = oi / 192, o = oi % 192;
        const float* x = xs[r];
        float acc = 0.f;
        for (int c = 0; c < 64; ++c) acc += x[c] * Ws[o][c];
        int row = row0 + r;
        int b = row >> 11, nn2 = row & 2047;
        int kind = o >> 6, hh = (o & 63) >> 4, d = o & 15;
        float* dst = kind == 0 ? qb : (kind == 1 ? kb : vb);
        dst[(((size_t)b * 4 + hh) * NN + nn2) * 16 + d] = acc;
    }
}

// ---------------- attention with KV split-K: partial exp-sums per split ----------------
#define KS 4
__global__ __launch_bounds__(256) void k_attn_sk(const float* __restrict__ qb,
                                                 const float* __restrict__ kb,
                                                 const float* __restrict__ vb,
                                                 float* __restrict__ Pacc,
                                                 float* __restrict__ Pssum) {
    __shared__ __align__(16) float4 ks[256];   // 64 rows x 16 floats
    __shared__ __align__(16) float4 vs[256];
    int bh = blockIdx.y;
    int sp = blockIdx.z;
    int n = blockIdx.x * 256 + threadIdx.x;
    const float4* qr = (const float4*)&qb[((size_t)bh * NN + n) * 16];
    float4 q0 = qr[0], q1 = qr[1], q2 = qr[2], q3 = qr[3];
    const float4* K = (const float4*)&kb[((size_t)bh * NN + sp * (NN / KS)) * 16];
    const float4* V = (const float4*)&vb[((size_t)bh * NN + sp * (NN / KS)) * 16];
    float4 a0 = make_float4(0, 0, 0, 0), a1 = a0, a2 = a0, a3 = a0;
    float ssum = 0.f;
    const float SCL = 0.36067376022224085f;   // log2e/4
    const float SH  = -11.541560327111707f;   // -8*log2e
    for (int m0 = 0; m0 < NN / KS; m0 += 64) {
        __syncthreads();
        ks[threadIdx.x] = K[m0 * 4 + threadIdx.x];
        vs[threadIdx.x] = V[m0 * 4 + threadIdx.x];
        __syncthreads();
#pragma unroll 4
        for (int mm = 0; mm < 64; ++mm) {
            float4 k0 = ks[mm * 4], k1 = ks[mm * 4 + 1], k2 = ks[mm * 4 + 2], k3 = ks[mm * 4 + 3];
            float d0 = q0.x * k0.x + q0.y * k0.y + q0.z * k0.z + q0.w * k0.w;
            float d1 = q1.x * k1.x + q1.y * k1.y + q1.z * k1.z + q1.w * k1.w;
            float d2 = q2.x * k2.x + q2.y * k2.y + q2.z * k2.z + q2.w * k2.w;
            float d3 = q3.x * k3.x + q3.y * k3.y + q3.z * k3.z + q3.w * k3.w;
            float s = (d0 + d1) + (d2 + d3);
            float p = exp2f(fmaf(s, SCL, SH));
            ssum += p;
            float4 v0 = vs[mm * 4], v1 = vs[mm * 4 + 1], v2 = vs[mm * 4 + 2], v3 = vs[mm * 4 + 3];
            a0.x += p * v0.x; a0.y += p * v0.y; a0.z += p * v0.z; a0.w += p * v0.w;
            a1.x += p * v1.x; a1.y += p * v1.y; a1.z += p * v1.z; a1.w += p * v1.w;
            a2.x += p * v2.x; a2.y += p * v2.y; a2.z += p * v2.z; a2.w += p * v2.w;
            a3.x += p * v3.x; a3.y += p * v3.y; a3.z += p * v3.z; a3.w += p * v3.w;
        }
    }
    float4* dst = (float4*)&Pacc[(((size_t)bh * KS + sp) * NN + n) * 16];
    dst[0] = a0; dst[1] = a1; dst[2] = a2; dst[3] = a3;
    Pssum[((size_t)bh * KS + sp) * NN + n] = ssum;
}

// ---------------- combine attention splits -> ctx[b][n][64] ----------------
__global__ __launch_bounds__(256) void k_attn_red(const float* __restrict__ Pacc,
                                                  const float* __restrict__ Pssum,
                                                  float* __restrict__ ctx) {
    int bh = blockIdx.y;
    int i = blockIdx.x * 256 + threadIdx.x;   // 0..32767
    int n = i >> 4, d = i & 15;
    float a = 0.f, ss = 0.f;
#pragma unroll
    for (int s = 0; s < KS; ++s) {
        a  += Pacc[(((size_t)bh * KS + s) * NN + n) * 16 + d];
        ss += Pssum[((size_t)bh * KS + s) * NN + n];
    }
    int b = bh >> 2, h = bh & 3;
    ctx[((size_t)b * NN + n) * 64 + h * 16 + d] = a / ss;
}

// ---------------- att_out = ctx@wo^T + bo; x = LN(att_out + XDF; g2,be2) ----------------
__global__ __launch_bounds__(256) void k_post1(const float* __restrict__ ctx,
                                               const float* __restrict__ XDF,
                                               const float* __restrict__ wo,
                                               const float* __restrict__ bo,
                                               const float* __restrict__ g2,
                                               const float* __restrict__ be2,
                                               float* __restrict__ xout) {
    __shared__ float W[64][65];
    __shared__ float xs[4][64];
    int tid = threadIdx.x;
    for (int i = tid; i < 4096; i += 256) W[i >> 6][i & 63] = wo[i];
    int row0 = blockIdx.x * 4;
    xs[tid >> 6][tid & 63] = ctx[(size_t)row0 * 64 + tid];
    __syncthreads();
    int r = tid >> 6, o = tid & 63;
    int row = row0 + r;
    const float* x = xs[r];
    float y = bo[o];
    for (int c = 0; c < 64; ++c) y += x[c] * W[o][c];
    y += XDF[(size_t)row * 64 + o];
    float mean = wsum64(y) * (1.f / 64.f);
    float d = y - mean;
    float var = wsum64(d * d) * (1.f / 64.f);
    float rstd = rsqrtf(var + 1e-5f);
    xout[(size_t)row * 64 + o] = d * rstd * g2[o] + be2[o];
}

// ---------------- t = relu(x @ f1w^T + f1b)  [rows][256] ----------------
__global__ __launch_bounds__(256) void k_ffn1(const float* __restrict__ x,
                                              const float* __restrict__ f1w,
                                              const float* __restrict__ f1b,
                                              float* __restrict__ t) {
    __shared__ float W[256 * 64];   // swizzled
    int tid = threadIdx.x;
    for (int i = tid; i < 16384; i += 256) {
        int j = i >> 6, c = i & 63;
        W[(j << 6) | (c ^ (j & 31))] = f1w[i];
    }
    __syncthreads();
    int j = tid;
    float bj = f1b[j];
    const float* Wj = &W[j << 6];
    int jx = j & 31;
    int row0 = blockIdx.x * 32;
    for (int rr = 0; rr < 32; ++rr) {
        int row = row0 + rr;
        const float* xr = &x[(size_t)row * 64];
        float acc = bj;
        for (int c = 0; c < 64; ++c) acc += xr[c] * Wj[c ^ jx];
        t[(size_t)row * 256 + j] = fmaxf(acc, 0.f);
    }
}

// ---------------- y = t @ f2w^T + f2b; out = LN(y + x; g3,be3) ----------------
__global__ __launch_bounds__(256) void k_ffn2(const float* __restrict__ t,
                                              const float* __restrict__ x,
                                              const float* __restrict__ f2w,
                                              const float* __restrict__ f2b,
                                              const float* __restrict__ g3,
                                              const float* __restrict__ be3,
                                              float* __restrict__ out) {
    __shared__ float W[64 * 256];   // swizzled
    int tid = threadIdx.x;
    for (int i = tid; i < 16384; i += 256) {
        int o = i >> 8, c = i & 255;
        W[(o << 8) | (c ^ (o & 31))] = f2w[i];
    }
    __syncthreads();
    int r = tid >> 6, o = tid & 63;
    int ox = o & 31;
    const float* Wo = &W[o << 8];
    int row0 = blockIdx.x * 16;
    for (int rr = 0; rr < 4; ++rr) {
        int row = row0 + rr * 4 + r;
        const float* tr = &t[(size_t)row * 256];
        float y = f2b[o];
        for (int j = 0; j < 256; ++j) y += tr[j] * Wo[j ^ ox];
        y += x[(size_t)row * 64 + o];
        float mean = wsum64(y) * (1.f / 64.f);
        float d = y - mean;
        float var = wsum64(d * d) * (1.f / 64.f);
        float rstd = rsqrtf(var + 1e-5f);
        out[(size_t)row * 64 + o] = d * rstd * g3[o] + be3[o];
    }
}

extern "C" void kernel_launch(void* const* d_in, const int* in_sizes, int n_in,
                              void* d_out, int out_size, void* d_ws, size_t ws_size,
                              hipStream_t stream) {
    const float* query = (const float*)d_in[0];
    const float* adj   = (const float*)d_in[1];
    const float* WF    = (const float*)d_in[2];
    const float* bF    = (const float*)d_in[3];
    const float* WD    = (const float*)d_in[4];
    const float* bD    = (const float*)d_in[5];
    const float* ffw1  = (const float*)d_in[6];
    const float* ffb1  = (const float*)d_in[7];
    const float* ffw2  = (const float*)d_in[8];
    const float* ffb2  = (const float*)d_in[9];
    const float* wq    = (const float*)d_in[10];
    const float* wk    = (const float*)d_in[11];
    const float* wv    = (const float*)d_in[12];
    const float* wo    = (const float*)d_in[13];
    const float* bo    = (const float*)d_in[14];
    const float* g2    = (const float*)d_in[15];
    const float* be2   = (const float*)d_in[16];
    const float* g3    = (const float*)d_in[17];
    const float* be3   = (const float*)d_in[18];
    const float* f1w   = (const float*)d_in[19];
    const float* f1b   = (const float*)d_in[20];
    const float* f2w   = (const float*)d_in[21];
    const float* f2b   = (const float*)d_in[22];
    float* out = (float*)d_out;

    // Arena: total 13,897,984 floats (55.6 MB) == round-1 proven workspace usage.
    float* w = (float*)d_ws;
    float* Qcat  = w;                    // 1048576    [N][512]; later vb
    float* Qsum  = w + 1048576;          // 131072
    float* Wc    = w + 1179648;          // 4096
    float* bc    = w + 1183744;          // 256 pad
    float* Rsum  = w + 1184000;          // 131072
    float* BigA  = w + 1315072;          // 4194304: Amat -> X1F/X1D/X1FT/X1DT -> qb/kb -> x1
    float* X2Fb  = w + 5509376;          // 1048576: QcatT -> X2F
    float* TTb   = w + 6557952;          // 4194304: adjT+RmT -> X2D -> Pacc -> tbuf
    float* XFo   = w + 10752256;         // 1048576 -> Pssum
    float* XDo   = w + 11800832;         // 1048576 -> ctx
    float* XDF   = w + 12849408;         // 1048576

    float*    Amat  = BigA;
    ushort_t* adjT  = (ushort_t*)TTb;                    // [2048][2048] bf16
    ushort_t* RmT   = (ushort_t*)(TTb + 2097152);        // [2048][2048] bf16
    ushort_t* QcatT = (ushort_t*)X2Fb;                   // [512][2048] bf16
    float*    X1F   = BigA;                              // [2048][512]
    float*    X1D   = BigA + 1048576;
    ushort_t* X1FT  = (ushort_t*)(BigA + 2097152);       // [512][2048] bf16
    ushort_t* X1DT  = (ushort_t*)(BigA + 2621440);
    float*    X2F   = X2Fb;                              // overwrites QcatT (dead)
    float*    X2D   = TTb;                               // overwrites adjT (dead)
    float*    qb    = BigA;
    float*    kb    = BigA + 1048576;
    float*    vb    = Qcat;
    float*    Pacc  = TTb;               // 4194304 == 32*KS*2048*16
    float*    Pssum = XFo;
    float*    ctxb  = XDo;
    float*    x1    = BigA;
    float*    tbuf  = TTb;

    k_wc<<<16, 256, 0, stream>>>(ffw1, ffb1, ffw2, ffb2, Wc, bc);
    k_qprep<<<512, 256, 0, stream>>>(query, Qcat, Qsum);
    k_rsum<<<512, 256, 0, stream>>>(Qsum, Wc, bc, Rsum);
    k_amat<<<dim3(32, 32), 256, 0, stream>>>(Rsum, Amat);
    k_softmax<<<2048, 256, 0, stream>>>(Amat);

    k_t32to16<<<dim3(32, 32), 256, 0, stream>>>(adj, adjT, NN, NN);
    k_t32to16<<<dim3(32, 32), 256, 0, stream>>>(Amat, RmT, NN, NN);
    k_t32to16<<<dim3(8, 32), 256, 0, stream>>>(Qcat, QcatT, NN, 512);

    // hop1 both branches
    k_hop<<<dim3(8, 32, 2), 256, 0, stream>>>(adjT, RmT, QcatT, QcatT,
                                              X1F, X1D, X1FT, X1DT);
    // hop2 F (needs adjT alive), then hop2 D (X2D overwrites adjT region)
    k_hop<<<dim3(8, 32, 1), 256, 0, stream>>>(adjT, adjT, X1FT, X1FT,
                                              X2F, X2F, nullptr, nullptr);
    k_gcn_out<<<2048, 512, 0, stream>>>(Qcat, X1F, nullptr, X2F, WF, bF, XFo);
    k_hop<<<dim3(8, 32, 1), 256, 0, stream>>>(RmT, RmT, X1DT, X1DT,
                                              X2D, X2D, nullptr, nullptr);
    k_gcn_out<<<2048, 512, 0, stream>>>(Qcat, X1D, nullptr, X2D, WD, bD, XDo);
    k_gate<<<4096, 256, 0, stream>>>(XFo, XDo, XDF);

    k_qkv<<<1024, 256, 0, stream>>>(XDF, wq, wk, wv, qb, kb, vb);
    k_attn_sk<<<dim3(8, 32, KS), 256, 0, stream>>>(qb, kb, vb, Pacc, Pssum);
    k_attn_red<<<dim3(128, 32), 256, 0, stream>>>(Pacc, Pssum, ctxb);
    k_post1<<<4096, 256, 0, stream>>>(ctxb, XDF, wo, bo, g2, be2, x1);
    k_ffn1<<<512, 256, 0, stream>>>(x1, f1w, f1b, tbuf);
    k_ffn2<<<1024, 256, 0, stream>>>(tbuf, x1, f2w, f2b, g3, be3, out);
}

// Round 5
// 478.157 us; speedup vs baseline: 2.6360x; 1.3654x over previous
//
#include <hip/hip_runtime.h>
#include <math.h>

#define NN 2048
#define BB 8
#define HD 64

typedef __attribute__((ext_vector_type(8))) short bf16x8;
typedef __attribute__((ext_vector_type(4))) float f32x4;
typedef __attribute__((ext_vector_type(16))) float f32x16;
typedef __attribute__((ext_vector_type(4))) unsigned short ushortx4;
typedef unsigned short ushort_t;

static __device__ __forceinline__ float wsum64(float v) {
#pragma unroll
    for (int off = 32; off >= 1; off >>= 1) v += __shfl_xor(v, off);
    return v;
}
static __device__ __forceinline__ float wmax64(float v) {
#pragma unroll
    for (int off = 32; off >= 1; off >>= 1) v = fmaxf(v, __shfl_xor(v, off));
    return v;
}
static __device__ __forceinline__ unsigned short brne(float x) {
    unsigned u = __float_as_uint(x);
    return (unsigned short)((u + 0x7fffu + ((u >> 16) & 1u)) >> 16);
}

// ---------------- Wc = ffw2 @ ffw1  [64,64], bc = ffw2@ffb1 + ffb2 ----------------
__global__ void k_wc(const float* __restrict__ ffw1, const float* __restrict__ ffb1,
                     const float* __restrict__ ffw2, const float* __restrict__ ffb2,
                     float* __restrict__ Wc, float* __restrict__ bc) {
    int idx = blockIdx.x * 256 + threadIdx.x;
    if (idx < 4096) {
        int o = idx >> 6, c = idx & 63;
        float s = 0.f;
        for (int j = 0; j < 384; ++j) s += ffw2[o * 384 + j] * ffw1[j * 64 + c];
        Wc[idx] = s;
    }
    if (idx < 64) {
        float s = ffb2[idx];
        for (int j = 0; j < 384; ++j) s += ffw2[idx * 384 + j] * ffb1[j];
        bc[idx] = s;
    }
}

// ---------------- Qcat[n][b*64+c] = query[b][n][c]; Qsum[n][c] = sum_b ----------------
__global__ __launch_bounds__(256) void k_qprep(const float* __restrict__ q,
                                               float* __restrict__ Qcat,
                                               float* __restrict__ Qsum) {
    int idx = blockIdx.x * 256 + threadIdx.x;   // 0..131071
    int n = idx >> 6, c = idx & 63;
    float s = 0.f;
#pragma unroll
    for (int b = 0; b < BB; ++b) {
        float v = q[((size_t)b * NN + n) * 64 + c];
        s += v;
        Qcat[(size_t)n * 512 + b * 64 + c] = v;
    }
    Qsum[idx] = s;
}

// ---------------- Rsum[n][h] = Qsum[n] . Wc[h] + 8*bc[h] ----------------
__global__ __launch_bounds__(256) void k_rsum(const float* __restrict__ Qsum,
                                              const float* __restrict__ Wc,
                                              const float* __restrict__ bc,
                                              float* __restrict__ Rsum) {
    __shared__ float W[64][65];
    int tid = threadIdx.x;
    for (int i = tid; i < 4096; i += 256) W[i >> 6][i & 63] = Wc[i];
    __syncthreads();
    int idx = blockIdx.x * 256 + tid;
    int n = idx >> 6, h = idx & 63;
    const float* qs = &Qsum[n * 64];
    float s = 8.f * bc[h];
    for (int c = 0; c < 64; ++c) s += qs[c] * W[h][c];
    Rsum[idx] = s;
}

// ---------------- A[n][m] = Rsum[n] . Rsum[m] ----------------
__global__ __launch_bounds__(256) void k_amat(const float* __restrict__ R, float* __restrict__ A) {
    __shared__ float Rn[64][65];
    __shared__ float Rm[64][65];
    int n0 = blockIdx.y * 64, m0 = blockIdx.x * 64;
    int tid = threadIdx.x;
    for (int i = tid; i < 4096; i += 256) {
        int r = i >> 6, c = i & 63;
        Rn[r][c] = R[(n0 + r) * 64 + c];
        Rm[r][c] = R[(m0 + r) * 64 + c];
    }
    __syncthreads();
    int tx = tid & 15, ty = tid >> 4;
    float acc[4][4] = {};
    for (int k = 0; k < 64; ++k) {
        float a[4], b[4];
#pragma unroll
        for (int i = 0; i < 4; ++i) a[i] = Rn[ty * 4 + i][k];
#pragma unroll
        for (int j = 0; j < 4; ++j) b[j] = Rm[tx * 4 + j][k];
#pragma unroll
        for (int i = 0; i < 4; ++i)
#pragma unroll
            for (int j = 0; j < 4; ++j) acc[i][j] += a[i] * b[j];
    }
#pragma unroll
    for (int i = 0; i < 4; ++i)
#pragma unroll
        for (int j = 0; j < 4; ++j)
            A[(size_t)(n0 + ty * 4 + i) * NN + m0 + tx * 4 + j] = acc[i][j];
}

// ---------------- in-place row softmax + identity: Rm = softmax(A,-1) + I ----------------
__global__ __launch_bounds__(256) void k_softmax(float* __restrict__ A) {
    __shared__ float red[8];
    int n = blockIdx.x, tid = threadIdx.x;
    float4* row = (float4*)&A[(size_t)n * NN];
    float4 a = row[tid * 2], b = row[tid * 2 + 1];
    float v[8] = {a.x, a.y, a.z, a.w, b.x, b.y, b.z, b.w};
    float mx = v[0];
#pragma unroll
    for (int i = 1; i < 8; ++i) mx = fmaxf(mx, v[i]);
    mx = wmax64(mx);
    int wid = tid >> 6, lane = tid & 63;
    if (lane == 0) red[wid] = mx;
    __syncthreads();
    mx = fmaxf(fmaxf(red[0], red[1]), fmaxf(red[2], red[3]));
    float s = 0.f;
#pragma unroll
    for (int i = 0; i < 8; ++i) { v[i] = exp2f((v[i] - mx) * 1.44269504f); s += v[i]; }
    s = wsum64(s);
    if (lane == 0) red[4 + wid] = s;
    __syncthreads();
    s = red[4] + red[5] + red[6] + red[7];
    float inv = 1.f / s;
    int col = tid * 8;
#pragma unroll
    for (int i = 0; i < 8; ++i) v[i] = v[i] * inv + ((col + i) == n ? 1.f : 0.f);
    row[tid * 2]     = make_float4(v[0], v[1], v[2], v[3]);
    row[tid * 2 + 1] = make_float4(v[4], v[5], v[6], v[7]);
}

// ---------------- transpose + fp32->bf16: out[c][r] = bf16(in[r][c]) ----------------
__global__ __launch_bounds__(256) void k_t32to16(const float* __restrict__ in,
                                                 ushort_t* __restrict__ out,
                                                 int R, int C) {
    __shared__ float tile[64][65];
    int r0 = blockIdx.y * 64, c0 = blockIdx.x * 64;
    int t = threadIdx.x;
    int tr = t >> 6, tc = t & 63;
#pragma unroll
    for (int i = 0; i < 16; ++i) {
        int r = tr + i * 4;
        tile[r][tc] = in[(size_t)(r0 + r) * C + c0 + tc];
    }
    __syncthreads();
#pragma unroll
    for (int i = 0; i < 16; ++i) {
        int cc = tr + i * 4;
        out[(size_t)(c0 + cc) * R + r0 + tc] = brne(tile[tc][cc]);
    }
}

// ---------------- MFMA propagation hop ----------------
// Y[m][j] = sum_k G[k][m] * X[k][j], using Gt[m][k] bf16 and Xt[j][k] bf16.
// Optionally writes Tt[j][m] = bf16(Y[m][j]) for the next hop.
__global__ __launch_bounds__(256) void k_hop(const ushort_t* __restrict__ G0t,
                                             const ushort_t* __restrict__ G1t,
                                             const ushort_t* __restrict__ B0t,
                                             const ushort_t* __restrict__ B1t,
                                             float* __restrict__ Y0, float* __restrict__ Y1,
                                             ushort_t* __restrict__ T0, ushort_t* __restrict__ T1) {
    __shared__ __align__(16) ushort_t As[4096];   // [64 m][64 k] swizzled, 8KB
    __shared__ __align__(16) ushort_t Bs[4096];   // [64 j][64 k] swizzled
    int z = blockIdx.z;
    const ushort_t* Gt = z ? G1t : G0t;
    const ushort_t* Xt = z ? B1t : B0t;
    float* Y = z ? Y1 : Y0;
    ushort_t* T = z ? T1 : T0;
    int m0 = blockIdx.y * 64, j0 = blockIdx.x * 64;
    int t = threadIdx.x;
    int srow = t >> 2, scb = (t & 3) * 2;         // staging: row 0..63, chunk pair
    int sw = srow & 7;
    const int lane = t & 63, w = t >> 6;
    const int wm = w >> 1, wj = w & 1;
    const int lg = lane >> 4, lr = lane & 15;
    const int ma = wm * 32 + lr, mb = ma + 16;    // A rows (same &7)
    const int ja = wj * 32 + lr, jb = ja + 16;    // B rows
    const int swa = ma & 7, swb = ja & 7;
    f32x4 acc00 = {}, acc01 = {}, acc10 = {}, acc11 = {};
    const size_t gbase = (size_t)(m0 + srow) * NN;
    const size_t xbase = (size_t)(j0 + srow) * NN;
    for (int k0 = 0; k0 < NN; k0 += 64) {
        bf16x8 g0 = *(const bf16x8*)(Gt + gbase + k0 + scb * 8);
        bf16x8 g1 = *(const bf16x8*)(Gt + gbase + k0 + scb * 8 + 8);
        bf16x8 x0 = *(const bf16x8*)(Xt + xbase + k0 + scb * 8);
        bf16x8 x1 = *(const bf16x8*)(Xt + xbase + k0 + scb * 8 + 8);
        __syncthreads();
        *(bf16x8*)&As[srow * 64 + ((scb    ) ^ sw) * 8] = g0;
        *(bf16x8*)&As[srow * 64 + ((scb + 1) ^ sw) * 8] = g1;
        *(bf16x8*)&Bs[srow * 64 + ((scb    ) ^ sw) * 8] = x0;
        *(bf16x8*)&Bs[srow * 64 + ((scb + 1) ^ sw) * 8] = x1;
        __syncthreads();
#pragma unroll
        for (int kk = 0; kk < 2; ++kk) {
            int c = kk * 4 + lg;
            bf16x8 a0 = *(const bf16x8*)&As[ma * 64 + (c ^ swa) * 8];
            bf16x8 a1 = *(const bf16x8*)&As[mb * 64 + (c ^ swa) * 8];
            bf16x8 b0 = *(const bf16x8*)&Bs[ja * 64 + (c ^ swb) * 8];
            bf16x8 b1 = *(const bf16x8*)&Bs[jb * 64 + (c ^ swb) * 8];
            acc00 = __builtin_amdgcn_mfma_f32_16x16x32_bf16(a0, b0, acc00, 0, 0, 0);
            acc01 = __builtin_amdgcn_mfma_f32_16x16x32_bf16(a0, b1, acc01, 0, 0, 0);
            acc10 = __builtin_amdgcn_mfma_f32_16x16x32_bf16(a1, b0, acc10, 0, 0, 0);
            acc11 = __builtin_amdgcn_mfma_f32_16x16x32_bf16(a1, b1, acc11, 0, 0, 0);
        }
    }
    // D layout: col(j) = lane&15, row(m) = lg*4 + r  [measured m89/m91]
    int jA = j0 + wj * 32 + lr;
    int mA = m0 + wm * 32 + lg * 4;
#pragma unroll
    for (int r = 0; r < 4; ++r) {
        Y[(size_t)(mA + r) * 512 + jA]           = acc00[r];
        Y[(size_t)(mA + r) * 512 + jA + 16]      = acc01[r];
        Y[(size_t)(mA + 16 + r) * 512 + jA]      = acc10[r];
        Y[(size_t)(mA + 16 + r) * 512 + jA + 16] = acc11[r];
    }
    if (T) {
        ushortx4 p0, p1, p2, p3;
#pragma unroll
        for (int r = 0; r < 4; ++r) {
            p0[r] = brne(acc00[r]);
            p1[r] = brne(acc01[r]);
            p2[r] = brne(acc10[r]);
            p3[r] = brne(acc11[r]);
        }
        *(ushortx4*)&T[(size_t)jA * NN + mA]            = p0;
        *(ushortx4*)&T[(size_t)(jA + 16) * NN + mA]     = p1;
        *(ushortx4*)&T[(size_t)jA * NN + mA + 16]       = p2;
        *(ushortx4*)&T[(size_t)(jA + 16) * NN + mA + 16] = p3;
    }
}

// ---------------- GCN output conv for one branch ----------------
__global__ __launch_bounds__(512) void k_gcn_out(const float* __restrict__ Qcat,
                                                 const float* __restrict__ x1a,
                                                 const float* __restrict__ x1b,
                                                 const float* __restrict__ x2,
                                                 const float* __restrict__ W,
                                                 const float* __restrict__ bias,
                                                 float* __restrict__ out) {
    __shared__ float Ws[64][193];
    __shared__ float rows[3][512];
    int n = blockIdx.x;
    int tid = threadIdx.x;
    for (int i = tid; i < 64 * 192; i += 512) Ws[i / 192][i % 192] = W[i];
    rows[0][tid] = Qcat[(size_t)n * 512 + tid];
    float v1 = x1a[(size_t)n * 512 + tid];
    if (x1b) v1 += x1b[(size_t)n * 512 + tid];
    rows[1][tid] = v1;
    rows[2][tid] = x2[(size_t)n * 512 + tid];
    __syncthreads();
    int b = tid >> 6, o = tid & 63;
    const float* r0 = &rows[0][b * 64];
    const float* r1 = &rows[1][b * 64];
    const float* r2 = &rows[2][b * 64];
    float acc = bias[o];
    for (int c = 0; c < 64; ++c)
        acc += r0[c] * Ws[o][c] + r1[c] * Ws[o][64 + c] + r2[c] * Ws[o][128 + c];
    out[((size_t)b * NN + n) * 64 + o] = acc;
}

// ---------------- gated fusion ----------------
__global__ __launch_bounds__(256) void k_gate(const float* __restrict__ XF,
                                              const float* __restrict__ XD,
                                              float* __restrict__ XDF) {
    int i = blockIdx.x * 256 + threadIdx.x;
    float f = XF[i], d = XD[i];
    XDF[i] = tanhf(d) * (1.f / (1.f + expf(-f)));
}

// ---------------- q,k,v projections -> bf16 qb/kb [bh][N][16], vbt [bh][32][N] (d>=16 zero) ----
__global__ __launch_bounds__(256) void k_qkv(const float* __restrict__ XDF,
                                             const float* __restrict__ wq,
                                             const float* __restrict__ wk,
                                             const float* __restrict__ wv,
                                             ushort_t* __restrict__ qb,
                                             ushort_t* __restrict__ kb,
                                             ushort_t* __restrict__ vbt) {
    __shared__ float Ws[192][65];
    __shared__ float xs[16][64];
    __shared__ __align__(16) ushort_t vt[64][16];
    int tid = threadIdx.x;
    for (int i = tid; i < 4096; i += 256) {
        int r = i >> 6, c = i & 63;
        Ws[r][c] = wq[i];
        Ws[64 + r][c] = wk[i];
        Ws[128 + r][c] = wv[i];
    }
    int row0 = blockIdx.x * 16;
    for (int i = tid; i < 1024; i += 256) xs[i >> 6][i & 63] = XDF[(size_t)row0 * 64 + i];
    __syncthreads();
#pragma unroll
    for (int it = 0; it < 12; ++it) {
        int oi = it * 256 + tid;
        int r = oi / 192, o = oi % 192;
        const float* x = xs[r];
        float acc = 0.f;
        for (int c = 0; c < 64; ++c) acc += x[c] * Ws[o][c];
        int row = row0 + r;
        int b = row >> 11, nn2 = row & 2047;
        int kind = o >> 6, hd = o & 63;
        if (kind < 2) {
            ushort_t* dst = kind == 0 ? qb : kb;
            dst[(((size_t)b * 4 + (hd >> 4)) * NN + nn2) * 16 + (hd & 15)] = brne(acc);
        } else {
            vt[hd][r] = brne(acc);
        }
    }
    __syncthreads();
    int b = row0 >> 11, nloc = row0 & 2047;
    if (tid < 128) {
        int hd = tid >> 1, half = tid & 1;
        *(uint4*)&vbt[(((size_t)b * 4 + (hd >> 4)) * 32 + (hd & 15)) * NN + nloc + half * 8] =
            *(const uint4*)&vt[hd][half * 8];
    } else {
        int t2 = tid - 128;                 // zero-pad rows d=16..31
        int hd = t2 >> 1, half = t2 & 1;
        uint4 z = make_uint4(0u, 0u, 0u, 0u);
        *(uint4*)&vbt[(((size_t)b * 4 + (hd >> 4)) * 32 + 16 + (hd & 15)) * NN + nloc + half * 8] = z;
    }
}

// ---------------- MFMA flash attention (32x32x16, swapped QK^T) ----------------
// S^T = MFMA(A=K-rows, B=Q-rows): lane holds P[q=lane&31][m=crow(r,hi)],
// crow(r,hi)=(r&3)+8*(r>>2)+4*hi [measured m101]. cvt_pk + shfl_xor(32) builds
// the PV A-fragment (P[q][m=8*hi+i]); V consumed via d-padded V^T rows.
__global__ __launch_bounds__(256) void k_attn_mf(const ushort_t* __restrict__ qb,
                                                 const ushort_t* __restrict__ kb,
                                                 const ushort_t* __restrict__ vbt,
                                                 float* __restrict__ ctx) {
    __shared__ float cpart[4][32][32];
    __shared__ float spart[4][32];
    int bh = blockIdx.y, n0 = blockIdx.x * 64;
    int tid = threadIdx.x, w = tid >> 6, l = tid & 63;
    int lc = l & 31, hi = l >> 5;
    int qsub = w & 1, mhalf = w >> 1;
    const ushort_t* Q  = qb + ((size_t)bh * NN + n0 + qsub * 32) * 16;
    const ushort_t* K  = kb + (size_t)bh * NN * 16;
    const ushort_t* VT = vbt + ((size_t)bh * 32 + lc) * NN;
    bf16x8 qf = *(const bf16x8*)(Q + lc * 16 + hi * 8);
    f32x16 zero = {};
    f32x16 acc = {};
    float ss = 0.f;
    const float SCL = 0.36067376022224085f;   // log2e/4
    const float SH  = -11.541560327111707f;   // -8*log2e
    for (int m0 = mhalf * 32; m0 < NN; m0 += 64) {
        bf16x8 kf = *(const bf16x8*)(K + (size_t)(m0 + lc) * 16 + hi * 8);
        bf16x8 v0 = *(const bf16x8*)(VT + m0 + hi * 8);
        bf16x8 v1 = *(const bf16x8*)(VT + m0 + 16 + hi * 8);
        f32x16 st = __builtin_amdgcn_mfma_f32_32x32x16_bf16(kf, qf, zero, 0, 0, 0);
        float p[16];
#pragma unroll
        for (int r = 0; r < 16; ++r) {
            p[r] = exp2f(fmaf(st[r], SCL, SH));
            ss += p[r];
        }
        unsigned d[8];
#pragma unroll
        for (int j = 0; j < 8; ++j)
            asm("v_cvt_pk_bf16_f32 %0, %1, %2" : "=v"(d[j]) : "v"(p[2 * j]), "v"(p[2 * j + 1]));
        unsigned s[8];
#pragma unroll
        for (int j = 0; j < 8; ++j) s[j] = (unsigned)__shfl_xor((int)d[j], 32);
        union { bf16x8 v; unsigned u[4]; } fa, fb;
        if (hi == 0) {
            fa.u[0] = d[0]; fa.u[1] = d[1]; fa.u[2] = s[0]; fa.u[3] = s[1];
            fb.u[0] = d[4]; fb.u[1] = d[5]; fb.u[2] = s[4]; fb.u[3] = s[5];
        } else {
            fa.u[0] = s[2]; fa.u[1] = s[3]; fa.u[2] = d[2]; fa.u[3] = d[3];
            fb.u[0] = s[6]; fb.u[1] = s[7]; fb.u[2] = d[6]; fb.u[3] = d[7];
        }
        acc = __builtin_amdgcn_mfma_f32_32x32x16_bf16(fa.v, v0, acc, 0, 0, 0);
        acc = __builtin_amdgcn_mfma_f32_32x32x16_bf16(fb.v, v1, acc, 0, 0, 0);
    }
    float s2v = ss + __shfl_xor(ss, 32);
    spart[w][lc] = s2v;
#pragma unroll
    for (int r = 0; r < 16; ++r)
        cpart[w][(r & 3) + 8 * (r >> 2) + 4 * hi][lc] = acc[r];
    __syncthreads();
    int q = tid >> 2, d4 = (tid & 3) * 4;
    int qs = q >> 5, q32 = q & 31;
    float sst = spart[qs][q32] + spart[2 + qs][q32];
    float inv = 1.f / sst;
    float4 o;
    o.x = (cpart[qs][q32][d4]     + cpart[2 + qs][q32][d4])     * inv;
    o.y = (cpart[qs][q32][d4 + 1] + cpart[2 + qs][q32][d4 + 1]) * inv;
    o.z = (cpart[qs][q32][d4 + 2] + cpart[2 + qs][q32][d4 + 2]) * inv;
    o.w = (cpart[qs][q32][d4 + 3] + cpart[2 + qs][q32][d4 + 3]) * inv;
    int b = bh >> 2, h = bh & 3;
    *(float4*)&ctx[((size_t)b * NN + n0 + q) * 64 + h * 16 + d4] = o;
}

// ---------------- att_out = ctx@wo^T + bo; x = LN(att_out + XDF; g2,be2) ----------------
__global__ __launch_bounds__(256) void k_post1(const float* __restrict__ ctx,
                                               const float* __restrict__ XDF,
                                               const float* __restrict__ wo,
                                               const float* __restrict__ bo,
                                               const float* __restrict__ g2,
                                               const float* __restrict__ be2,
                                               float* __restrict__ xout) {
    __shared__ float W[64][65];
    __shared__ float xs[4][64];
    int tid = threadIdx.x;
    for (int i = tid; i < 4096; i += 256) W[i >> 6][i & 63] = wo[i];
    int row0 = blockIdx.x * 4;
    xs[tid >> 6][tid & 63] = ctx[(size_t)row0 * 64 + tid];
    __syncthreads();
    int r = tid >> 6, o = tid & 63;
    int row = row0 + r;
    const float* x = xs[r];
    float y = bo[o];
    for (int c = 0; c < 64; ++c) y += x[c] * W[o][c];
    y += XDF[(size_t)row * 64 + o];
    float mean = wsum64(y) * (1.f / 64.f);
    float d = y - mean;
    float var = wsum64(d * d) * (1.f / 64.f);
    float rstd = rsqrtf(var + 1e-5f);
    xout[(size_t)row * 64 + o] = d * rstd * g2[o] + be2[o];
}

// ---------------- t = relu(x @ f1w^T + f1b)  [rows][256] ----------------
__global__ __launch_bounds__(256) void k_ffn1(const float* __restrict__ x,
                                              const float* __restrict__ f1w,
                                              const float* __restrict__ f1b,
                                              float* __restrict__ t) {
    __shared__ float W[256 * 64];   // swizzled
    int tid = threadIdx.x;
    for (int i = tid; i < 16384; i += 256) {
        int j = i >> 6, c = i & 63;
        W[(j << 6) | (c ^ (j & 31))] = f1w[i];
    }
    __syncthreads();
    int j = tid;
    float bj = f1b[j];
    const float* Wj = &W[j << 6];
    int jx = j & 31;
    int row0 = blockIdx.x * 32;
    for (int rr = 0; rr < 32; ++rr) {
        int row = row0 + rr;
        const float* xr = &x[(size_t)row * 64];
        float acc = bj;
        for (int c = 0; c < 64; ++c) acc += xr[c] * Wj[c ^ jx];
        t[(size_t)row * 256 + j] = fmaxf(acc, 0.f);
    }
}

// ---------------- y = t @ f2w^T + f2b; out = LN(y + x; g3,be3) ----------------
__global__ __launch_bounds__(256) void k_ffn2(const float* __restrict__ t,
                                              const float* __restrict__ x,
                                              const float* __restrict__ f2w,
                                              const float* __restrict__ f2b,
                                              const float* __restrict__ g3,
                                              const float* __restrict__ be3,
                                              float* __restrict__ out) {
    __shared__ float W[64 * 256];   // swizzled
    int tid = threadIdx.x;
    for (int i = tid; i < 16384; i += 256) {
        int o = i >> 8, c = i & 255;
        W[(o << 8) | (c ^ (o & 31))] = f2w[i];
    }
    __syncthreads();
    int r = tid >> 6, o = tid & 63;
    int ox = o & 31;
    const float* Wo = &W[o << 8];
    int row0 = blockIdx.x * 16;
    for (int rr = 0; rr < 4; ++rr) {
        int row = row0 + rr * 4 + r;
        const float* tr = &t[(size_t)row * 256];
        float y = f2b[o];
        for (int j = 0; j < 256; ++j) y += tr[j] * Wo[j ^ ox];
        y += x[(size_t)row * 64 + o];
        float mean = wsum64(y) * (1.f / 64.f);
        float d = y - mean;
        float var = wsum64(d * d) * (1.f / 64.f);
        float rstd = rsqrtf(var + 1e-5f);
        out[(size_t)row * 64 + o] = d * rstd * g3[o] + be3[o];
    }
}

extern "C" void kernel_launch(void* const* d_in, const int* in_sizes, int n_in,
                              void* d_out, int out_size, void* d_ws, size_t ws_size,
                              hipStream_t stream) {
    const float* query = (const float*)d_in[0];
    const float* adj   = (const float*)d_in[1];
    const float* WF    = (const float*)d_in[2];
    const float* bF    = (const float*)d_in[3];
    const float* WD    = (const float*)d_in[4];
    const float* bD    = (const float*)d_in[5];
    const float* ffw1  = (const float*)d_in[6];
    const float* ffb1  = (const float*)d_in[7];
    const float* ffw2  = (const float*)d_in[8];
    const float* ffb2  = (const float*)d_in[9];
    const float* wq    = (const float*)d_in[10];
    const float* wk    = (const float*)d_in[11];
    const float* wv    = (const float*)d_in[12];
    const float* wo    = (const float*)d_in[13];
    const float* bo    = (const float*)d_in[14];
    const float* g2    = (const float*)d_in[15];
    const float* be2   = (const float*)d_in[16];
    const float* g3    = (const float*)d_in[17];
    const float* be3   = (const float*)d_in[18];
    const float* f1w   = (const float*)d_in[19];
    const float* f1b   = (const float*)d_in[20];
    const float* f2w   = (const float*)d_in[21];
    const float* f2b   = (const float*)d_in[22];
    float* out = (float*)d_out;

    // Arena (floats), total 13,897,984 == round-1 proven workspace usage.
    float* w = (float*)d_ws;
    float* Qcat  = w;                    // 1048576    [N][512]
    float* Qsum  = w + 1048576;          // 131072
    float* Wc    = w + 1179648;          // 4096
    float* bc    = w + 1183744;          // 256 pad
    float* Rsum  = w + 1184000;          // 131072
    float* BigA  = w + 1315072;          // 4194304: Amat -> X1F/X1D/X1FT/X1DT -> qb/kb/vbt -> x1
    float* X2Fb  = w + 5509376;          // 1048576: QcatT -> X2F
    float* TTb   = w + 6557952;          // 4194304: adjT+RmT -> X2D -> tbuf
    float* XFo   = w + 10752256;         // 1048576
    float* XDo   = w + 11800832;         // 1048576 -> ctx
    float* XDF   = w + 12849408;         // 1048576

    float*    Amat  = BigA;
    ushort_t* adjT  = (ushort_t*)TTb;                    // [2048][2048] bf16
    ushort_t* RmT   = (ushort_t*)(TTb + 2097152);        // [2048][2048] bf16
    ushort_t* QcatT = (ushort_t*)X2Fb;                   // [512][2048] bf16
    float*    X1F   = BigA;                              // [2048][512]
    float*    X1D   = BigA + 1048576;
    ushort_t* X1FT  = (ushort_t*)(BigA + 2097152);       // [512][2048] bf16
    ushort_t* X1DT  = (ushort_t*)(BigA + 2621440);
    float*    X2F   = X2Fb;                              // overwrites QcatT (dead)
    float*    X2D   = TTb;                               // overwrites adjT (dead)
    ushort_t* qb    = (ushort_t*)BigA;                   // [32][2048][16] bf16
    ushort_t* kb    = (ushort_t*)(BigA + 524288);        // [32][2048][16] bf16
    ushort_t* vbt   = (ushort_t*)(BigA + 1048576);       // [32][32][2048] bf16 (d-padded)
    float*    ctxb  = XDo;
    float*    x1    = BigA;                              // overwrites qb/kb (dead)
    float*    tbuf  = TTb;

    k_wc<<<16, 256, 0, stream>>>(ffw1, ffb1, ffw2, ffb2, Wc, bc);
    k_qprep<<<512, 256, 0, stream>>>(query, Qcat, Qsum);
    k_rsum<<<512, 256, 0, stream>>>(Qsum, Wc, bc, Rsum);
    k_amat<<<dim3(32, 32), 256, 0, stream>>>(Rsum, Amat);
    k_softmax<<<2048, 256, 0, stream>>>(Amat);

    k_t32to16<<<dim3(32, 32), 256, 0, stream>>>(adj, adjT, NN, NN);
    k_t32to16<<<dim3(32, 32), 256, 0, stream>>>(Amat, RmT, NN, NN);
    k_t32to16<<<dim3(8, 32), 256, 0, stream>>>(Qcat, QcatT, NN, 512);

    // hop1 both branches
    k_hop<<<dim3(8, 32, 2), 256, 0, stream>>>(adjT, RmT, QcatT, QcatT,
                                              X1F, X1D, X1FT, X1DT);
    // hop2 F (needs adjT alive), then hop2 D (X2D overwrites adjT region)
    k_hop<<<dim3(8, 32, 1), 256, 0, stream>>>(adjT, adjT, X1FT, X1FT,
                                              X2F, X2F, nullptr, nullptr);
    k_gcn_out<<<2048, 512, 0, stream>>>(Qcat, X1F, nullptr, X2F, WF, bF, XFo);
    k_hop<<<dim3(8, 32, 1), 256, 0, stream>>>(RmT, RmT, X1DT, X1DT,
                                              X2D, X2D, nullptr, nullptr);
    k_gcn_out<<<2048, 512, 0, stream>>>(Qcat, X1D, nullptr, X2D, WD, bD, XDo);
    k_gate<<<4096, 256, 0, stream>>>(XFo, XDo, XDF);

    k_qkv<<<1024, 256, 0, stream>>>(XDF, wq, wk, wv, qb, kb, vbt);
    k_attn_mf<<<dim3(32, 32), 256, 0, stream>>>(qb, kb, vbt, ctxb);
    k_post1<<<4096, 256, 0, stream>>>(ctxb, XDF, wo, bo, g2, be2, x1);
    k_ffn1<<<512, 256, 0, stream>>>(x1, f1w, f1b, tbuf);
    k_ffn2<<<1024, 256, 0, stream>>>(tbuf, x1, f2w, f2b, g3, be3, out);
}

// Round 7
// 315.858 us; speedup vs baseline: 3.9905x; 1.5138x over previous
//
#include <hip/hip_runtime.h>
#include <math.h>

#define NN 2048
#define BB 8
#define HD 64

typedef __attribute__((ext_vector_type(8))) short bf16x8;
typedef __attribute__((ext_vector_type(4))) float f32x4;
typedef __attribute__((ext_vector_type(16))) float f32x16;
typedef __attribute__((ext_vector_type(4))) unsigned short ushortx4;
typedef unsigned short ushort_t;

static __device__ __forceinline__ float wsum64(float v) {
#pragma unroll
    for (int off = 32; off >= 1; off >>= 1) v += __shfl_xor(v, off);
    return v;
}
static __device__ __forceinline__ float wmax64(float v) {
#pragma unroll
    for (int off = 32; off >= 1; off >>= 1) v = fmaxf(v, __shfl_xor(v, off));
    return v;
}
static __device__ __forceinline__ unsigned short brne(float x) {
    unsigned u = __float_as_uint(x);
    return (unsigned short)((u + 0x7fffu + ((u >> 16) & 1u)) >> 16);
}

#define QSCL 0.36067376022224085f   // log2e / sqrt(16)

// ---------------- weight prep: Wc = ffw2@ffw1, bc; bf16 copies of all MFMA weights ----
__global__ void k_prep(const float* __restrict__ ffw1, const float* __restrict__ ffb1,
                       const float* __restrict__ ffw2, const float* __restrict__ ffb2,
                       const float* __restrict__ WF, const float* __restrict__ WD,
                       const float* __restrict__ wq, const float* __restrict__ wk,
                       const float* __restrict__ wv,
                       const float* __restrict__ f1w, const float* __restrict__ f2w,
                       float* __restrict__ Wc, float* __restrict__ bc,
                       ushort_t* __restrict__ Wfb, ushort_t* __restrict__ Wdb,
                       ushort_t* __restrict__ Wqkvb,
                       ushort_t* __restrict__ f1wb, ushort_t* __restrict__ f2wb) {
    int idx = blockIdx.x * 256 + threadIdx.x;   // 0..16383
    if (idx < 4096) {
        int o = idx >> 6, c = idx & 63;
        float s = 0.f;
        for (int j = 0; j < 384; ++j) s += ffw2[o * 384 + j] * ffw1[j * 64 + c];
        Wc[idx] = s;
    }
    if (idx < 64) {
        float s = ffb2[idx];
        for (int j = 0; j < 384; ++j) s += ffw2[idx * 384 + j] * ffb1[j];
        bc[idx] = s;
    }
    if (idx < 12288) {
        Wfb[idx] = brne(WF[idx]);
        Wdb[idx] = brne(WD[idx]);
        int o = idx >> 6, c = idx & 63;
        float v = o < 64 ? wq[o * 64 + c] * QSCL
                         : (o < 128 ? wk[(o - 64) * 64 + c] : wv[(o - 128) * 64 + c]);
        Wqkvb[idx] = brne(v);
    }
    if (idx < 16384) {
        f1wb[idx] = brne(f1w[idx]);
        f2wb[idx] = brne(f2w[idx]);
    }
}

// ---------------- Qcat[n][b*64+c], Qcatb bf16, Qsum[n][c] = sum_b ----------------
__global__ __launch_bounds__(256) void k_qprep(const float* __restrict__ q,
                                               float* __restrict__ Qcat,
                                               ushort_t* __restrict__ Qcatb,
                                               float* __restrict__ Qsum) {
    int idx = blockIdx.x * 256 + threadIdx.x;   // 0..131071
    int n = idx >> 6, c = idx & 63;
    float s = 0.f;
#pragma unroll
    for (int b = 0; b < BB; ++b) {
        float v = q[((size_t)b * NN + n) * 64 + c];
        s += v;
        Qcat[(size_t)n * 512 + b * 64 + c] = v;
        Qcatb[(size_t)n * 512 + b * 64 + c] = brne(v);
    }
    Qsum[idx] = s;
}

// ---------------- Rsum[n][h] = Qsum[n] . Wc[h] + 8*bc[h] ----------------
__global__ __launch_bounds__(256) void k_rsum(const float* __restrict__ Qsum,
                                              const float* __restrict__ Wc,
                                              const float* __restrict__ bc,
                                              float* __restrict__ Rsum) {
    __shared__ float W[64][65];
    int tid = threadIdx.x;
    for (int i = tid; i < 4096; i += 256) W[i >> 6][i & 63] = Wc[i];
    __syncthreads();
    int idx = blockIdx.x * 256 + tid;
    int n = idx >> 6, h = idx & 63;
    const float* qs = &Qsum[n * 64];
    float s = 8.f * bc[h];
    for (int c = 0; c < 64; ++c) s += qs[c] * W[h][c];
    Rsum[idx] = s;
}

// ---------------- A[n][m] = Rsum[n] . Rsum[m] ----------------
__global__ __launch_bounds__(256) void k_amat(const float* __restrict__ R, float* __restrict__ A) {
    __shared__ float Rn[64][65];
    __shared__ float Rm[64][65];
    int n0 = blockIdx.y * 64, m0 = blockIdx.x * 64;
    int tid = threadIdx.x;
    for (int i = tid; i < 4096; i += 256) {
        int r = i >> 6, c = i & 63;
        Rn[r][c] = R[(n0 + r) * 64 + c];
        Rm[r][c] = R[(m0 + r) * 64 + c];
    }
    __syncthreads();
    int tx = tid & 15, ty = tid >> 4;
    float acc[4][4] = {};
    for (int k = 0; k < 64; ++k) {
        float a[4], b[4];
#pragma unroll
        for (int i = 0; i < 4; ++i) a[i] = Rn[ty * 4 + i][k];
#pragma unroll
        for (int j = 0; j < 4; ++j) b[j] = Rm[tx * 4 + j][k];
#pragma unroll
        for (int i = 0; i < 4; ++i)
#pragma unroll
            for (int j = 0; j < 4; ++j) acc[i][j] += a[i] * b[j];
    }
#pragma unroll
    for (int i = 0; i < 4; ++i)
#pragma unroll
        for (int j = 0; j < 4; ++j)
            A[(size_t)(n0 + ty * 4 + i) * NN + m0 + tx * 4 + j] = acc[i][j];
}

// ---------------- in-place row softmax + identity ----------------
__global__ __launch_bounds__(256) void k_softmax(float* __restrict__ A) {
    __shared__ float red[8];
    int n = blockIdx.x, tid = threadIdx.x;
    float4* row = (float4*)&A[(size_t)n * NN];
    float4 a = row[tid * 2], b = row[tid * 2 + 1];
    float v[8] = {a.x, a.y, a.z, a.w, b.x, b.y, b.z, b.w};
    float mx = v[0];
#pragma unroll
    for (int i = 1; i < 8; ++i) mx = fmaxf(mx, v[i]);
    mx = wmax64(mx);
    int wid = tid >> 6, lane = tid & 63;
    if (lane == 0) red[wid] = mx;
    __syncthreads();
    mx = fmaxf(fmaxf(red[0], red[1]), fmaxf(red[2], red[3]));
    float s = 0.f;
#pragma unroll
    for (int i = 0; i < 8; ++i) { v[i] = exp2f((v[i] - mx) * 1.44269504f); s += v[i]; }
    s = wsum64(s);
    if (lane == 0) red[4 + wid] = s;
    __syncthreads();
    s = red[4] + red[5] + red[6] + red[7];
    float inv = 1.f / s;
    int col = tid * 8;
#pragma unroll
    for (int i = 0; i < 8; ++i) v[i] = v[i] * inv + ((col + i) == n ? 1.f : 0.f);
    row[tid * 2]     = make_float4(v[0], v[1], v[2], v[3]);
    row[tid * 2 + 1] = make_float4(v[4], v[5], v[6], v[7]);
}

// ---------------- transpose + fp32->bf16 ----------------
__global__ __launch_bounds__(256) void k_t32to16(const float* __restrict__ in,
                                                 ushort_t* __restrict__ out,
                                                 int R, int C) {
    __shared__ float tile[64][65];
    int r0 = blockIdx.y * 64, c0 = blockIdx.x * 64;
    int t = threadIdx.x;
    int tr = t >> 6, tc = t & 63;
#pragma unroll
    for (int i = 0; i < 16; ++i) {
        int r = tr + i * 4;
        tile[r][tc] = in[(size_t)(r0 + r) * C + c0 + tc];
    }
    __syncthreads();
#pragma unroll
    for (int i = 0; i < 16; ++i) {
        int cc = tr + i * 4;
        out[(size_t)(c0 + cc) * R + r0 + tc] = brne(tile[tc][cc]);
    }
}

// ---------------- MFMA propagation hop ----------------
// Y[m][j] = sum_k G[k][m] * X[k][j]. Outputs (each optional): fp32 Y [m][512],
// bf16 transposed T [j][2048], bf16 row-major R [m][512].
__global__ __launch_bounds__(256) void k_hop(const ushort_t* __restrict__ G0t,
                                             const ushort_t* __restrict__ G1t,
                                             const ushort_t* __restrict__ B0t,
                                             const ushort_t* __restrict__ B1t,
                                             float* __restrict__ Y0, float* __restrict__ Y1,
                                             ushort_t* __restrict__ T0, ushort_t* __restrict__ T1,
                                             ushort_t* __restrict__ R0, ushort_t* __restrict__ R1) {
    __shared__ __align__(16) ushort_t As[4096];
    __shared__ __align__(16) ushort_t Bs[4096];
    int z = blockIdx.z;
    const ushort_t* Gt = z ? G1t : G0t;
    const ushort_t* Xt = z ? B1t : B0t;
    float* Y = z ? Y1 : Y0;
    ushort_t* T = z ? T1 : T0;
    ushort_t* R = z ? R1 : R0;
    int m0 = blockIdx.y * 64, j0 = blockIdx.x * 64;
    int t = threadIdx.x;
    int srow = t >> 2, scb = (t & 3) * 2;
    int sw = srow & 7;
    const int lane = t & 63, w = t >> 6;
    const int wm = w >> 1, wj = w & 1;
    const int lg = lane >> 4, lr = lane & 15;
    const int ma = wm * 32 + lr, mb = ma + 16;
    const int ja = wj * 32 + lr, jb = ja + 16;
    const int swa = ma & 7, swb = ja & 7;
    f32x4 acc00 = {}, acc01 = {}, acc10 = {}, acc11 = {};
    const size_t gbase = (size_t)(m0 + srow) * NN;
    const size_t xbase = (size_t)(j0 + srow) * NN;
    for (int k0 = 0; k0 < NN; k0 += 64) {
        bf16x8 g0 = *(const bf16x8*)(Gt + gbase + k0 + scb * 8);
        bf16x8 g1 = *(const bf16x8*)(Gt + gbase + k0 + scb * 8 + 8);
        bf16x8 x0 = *(const bf16x8*)(Xt + xbase + k0 + scb * 8);
        bf16x8 x1 = *(const bf16x8*)(Xt + xbase + k0 + scb * 8 + 8);
        __syncthreads();
        *(bf16x8*)&As[srow * 64 + ((scb    ) ^ sw) * 8] = g0;
        *(bf16x8*)&As[srow * 64 + ((scb + 1) ^ sw) * 8] = g1;
        *(bf16x8*)&Bs[srow * 64 + ((scb    ) ^ sw) * 8] = x0;
        *(bf16x8*)&Bs[srow * 64 + ((scb + 1) ^ sw) * 8] = x1;
        __syncthreads();
#pragma unroll
        for (int kk = 0; kk < 2; ++kk) {
            int c = kk * 4 + lg;
            bf16x8 a0 = *(const bf16x8*)&As[ma * 64 + (c ^ swa) * 8];
            bf16x8 a1 = *(const bf16x8*)&As[mb * 64 + (c ^ swa) * 8];
            bf16x8 b0 = *(const bf16x8*)&Bs[ja * 64 + (c ^ swb) * 8];
            bf16x8 b1 = *(const bf16x8*)&Bs[jb * 64 + (c ^ swb) * 8];
            acc00 = __builtin_amdgcn_mfma_f32_16x16x32_bf16(a0, b0, acc00, 0, 0, 0);
            acc01 = __builtin_amdgcn_mfma_f32_16x16x32_bf16(a0, b1, acc01, 0, 0, 0);
            acc10 = __builtin_amdgcn_mfma_f32_16x16x32_bf16(a1, b0, acc10, 0, 0, 0);
            acc11 = __builtin_amdgcn_mfma_f32_16x16x32_bf16(a1, b1, acc11, 0, 0, 0);
        }
    }
    int jA = j0 + wj * 32 + lr;
    int mA = m0 + wm * 32 + lg * 4;
    if (Y) {
#pragma unroll
        for (int r = 0; r < 4; ++r) {
            Y[(size_t)(mA + r) * 512 + jA]           = acc00[r];
            Y[(size_t)(mA + r) * 512 + jA + 16]      = acc01[r];
            Y[(size_t)(mA + 16 + r) * 512 + jA]      = acc10[r];
            Y[(size_t)(mA + 16 + r) * 512 + jA + 16] = acc11[r];
        }
    }
    if (T || R) {
        ushortx4 p0, p1, p2, p3;
#pragma unroll
        for (int r = 0; r < 4; ++r) {
            p0[r] = brne(acc00[r]);
            p1[r] = brne(acc01[r]);
            p2[r] = brne(acc10[r]);
            p3[r] = brne(acc11[r]);
        }
        if (T) {
            *(ushortx4*)&T[(size_t)jA * NN + mA]             = p0;
            *(ushortx4*)&T[(size_t)(jA + 16) * NN + mA]      = p1;
            *(ushortx4*)&T[(size_t)jA * NN + mA + 16]        = p2;
            *(ushortx4*)&T[(size_t)(jA + 16) * NN + mA + 16] = p3;
        }
        if (R) {
#pragma unroll
            for (int r = 0; r < 4; ++r) {
                R[(size_t)(mA + r) * 512 + jA]           = p0[r];
                R[(size_t)(mA + r) * 512 + jA + 16]      = p1[r];
                R[(size_t)(mA + 16 + r) * 512 + jA]      = p2[r];
                R[(size_t)(mA + 16 + r) * 512 + jA + 16] = p3[r];
            }
        }
    }
}

// ---------------- fused GCN 1x1 convs (F,D) + gate -> XDF fp32 + bf16 ----------------
__global__ __launch_bounds__(256) void k_gcnz(const ushort_t* __restrict__ Qcatb,
                                              const ushort_t* __restrict__ X1Fb,
                                              const ushort_t* __restrict__ X2Fb,
                                              const ushort_t* __restrict__ X1Db,
                                              const ushort_t* __restrict__ X2Db,
                                              const ushort_t* __restrict__ Wfb,
                                              const ushort_t* __restrict__ Wdb,
                                              const float* __restrict__ bF,
                                              const float* __restrict__ bD,
                                              float* __restrict__ XDF,
                                              ushort_t* __restrict__ XDFb) {
    __shared__ ushort_t Wl[2][64][200];
    int tid = threadIdx.x;
    for (int i = tid; i < 12288; i += 256) {
        int o = i / 192, k = i % 192;
        Wl[0][o][k] = Wfb[i];
        Wl[1][o][k] = Wdb[i];
    }
    int blk = blockIdx.x;
    int b = blk >> 5, n0 = (blk & 31) * 64;
    int lane = tid & 63, rt = tid >> 6;
    int lr = lane & 15, lg = lane >> 4;
    int nA = n0 + rt * 16 + lr;
    const size_t rb = (size_t)nA * 512 + b * 64 + lg * 8;
    bf16x8 aQ0  = *(const bf16x8*)(Qcatb + rb);
    bf16x8 aQ1  = *(const bf16x8*)(Qcatb + rb + 32);
    bf16x8 a1F0 = *(const bf16x8*)(X1Fb + rb);
    bf16x8 a1F1 = *(const bf16x8*)(X1Fb + rb + 32);
    bf16x8 a2F0 = *(const bf16x8*)(X2Fb + rb);
    bf16x8 a2F1 = *(const bf16x8*)(X2Fb + rb + 32);
    bf16x8 a1D0 = *(const bf16x8*)(X1Db + rb);
    bf16x8 a1D1 = *(const bf16x8*)(X1Db + rb + 32);
    bf16x8 a2D0 = *(const bf16x8*)(X2Db + rb);
    bf16x8 a2D1 = *(const bf16x8*)(X2Db + rb + 32);
    float bFv[4], bDv[4];
#pragma unroll
    for (int ot = 0; ot < 4; ++ot) { bFv[ot] = bF[ot * 16 + lr]; bDv[ot] = bD[ot * 16 + lr]; }
    __syncthreads();
    f32x4 accF[4], accD[4];
#pragma unroll
    for (int ot = 0; ot < 4; ++ot) {
        int o = ot * 16 + lr;
        const ushort_t* wf = &Wl[0][o][lg * 8];
        const ushort_t* wd = &Wl[1][o][lg * 8];
        f32x4 aF = {}, aD = {};
        aF = __builtin_amdgcn_mfma_f32_16x16x32_bf16(aQ0,  *(const bf16x8*)(wf),       aF, 0, 0, 0);
        aF = __builtin_amdgcn_mfma_f32_16x16x32_bf16(aQ1,  *(const bf16x8*)(wf + 32),  aF, 0, 0, 0);
        aF = __builtin_amdgcn_mfma_f32_16x16x32_bf16(a1F0, *(const bf16x8*)(wf + 64),  aF, 0, 0, 0);
        aF = __builtin_amdgcn_mfma_f32_16x16x32_bf16(a1F1, *(const bf16x8*)(wf + 96),  aF, 0, 0, 0);
        aF = __builtin_amdgcn_mfma_f32_16x16x32_bf16(a2F0, *(const bf16x8*)(wf + 128), aF, 0, 0, 0);
        aF = __builtin_amdgcn_mfma_f32_16x16x32_bf16(a2F1, *(const bf16x8*)(wf + 160), aF, 0, 0, 0);
        aD = __builtin_amdgcn_mfma_f32_16x16x32_bf16(aQ0,  *(const bf16x8*)(wd),       aD, 0, 0, 0);
        aD = __builtin_amdgcn_mfma_f32_16x16x32_bf16(aQ1,  *(const bf16x8*)(wd + 32),  aD, 0, 0, 0);
        aD = __builtin_amdgcn_mfma_f32_16x16x32_bf16(a1D0, *(const bf16x8*)(wd + 64),  aD, 0, 0, 0);
        aD = __builtin_amdgcn_mfma_f32_16x16x32_bf16(a1D1, *(const bf16x8*)(wd + 96),  aD, 0, 0, 0);
        aD = __builtin_amdgcn_mfma_f32_16x16x32_bf16(a2D0, *(const bf16x8*)(wd + 128), aD, 0, 0, 0);
        aD = __builtin_amdgcn_mfma_f32_16x16x32_bf16(a2D1, *(const bf16x8*)(wd + 160), aD, 0, 0, 0);
        accF[ot] = aF; accD[ot] = aD;
    }
    const float L2E = 1.44269504f;
#pragma unroll
    for (int ot = 0; ot < 4; ++ot) {
#pragma unroll
        for (int r = 0; r < 4; ++r) {
            float f = accF[ot][r] + bFv[ot];
            float d = accD[ot][r] + bDv[ot];
            float sg = 1.f / (1.f + exp2f(-f * L2E));
            float th = 2.f / (1.f + exp2f(-2.f * d * L2E)) - 1.f;
            float xv = th * sg;
            int nD = n0 + rt * 16 + lg * 4 + r;
            size_t oa = ((size_t)b * NN + nD) * 64 + ot * 16 + lr;
            XDF[oa] = xv;
            XDFb[oa] = brne(xv);
        }
    }
}

// ---------------- MFMA qkv: qb/kb bf16 [bh][N][16] (q pre-scaled), vbt [bh][32][N] ----
__global__ __launch_bounds__(256) void k_qkvm(const ushort_t* __restrict__ XDFb,
                                              const ushort_t* __restrict__ Wqkvb,
                                              ushort_t* __restrict__ qb,
                                              ushort_t* __restrict__ kb,
                                              ushort_t* __restrict__ vbt) {
    __shared__ ushort_t Wl[192][72];
    __shared__ float vt[4][64][17];
    int tid = threadIdx.x;
    for (int i = tid; i < 12288; i += 256) Wl[i >> 6][i & 63] = Wqkvb[i];
    int blk = blockIdx.x;
    size_t row0 = (size_t)blk * 64;
    int b = (int)(row0 >> 11), nbase = (int)(row0 & 2047);
    int lane = tid & 63, rt = tid >> 6;
    int lr = lane & 15, lg = lane >> 4;
    int nl = rt * 16 + lr;
    const ushort_t* xr = XDFb + (row0 + nl) * 64 + lg * 8;
    bf16x8 a0 = *(const bf16x8*)(xr);
    bf16x8 a1 = *(const bf16x8*)(xr + 32);
    __syncthreads();
#pragma unroll
    for (int ot = 0; ot < 12; ++ot) {
        f32x4 acc = {};
        const ushort_t* wp = &Wl[ot * 16 + lr][lg * 8];
        acc = __builtin_amdgcn_mfma_f32_16x16x32_bf16(a0, *(const bf16x8*)(wp),      acc, 0, 0, 0);
        acc = __builtin_amdgcn_mfma_f32_16x16x32_bf16(a1, *(const bf16x8*)(wp + 32), acc, 0, 0, 0);
        int kind = ot >> 2, h = ot & 3;
        int nD = rt * 16 + lg * 4;
        if (kind < 2) {
            ushort_t* dst = (kind == 0 ? qb : kb) + (((size_t)(b * 4 + h) * NN + nbase + nD) * 16 + lr);
#pragma unroll
            for (int r = 0; r < 4; ++r) dst[r * 16] = brne(acc[r]);
        } else {
#pragma unroll
            for (int r = 0; r < 4; ++r) vt[h][nD + r][lr] = acc[r];
        }
    }
    __syncthreads();
    if (tid < 128) {
        int h = tid >> 5, d = (tid >> 1) & 15, half = tid & 1;
        ushort_t* dst = vbt + ((size_t)(b * 4 + h) * 32 + d) * NN + nbase + half * 32;
#pragma unroll
        for (int g = 0; g < 4; ++g) {
            uint4 u;
            int i0 = half * 32 + g * 8;
            u.x = (unsigned)brne(vt[h][i0 + 0][d]) | ((unsigned)brne(vt[h][i0 + 1][d]) << 16);
            u.y = (unsigned)brne(vt[h][i0 + 2][d]) | ((unsigned)brne(vt[h][i0 + 3][d]) << 16);
            u.z = (unsigned)brne(vt[h][i0 + 4][d]) | ((unsigned)brne(vt[h][i0 + 5][d]) << 16);
            u.w = (unsigned)brne(vt[h][i0 + 6][d]) | ((unsigned)brne(vt[h][i0 + 7][d]) << 16);
            ((uint4*)dst)[g] = u;
        }
    } else {
        int t2 = tid - 128;
        int h = t2 >> 5, dz = 16 + ((t2 >> 1) & 15), half = t2 & 1;
        unsigned pv = (dz == 16) ? 0x3F803F80u : 0u;   // row16 = ones (ssum trick)
        uint4 z; z.x = pv; z.y = pv; z.z = pv; z.w = pv;
        ushort_t* dst = vbt + ((size_t)(b * 4 + h) * 32 + dz) * NN + nbase + half * 32;
#pragma unroll
        for (int g = 0; g < 4; ++g) ((uint4*)dst)[g] = z;
    }
}

// ---------------- MFMA flash attention (32x32x16, swapped QK^T, ssum via ones-row) ----
__global__ __launch_bounds__(256) void k_attn_mf(const ushort_t* __restrict__ qb,
                                                 const ushort_t* __restrict__ kb,
                                                 const ushort_t* __restrict__ vbt,
                                                 float* __restrict__ ctx) {
    __shared__ float cpart[4][32][33];
    int bh = blockIdx.y, n0 = blockIdx.x * 64;
    int tid = threadIdx.x, w = tid >> 6, l = tid & 63;
    int lc = l & 31, hi = l >> 5;
    int qsub = w & 1, mhalf = w >> 1;
    const ushort_t* Q  = qb + ((size_t)bh * NN + n0 + qsub * 32) * 16;
    const ushort_t* K  = kb + (size_t)bh * NN * 16;
    const ushort_t* VT = vbt + ((size_t)bh * 32 + lc) * NN;
    bf16x8 qf = *(const bf16x8*)(Q + lc * 16 + hi * 8);
    f32x16 zero = {};
    f32x16 acc = {};
    for (int m0 = mhalf * 32; m0 < NN; m0 += 64) {
        bf16x8 kf = *(const bf16x8*)(K + (size_t)(m0 + lc) * 16 + hi * 8);
        bf16x8 v0 = *(const bf16x8*)(VT + m0 + hi * 8);
        bf16x8 v1 = *(const bf16x8*)(VT + m0 + 16 + hi * 8);
        f32x16 st = __builtin_amdgcn_mfma_f32_32x32x16_bf16(kf, qf, zero, 0, 0, 0);
        float p[16];
#pragma unroll
        for (int r = 0; r < 16; ++r) p[r] = exp2f(st[r]);
        unsigned d[8];
#pragma unroll
        for (int j = 0; j < 8; ++j)
            asm("v_cvt_pk_bf16_f32 %0, %1, %2" : "=v"(d[j]) : "v"(p[2 * j]), "v"(p[2 * j + 1]));
        unsigned s[8];
#pragma unroll
        for (int j = 0; j < 8; ++j) s[j] = (unsigned)__shfl_xor((int)d[j], 32);
        union { bf16x8 v; unsigned u[4]; } fa, fb;
        if (hi == 0) {
            fa.u[0] = d[0]; fa.u[1] = d[1]; fa.u[2] = s[0]; fa.u[3] = s[1];
            fb.u[0] = d[4]; fb.u[1] = d[5]; fb.u[2] = s[4]; fb.u[3] = s[5];
        } else {
            fa.u[0] = s[2]; fa.u[1] = s[3]; fa.u[2] = d[2]; fa.u[3] = d[3];
            fb.u[0] = s[6]; fb.u[1] = s[7]; fb.u[2] = d[6]; fb.u[3] = d[7];
        }
        acc = __builtin_amdgcn_mfma_f32_32x32x16_bf16(fa.v, v0, acc, 0, 0, 0);
        acc = __builtin_amdgcn_mfma_f32_32x32x16_bf16(fb.v, v1, acc, 0, 0, 0);
    }
#pragma unroll
    for (int r = 0; r < 16; ++r)
        cpart[w][(r & 3) + 8 * (r >> 2) + 4 * hi][lc] = acc[r];
    __syncthreads();
    int q = tid >> 2, d4 = (tid & 3) * 4;
    int qs = q >> 5, q32 = q & 31;
    float sst = cpart[qs][q32][16] + cpart[2 + qs][q32][16];
    float inv = 1.f / sst;
    float4 o;
    o.x = (cpart[qs][q32][d4]     + cpart[2 + qs][q32][d4])     * inv;
    o.y = (cpart[qs][q32][d4 + 1] + cpart[2 + qs][q32][d4 + 1]) * inv;
    o.z = (cpart[qs][q32][d4 + 2] + cpart[2 + qs][q32][d4 + 2]) * inv;
    o.w = (cpart[qs][q32][d4 + 3] + cpart[2 + qs][q32][d4 + 3]) * inv;
    int b = bh >> 2, h = bh & 3;
    *(float4*)&ctx[((size_t)b * NN + n0 + q) * 64 + h * 16 + d4] = o;
}

// ---------------- att_out = ctx@wo^T + bo; x = LN(att_out + XDF; g2,be2) ----------------
__global__ __launch_bounds__(256) void k_post1(const float* __restrict__ ctx,
                                               const float* __restrict__ XDF,
                                               const float* __restrict__ wo,
                                               const float* __restrict__ bo,
                                               const float* __restrict__ g2,
                                               const float* __restrict__ be2,
                                               float* __restrict__ xout) {
    __shared__ float W[64][65];
    __shared__ float xs[4][64];
    int tid = threadIdx.x;
    for (int i = tid; i < 4096; i += 256) W[i >> 6][i & 63] = wo[i];
    int row0 = blockIdx.x * 4;
    xs[tid >> 6][tid & 63] = ctx[(size_t)row0 * 64 + tid];
    __syncthreads();
    int r = tid >> 6, o = tid & 63;
    int row = row0 + r;
    const float* x = xs[r];
    float y = bo[o];
    for (int c = 0; c < 64; ++c) y += x[c] * W[o][c];
    y += XDF[(size_t)row * 64 + o];
    float mean = wsum64(y) * (1.f / 64.f);
    float d = y - mean;
    float var = wsum64(d * d) * (1.f / 64.f);
    float rstd = rsqrtf(var + 1e-5f);
    xout[(size_t)row * 64 + o] = d * rstd * g2[o] + be2[o];
}

// ---------------- fused FFN: t=relu(x@W1^T+b1); y=t@W2^T+b2; out=LN(y+x) ----------------
__global__ __launch_bounds__(256) void k_ffn(const float* __restrict__ x,
                                             const ushort_t* __restrict__ f1wb,
                                             const float* __restrict__ f1b,
                                             const ushort_t* __restrict__ f2wb,
                                             const float* __restrict__ f2b,
                                             const float* __restrict__ g3,
                                             const float* __restrict__ be3,
                                             float* __restrict__ out) {
    __shared__ ushort_t xs[64][72];
    __shared__ ushort_t tl[64][264];
    int tid = threadIdx.x;
    size_t row0 = (size_t)blockIdx.x * 64;
    for (int i = tid; i < 1024; i += 256) {
        int r = i >> 4, c4 = (i & 15) * 4;
        float4 v = *(const float4*)&x[(row0 + r) * 64 + c4];
        xs[r][c4] = brne(v.x); xs[r][c4 + 1] = brne(v.y);
        xs[r][c4 + 2] = brne(v.z); xs[r][c4 + 3] = brne(v.w);
    }
    __syncthreads();
    int lane = tid & 63, rt = tid >> 6;
    int lr = lane & 15, lg = lane >> 4;
    bf16x8 a0 = *(const bf16x8*)&xs[rt * 16 + lr][lg * 8];
    bf16x8 a1 = *(const bf16x8*)&xs[rt * 16 + lr][32 + lg * 8];
#pragma unroll
    for (int jt = 0; jt < 16; ++jt) {
        f32x4 acc = {};
        const ushort_t* wp = f1wb + (size_t)(jt * 16 + lr) * 64 + lg * 8;
        acc = __builtin_amdgcn_mfma_f32_16x16x32_bf16(a0, *(const bf16x8*)(wp),      acc, 0, 0, 0);
        acc = __builtin_amdgcn_mfma_f32_16x16x32_bf16(a1, *(const bf16x8*)(wp + 32), acc, 0, 0, 0);
        float bj = f1b[jt * 16 + lr];
#pragma unroll
        for (int r = 0; r < 4; ++r)
            tl[rt * 16 + lg * 4 + r][jt * 16 + lr] = brne(fmaxf(acc[r] + bj, 0.f));
    }
    __syncthreads();
    bf16x8 af[8];
#pragma unroll
    for (int kc = 0; kc < 8; ++kc)
        af[kc] = *(const bf16x8*)&tl[rt * 16 + lr][kc * 32 + lg * 8];
    f32x4 acc2[4];
#pragma unroll
    for (int ot = 0; ot < 4; ++ot) {
        f32x4 a = {};
#pragma unroll
        for (int kc = 0; kc < 8; ++kc) {
            bf16x8 bf = *(const bf16x8*)(f2wb + (size_t)(ot * 16 + lr) * 256 + kc * 32 + lg * 8);
            a = __builtin_amdgcn_mfma_f32_16x16x32_bf16(af[kc], bf, a, 0, 0, 0);
        }
        acc2[ot] = a;
    }
    float g3v[4], be3v[4], f2bv[4];
#pragma unroll
    for (int ot = 0; ot < 4; ++ot) {
        int o = ot * 16 + lr;
        g3v[ot] = g3[o]; be3v[ot] = be3[o]; f2bv[ot] = f2b[o];
    }
#pragma unroll
    for (int r = 0; r < 4; ++r) {
        int rowL = rt * 16 + lg * 4 + r;
        float y[4]; float s = 0.f;
#pragma unroll
        for (int ot = 0; ot < 4; ++ot) {
            y[ot] = acc2[ot][r] + f2bv[ot] + x[(row0 + rowL) * 64 + ot * 16 + lr];
            s += y[ot];
        }
        s += __shfl_xor(s, 1); s += __shfl_xor(s, 2);
        s += __shfl_xor(s, 4); s += __shfl_xor(s, 8);
        float mean = s * (1.f / 64.f);
        float vs = 0.f;
#pragma unroll
        for (int ot = 0; ot < 4; ++ot) { float dd = y[ot] - mean; vs += dd * dd; }
        vs += __shfl_xor(vs, 1); vs += __shfl_xor(vs, 2);
        vs += __shfl_xor(vs, 4); vs += __shfl_xor(vs, 8);
        float rstd = rsqrtf(vs * (1.f / 64.f) + 1e-5f);
#pragma unroll
        for (int ot = 0; ot < 4; ++ot)
            out[(row0 + rowL) * 64 + ot * 16 + lr] = (y[ot] - mean) * rstd * g3v[ot] + be3v[ot];
    }
}

extern "C" void kernel_launch(void* const* d_in, const int* in_sizes, int n_in,
                              void* d_out, int out_size, void* d_ws, size_t ws_size,
                              hipStream_t stream) {
    const float* query = (const float*)d_in[0];
    const float* adj   = (const float*)d_in[1];
    const float* WF    = (const float*)d_in[2];
    const float* bF    = (const float*)d_in[3];
    const float* WD    = (const float*)d_in[4];
    const float* bD    = (const float*)d_in[5];
    const float* ffw1  = (const float*)d_in[6];
    const float* ffb1  = (const float*)d_in[7];
    const float* ffw2  = (const float*)d_in[8];
    const float* ffb2  = (const float*)d_in[9];
    const float* wq    = (const float*)d_in[10];
    const float* wk    = (const float*)d_in[11];
    const float* wv    = (const float*)d_in[12];
    const float* wo    = (const float*)d_in[13];
    const float* bo    = (const float*)d_in[14];
    const float* g2    = (const float*)d_in[15];
    const float* be2   = (const float*)d_in[16];
    const float* g3    = (const float*)d_in[17];
    const float* be3   = (const float*)d_in[18];
    const float* f1w   = (const float*)d_in[19];
    const float* f1b   = (const float*)d_in[20];
    const float* f2w   = (const float*)d_in[21];
    const float* f2b   = (const float*)d_in[22];
    float* out = (float*)d_out;

    // Arena (float units). FIXED round-6 bug: Qcatb is 524,288 floats (was
    // allotted only 262,144 -> X1FT overwrote Qcatb rows n>=1024).
    // Total = 13,408,512 floats < 13,897,984 proven budget.
    float* w = (float*)d_ws;
    float*    Qcat  = w;                                   // 1,048,576 -> qb/kb later
    float*    Qsum  = w + 1048576;                         // 131,072
    float*    Wc    = w + 1179648;                         // 4,096
    float*    bc    = w + 1183744;                         // 256
    ushort_t* Wfb   = (ushort_t*)(w + 1184000);            // 12,288 u16 (6,144 f)
    ushort_t* Wdb   = (ushort_t*)(w + 1190144);
    ushort_t* Wqkvb = (ushort_t*)(w + 1196288);
    ushort_t* f1wb  = (ushort_t*)(w + 1202432);            // 16,384 u16 (8,192 f)
    ushort_t* f2wb  = (ushort_t*)(w + 1210624);
    float*    Rsum  = w + 1218816;                         // 131,072
    float*    Amat  = w + 1349888;                         // 4,194,304 -> vbt/ctx later
    ushort_t* adjT  = (ushort_t*)(w + 5544192);            // 2,097,152 f -> XDF/x1 later
    ushort_t* RmT   = (ushort_t*)(w + 7641344);            // 2,097,152 f -> XDFb later
    ushort_t* QcatT = (ushort_t*)(w + 9738496);            // 524,288 f -> X2Fb later
    ushort_t* Qcatb = (ushort_t*)(w + 10262784);           // 524,288 f  [2048][512] bf16
    ushort_t* X1FT  = (ushort_t*)(w + 10787072);           // 524,288 f  [512][2048] bf16
    ushort_t* X1DT  = (ushort_t*)(w + 11311360);           // 524,288 f
    ushort_t* X1Fb  = (ushort_t*)(w + 11835648);           // 524,288 f  [2048][512] bf16
    ushort_t* X1Db  = (ushort_t*)(w + 12359936);           // 524,288 f
    ushort_t* X2Db  = (ushort_t*)(w + 12884224);           // 524,288 f (ends 13,408,512)
    // reuses:
    ushort_t* X2Fb  = QcatT;                               // QcatT dead after hop1
    ushort_t* qb    = (ushort_t*)Qcat;                     // Qcat fp32 dead after QcatT made
    ushort_t* kb    = (ushort_t*)(Qcat + 524288);
    ushort_t* vbt   = (ushort_t*)Amat;                     // Amat dead after RmT made
    float*    ctxb  = Amat + 1048576;
    float*    XDF   = (float*)adjT;                        // adjT dead after hop2
    float*    x1    = (float*)adjT + 1048576;
    ushort_t* XDFb  = RmT;                                 // RmT dead after hop2

    k_prep<<<64, 256, 0, stream>>>(ffw1, ffb1, ffw2, ffb2, WF, WD, wq, wk, wv, f1w, f2w,
                                   Wc, bc, Wfb, Wdb, Wqkvb, f1wb, f2wb);
    k_qprep<<<512, 256, 0, stream>>>(query, Qcat, Qcatb, Qsum);
    k_rsum<<<512, 256, 0, stream>>>(Qsum, Wc, bc, Rsum);
    k_amat<<<dim3(32, 32), 256, 0, stream>>>(Rsum, Amat);
    k_softmax<<<2048, 256, 0, stream>>>(Amat);

    k_t32to16<<<dim3(32, 32), 256, 0, stream>>>(adj, adjT, NN, NN);
    k_t32to16<<<dim3(32, 32), 256, 0, stream>>>(Amat, RmT, NN, NN);
    k_t32to16<<<dim3(8, 32), 256, 0, stream>>>(Qcat, QcatT, NN, 512);

    // hop1: T (for hop2) + R (bf16 row-major for gcnz); no fp32
    k_hop<<<dim3(8, 32, 2), 256, 0, stream>>>(adjT, RmT, QcatT, QcatT,
                                              nullptr, nullptr, X1FT, X1DT, X1Fb, X1Db);
    // hop2 both branches: R only
    k_hop<<<dim3(8, 32, 2), 256, 0, stream>>>(adjT, RmT, X1FT, X1DT,
                                              nullptr, nullptr, nullptr, nullptr, X2Fb, X2Db);

    k_gcnz<<<256, 256, 0, stream>>>(Qcatb, X1Fb, X2Fb, X1Db, X2Db, Wfb, Wdb, bF, bD,
                                    XDF, XDFb);
    k_qkvm<<<256, 256, 0, stream>>>(XDFb, Wqkvb, qb, kb, vbt);
    k_attn_mf<<<dim3(32, 32), 256, 0, stream>>>(qb, kb, vbt, ctxb);
    k_post1<<<4096, 256, 0, stream>>>(ctxb, XDF, wo, bo, g2, be2, x1);
    k_ffn<<<256, 256, 0, stream>>>(x1, f1wb, f1b, f2wb, f2b, g3, be3, out);
}

// Round 8
// 292.252 us; speedup vs baseline: 4.3128x; 1.0808x over previous
//
#include <hip/hip_runtime.h>
#include <math.h>

#define NN 2048
#define BB 8
#define HD 64

typedef __attribute__((ext_vector_type(8))) short bf16x8;
typedef __attribute__((ext_vector_type(4))) float f32x4;
typedef __attribute__((ext_vector_type(16))) float f32x16;
typedef __attribute__((ext_vector_type(4))) unsigned short ushortx4;
typedef unsigned short ushort_t;

static __device__ __forceinline__ float wsum64(float v) {
#pragma unroll
    for (int off = 32; off >= 1; off >>= 1) v += __shfl_xor(v, off);
    return v;
}
static __device__ __forceinline__ float wmax64(float v) {
#pragma unroll
    for (int off = 32; off >= 1; off >>= 1) v = fmaxf(v, __shfl_xor(v, off));
    return v;
}
static __device__ __forceinline__ unsigned short brne(float x) {
    unsigned u = __float_as_uint(x);
    return (unsigned short)((u + 0x7fffu + ((u >> 16) & 1u)) >> 16);
}

#define QSCL 0.36067376022224085f   // log2e / sqrt(16)

// ---------------- weight prep ----------------
__global__ void k_prep(const float* __restrict__ ffw1, const float* __restrict__ ffb1,
                       const float* __restrict__ ffw2, const float* __restrict__ ffb2,
                       const float* __restrict__ WF, const float* __restrict__ WD,
                       const float* __restrict__ wq, const float* __restrict__ wk,
                       const float* __restrict__ wv, const float* __restrict__ wo,
                       const float* __restrict__ f1w, const float* __restrict__ f2w,
                       float* __restrict__ Wc, float* __restrict__ bc,
                       ushort_t* __restrict__ Wfb, ushort_t* __restrict__ Wdb,
                       ushort_t* __restrict__ Wqkvb, ushort_t* __restrict__ wob,
                       ushort_t* __restrict__ f1wb, ushort_t* __restrict__ f2wb) {
    int idx = blockIdx.x * 256 + threadIdx.x;   // 0..16383
    if (idx < 4096) {
        int o = idx >> 6, c = idx & 63;
        float s = 0.f;
        for (int j = 0; j < 384; ++j) s += ffw2[o * 384 + j] * ffw1[j * 64 + c];
        Wc[idx] = s;
        wob[idx] = brne(wo[idx]);
    }
    if (idx < 64) {
        float s = ffb2[idx];
        for (int j = 0; j < 384; ++j) s += ffw2[idx * 384 + j] * ffb1[j];
        bc[idx] = s;
    }
    if (idx < 12288) {
        Wfb[idx] = brne(WF[idx]);
        Wdb[idx] = brne(WD[idx]);
        int o = idx >> 6, c = idx & 63;
        float v = o < 64 ? wq[o * 64 + c] * QSCL
                         : (o < 128 ? wk[(o - 64) * 64 + c] : wv[(o - 128) * 64 + c]);
        Wqkvb[idx] = brne(v);
    }
    if (idx < 16384) {
        f1wb[idx] = brne(f1w[idx]);
        f2wb[idx] = brne(f2w[idx]);
    }
}

// ---------------- Qcat[n][b*64+c], Qcatb bf16, Qsum[n][c] = sum_b ----------------
__global__ __launch_bounds__(256) void k_qprep(const float* __restrict__ q,
                                               float* __restrict__ Qcat,
                                               ushort_t* __restrict__ Qcatb,
                                               float* __restrict__ Qsum) {
    int idx = blockIdx.x * 256 + threadIdx.x;   // 0..131071
    int n = idx >> 6, c = idx & 63;
    float s = 0.f;
#pragma unroll
    for (int b = 0; b < BB; ++b) {
        float v = q[((size_t)b * NN + n) * 64 + c];
        s += v;
        Qcat[(size_t)n * 512 + b * 64 + c] = v;
        Qcatb[(size_t)n * 512 + b * 64 + c] = brne(v);
    }
    Qsum[idx] = s;
}

// ---------------- Rsumb[n][h] = bf16(Qsum[n] . Wc[h] + 8*bc[h]) ----------------
__global__ __launch_bounds__(256) void k_rsum(const float* __restrict__ Qsum,
                                              const float* __restrict__ Wc,
                                              const float* __restrict__ bc,
                                              ushort_t* __restrict__ Rsumb) {
    __shared__ float W[64][65];
    int tid = threadIdx.x;
    for (int i = tid; i < 4096; i += 256) W[i >> 6][i & 63] = Wc[i];
    __syncthreads();
    int idx = blockIdx.x * 256 + tid;
    int n = idx >> 6, h = idx & 63;
    const float* qs = &Qsum[n * 64];
    float s = 8.f * bc[h];
    for (int c = 0; c < 64; ++c) s += qs[c] * W[h][c];
    Rsumb[idx] = brne(s);
}

// ---------------- A[n][m] = Rsumb[n] . Rsumb[m]  (MFMA, K=64) ----------------
__global__ __launch_bounds__(256) void k_amat_m(const ushort_t* __restrict__ Rb,
                                                float* __restrict__ A) {
    __shared__ __align__(16) ushort_t As[4096];
    __shared__ __align__(16) ushort_t Bs[4096];
    int n0 = blockIdx.y * 64, m0 = blockIdx.x * 64;
    int t = threadIdx.x;
    int srow = t >> 2, scb = (t & 3) * 2;
    int sw = srow & 7;
    const int lane = t & 63, w = t >> 6;
    const int wm = w >> 1, wj = w & 1;
    const int lg = lane >> 4, lr = lane & 15;
    const int ma = wm * 32 + lr, mb = ma + 16;
    const int ja = wj * 32 + lr, jb = ja + 16;
    const int swa = ma & 7, swb = ja & 7;
    bf16x8 g0 = *(const bf16x8*)(Rb + (size_t)(n0 + srow) * 64 + scb * 8);
    bf16x8 g1 = *(const bf16x8*)(Rb + (size_t)(n0 + srow) * 64 + scb * 8 + 8);
    bf16x8 x0 = *(const bf16x8*)(Rb + (size_t)(m0 + srow) * 64 + scb * 8);
    bf16x8 x1 = *(const bf16x8*)(Rb + (size_t)(m0 + srow) * 64 + scb * 8 + 8);
    *(bf16x8*)&As[srow * 64 + ((scb    ) ^ sw) * 8] = g0;
    *(bf16x8*)&As[srow * 64 + ((scb + 1) ^ sw) * 8] = g1;
    *(bf16x8*)&Bs[srow * 64 + ((scb    ) ^ sw) * 8] = x0;
    *(bf16x8*)&Bs[srow * 64 + ((scb + 1) ^ sw) * 8] = x1;
    __syncthreads();
    f32x4 acc00 = {}, acc01 = {}, acc10 = {}, acc11 = {};
#pragma unroll
    for (int kk = 0; kk < 2; ++kk) {
        int c = kk * 4 + lg;
        bf16x8 a0 = *(const bf16x8*)&As[ma * 64 + (c ^ swa) * 8];
        bf16x8 a1 = *(const bf16x8*)&As[mb * 64 + (c ^ swa) * 8];
        bf16x8 b0 = *(const bf16x8*)&Bs[ja * 64 + (c ^ swb) * 8];
        bf16x8 b1 = *(const bf16x8*)&Bs[jb * 64 + (c ^ swb) * 8];
        acc00 = __builtin_amdgcn_mfma_f32_16x16x32_bf16(a0, b0, acc00, 0, 0, 0);
        acc01 = __builtin_amdgcn_mfma_f32_16x16x32_bf16(a0, b1, acc01, 0, 0, 0);
        acc10 = __builtin_amdgcn_mfma_f32_16x16x32_bf16(a1, b0, acc10, 0, 0, 0);
        acc11 = __builtin_amdgcn_mfma_f32_16x16x32_bf16(a1, b1, acc11, 0, 0, 0);
    }
    int jA = m0 + wj * 32 + lr;
    int nA = n0 + wm * 32 + lg * 4;
#pragma unroll
    for (int r = 0; r < 4; ++r) {
        A[(size_t)(nA + r) * NN + jA]           = acc00[r];
        A[(size_t)(nA + r) * NN + jA + 16]      = acc01[r];
        A[(size_t)(nA + 16 + r) * NN + jA]      = acc10[r];
        A[(size_t)(nA + 16 + r) * NN + jA + 16] = acc11[r];
    }
}

// ---------------- in-place row softmax + identity ----------------
__global__ __launch_bounds__(256) void k_softmax(float* __restrict__ A) {
    __shared__ float red[8];
    int n = blockIdx.x, tid = threadIdx.x;
    float4* row = (float4*)&A[(size_t)n * NN];
    float4 a = row[tid * 2], b = row[tid * 2 + 1];
    float v[8] = {a.x, a.y, a.z, a.w, b.x, b.y, b.z, b.w};
    float mx = v[0];
#pragma unroll
    for (int i = 1; i < 8; ++i) mx = fmaxf(mx, v[i]);
    mx = wmax64(mx);
    int wid = tid >> 6, lane = tid & 63;
    if (lane == 0) red[wid] = mx;
    __syncthreads();
    mx = fmaxf(fmaxf(red[0], red[1]), fmaxf(red[2], red[3]));
    float s = 0.f;
#pragma unroll
    for (int i = 0; i < 8; ++i) { v[i] = exp2f((v[i] - mx) * 1.44269504f); s += v[i]; }
    s = wsum64(s);
    if (lane == 0) red[4 + wid] = s;
    __syncthreads();
    s = red[4] + red[5] + red[6] + red[7];
    float inv = 1.f / s;
    int col = tid * 8;
#pragma unroll
    for (int i = 0; i < 8; ++i) v[i] = v[i] * inv + ((col + i) == n ? 1.f : 0.f);
    row[tid * 2]     = make_float4(v[0], v[1], v[2], v[3]);
    row[tid * 2 + 1] = make_float4(v[4], v[5], v[6], v[7]);
}

// ---------------- transpose + fp32->bf16 ----------------
__global__ __launch_bounds__(256) void k_t32to16(const float* __restrict__ in,
                                                 ushort_t* __restrict__ out,
                                                 int R, int C) {
    __shared__ float tile[64][65];
    int r0 = blockIdx.y * 64, c0 = blockIdx.x * 64;
    int t = threadIdx.x;
    int tr = t >> 6, tc = t & 63;
#pragma unroll
    for (int i = 0; i < 16; ++i) {
        int r = tr + i * 4;
        tile[r][tc] = in[(size_t)(r0 + r) * C + c0 + tc];
    }
    __syncthreads();
#pragma unroll
    for (int i = 0; i < 16; ++i) {
        int cc = tr + i * 4;
        out[(size_t)(c0 + cc) * R + r0 + tc] = brne(tile[tc][cc]);
    }
}

// ---------------- MFMA propagation hop ----------------
__global__ __launch_bounds__(256) void k_hop(const ushort_t* __restrict__ G0t,
                                             const ushort_t* __restrict__ G1t,
                                             const ushort_t* __restrict__ B0t,
                                             const ushort_t* __restrict__ B1t,
                                             float* __restrict__ Y0, float* __restrict__ Y1,
                                             ushort_t* __restrict__ T0, ushort_t* __restrict__ T1,
                                             ushort_t* __restrict__ R0, ushort_t* __restrict__ R1) {
    __shared__ __align__(16) ushort_t As[4096];
    __shared__ __align__(16) ushort_t Bs[4096];
    int z = blockIdx.z;
    const ushort_t* Gt = z ? G1t : G0t;
    const ushort_t* Xt = z ? B1t : B0t;
    float* Y = z ? Y1 : Y0;
    ushort_t* T = z ? T1 : T0;
    ushort_t* R = z ? R1 : R0;
    int m0 = blockIdx.y * 64, j0 = blockIdx.x * 64;
    int t = threadIdx.x;
    int srow = t >> 2, scb = (t & 3) * 2;
    int sw = srow & 7;
    const int lane = t & 63, w = t >> 6;
    const int wm = w >> 1, wj = w & 1;
    const int lg = lane >> 4, lr = lane & 15;
    const int ma = wm * 32 + lr, mb = ma + 16;
    const int ja = wj * 32 + lr, jb = ja + 16;
    const int swa = ma & 7, swb = ja & 7;
    f32x4 acc00 = {}, acc01 = {}, acc10 = {}, acc11 = {};
    const size_t gbase = (size_t)(m0 + srow) * NN;
    const size_t xbase = (size_t)(j0 + srow) * NN;
    for (int k0 = 0; k0 < NN; k0 += 64) {
        bf16x8 g0 = *(const bf16x8*)(Gt + gbase + k0 + scb * 8);
        bf16x8 g1 = *(const bf16x8*)(Gt + gbase + k0 + scb * 8 + 8);
        bf16x8 x0 = *(const bf16x8*)(Xt + xbase + k0 + scb * 8);
        bf16x8 x1 = *(const bf16x8*)(Xt + xbase + k0 + scb * 8 + 8);
        __syncthreads();
        *(bf16x8*)&As[srow * 64 + ((scb    ) ^ sw) * 8] = g0;
        *(bf16x8*)&As[srow * 64 + ((scb + 1) ^ sw) * 8] = g1;
        *(bf16x8*)&Bs[srow * 64 + ((scb    ) ^ sw) * 8] = x0;
        *(bf16x8*)&Bs[srow * 64 + ((scb + 1) ^ sw) * 8] = x1;
        __syncthreads();
#pragma unroll
        for (int kk = 0; kk < 2; ++kk) {
            int c = kk * 4 + lg;
            bf16x8 a0 = *(const bf16x8*)&As[ma * 64 + (c ^ swa) * 8];
            bf16x8 a1 = *(const bf16x8*)&As[mb * 64 + (c ^ swa) * 8];
            bf16x8 b0 = *(const bf16x8*)&Bs[ja * 64 + (c ^ swb) * 8];
            bf16x8 b1 = *(const bf16x8*)&Bs[jb * 64 + (c ^ swb) * 8];
            acc00 = __builtin_amdgcn_mfma_f32_16x16x32_bf16(a0, b0, acc00, 0, 0, 0);
            acc01 = __builtin_amdgcn_mfma_f32_16x16x32_bf16(a0, b1, acc01, 0, 0, 0);
            acc10 = __builtin_amdgcn_mfma_f32_16x16x32_bf16(a1, b0, acc10, 0, 0, 0);
            acc11 = __builtin_amdgcn_mfma_f32_16x16x32_bf16(a1, b1, acc11, 0, 0, 0);
        }
    }
    int jA = j0 + wj * 32 + lr;
    int mA = m0 + wm * 32 + lg * 4;
    if (Y) {
#pragma unroll
        for (int r = 0; r < 4; ++r) {
            Y[(size_t)(mA + r) * 512 + jA]           = acc00[r];
            Y[(size_t)(mA + r) * 512 + jA + 16]      = acc01[r];
            Y[(size_t)(mA + 16 + r) * 512 + jA]      = acc10[r];
            Y[(size_t)(mA + 16 + r) * 512 + jA + 16] = acc11[r];
        }
    }
    if (T || R) {
        ushortx4 p0, p1, p2, p3;
#pragma unroll
        for (int r = 0; r < 4; ++r) {
            p0[r] = brne(acc00[r]);
            p1[r] = brne(acc01[r]);
            p2[r] = brne(acc10[r]);
            p3[r] = brne(acc11[r]);
        }
        if (T) {
            *(ushortx4*)&T[(size_t)jA * NN + mA]             = p0;
            *(ushortx4*)&T[(size_t)(jA + 16) * NN + mA]      = p1;
            *(ushortx4*)&T[(size_t)jA * NN + mA + 16]        = p2;
            *(ushortx4*)&T[(size_t)(jA + 16) * NN + mA + 16] = p3;
        }
        if (R) {
#pragma unroll
            for (int r = 0; r < 4; ++r) {
                R[(size_t)(mA + r) * 512 + jA]           = p0[r];
                R[(size_t)(mA + r) * 512 + jA + 16]      = p1[r];
                R[(size_t)(mA + 16 + r) * 512 + jA]      = p2[r];
                R[(size_t)(mA + 16 + r) * 512 + jA + 16] = p3[r];
            }
        }
    }
}

// ---------------- fused GCN 1x1 convs (F,D) + gate -> XDF fp32 + bf16 ----------------
__global__ __launch_bounds__(256) void k_gcnz(const ushort_t* __restrict__ Qcatb,
                                              const ushort_t* __restrict__ X1Fb,
                                              const ushort_t* __restrict__ X2Fb,
                                              const ushort_t* __restrict__ X1Db,
                                              const ushort_t* __restrict__ X2Db,
                                              const ushort_t* __restrict__ Wfb,
                                              const ushort_t* __restrict__ Wdb,
                                              const float* __restrict__ bF,
                                              const float* __restrict__ bD,
                                              float* __restrict__ XDF,
                                              ushort_t* __restrict__ XDFb) {
    __shared__ ushort_t Wl[2][64][200];
    int tid = threadIdx.x;
    for (int i = tid; i < 12288; i += 256) {
        int o = i / 192, k = i % 192;
        Wl[0][o][k] = Wfb[i];
        Wl[1][o][k] = Wdb[i];
    }
    int blk = blockIdx.x;
    int b = blk >> 5, n0 = (blk & 31) * 64;
    int lane = tid & 63, rt = tid >> 6;
    int lr = lane & 15, lg = lane >> 4;
    int nA = n0 + rt * 16 + lr;
    const size_t rb = (size_t)nA * 512 + b * 64 + lg * 8;
    bf16x8 aQ0  = *(const bf16x8*)(Qcatb + rb);
    bf16x8 aQ1  = *(const bf16x8*)(Qcatb + rb + 32);
    bf16x8 a1F0 = *(const bf16x8*)(X1Fb + rb);
    bf16x8 a1F1 = *(const bf16x8*)(X1Fb + rb + 32);
    bf16x8 a2F0 = *(const bf16x8*)(X2Fb + rb);
    bf16x8 a2F1 = *(const bf16x8*)(X2Fb + rb + 32);
    bf16x8 a1D0 = *(const bf16x8*)(X1Db + rb);
    bf16x8 a1D1 = *(const bf16x8*)(X1Db + rb + 32);
    bf16x8 a2D0 = *(const bf16x8*)(X2Db + rb);
    bf16x8 a2D1 = *(const bf16x8*)(X2Db + rb + 32);
    float bFv[4], bDv[4];
#pragma unroll
    for (int ot = 0; ot < 4; ++ot) { bFv[ot] = bF[ot * 16 + lr]; bDv[ot] = bD[ot * 16 + lr]; }
    __syncthreads();
    f32x4 accF[4], accD[4];
#pragma unroll
    for (int ot = 0; ot < 4; ++ot) {
        int o = ot * 16 + lr;
        const ushort_t* wf = &Wl[0][o][lg * 8];
        const ushort_t* wd = &Wl[1][o][lg * 8];
        f32x4 aF = {}, aD = {};
        aF = __builtin_amdgcn_mfma_f32_16x16x32_bf16(aQ0,  *(const bf16x8*)(wf),       aF, 0, 0, 0);
        aF = __builtin_amdgcn_mfma_f32_16x16x32_bf16(aQ1,  *(const bf16x8*)(wf + 32),  aF, 0, 0, 0);
        aF = __builtin_amdgcn_mfma_f32_16x16x32_bf16(a1F0, *(const bf16x8*)(wf + 64),  aF, 0, 0, 0);
        aF = __builtin_amdgcn_mfma_f32_16x16x32_bf16(a1F1, *(const bf16x8*)(wf + 96),  aF, 0, 0, 0);
        aF = __builtin_amdgcn_mfma_f32_16x16x32_bf16(a2F0, *(const bf16x8*)(wf + 128), aF, 0, 0, 0);
        aF = __builtin_amdgcn_mfma_f32_16x16x32_bf16(a2F1, *(const bf16x8*)(wf + 160), aF, 0, 0, 0);
        aD = __builtin_amdgcn_mfma_f32_16x16x32_bf16(aQ0,  *(const bf16x8*)(wd),       aD, 0, 0, 0);
        aD = __builtin_amdgcn_mfma_f32_16x16x32_bf16(aQ1,  *(const bf16x8*)(wd + 32),  aD, 0, 0, 0);
        aD = __builtin_amdgcn_mfma_f32_16x16x32_bf16(a1D0, *(const bf16x8*)(wd + 64),  aD, 0, 0, 0);
        aD = __builtin_amdgcn_mfma_f32_16x16x32_bf16(a1D1, *(const bf16x8*)(wd + 96),  aD, 0, 0, 0);
        aD = __builtin_amdgcn_mfma_f32_16x16x32_bf16(a2D0, *(const bf16x8*)(wd + 128), aD, 0, 0, 0);
        aD = __builtin_amdgcn_mfma_f32_16x16x32_bf16(a2D1, *(const bf16x8*)(wd + 160), aD, 0, 0, 0);
        accF[ot] = aF; accD[ot] = aD;
    }
    const float L2E = 1.44269504f;
#pragma unroll
    for (int ot = 0; ot < 4; ++ot) {
#pragma unroll
        for (int r = 0; r < 4; ++r) {
            float f = accF[ot][r] + bFv[ot];
            float d = accD[ot][r] + bDv[ot];
            float sg = 1.f / (1.f + exp2f(-f * L2E));
            float th = 2.f / (1.f + exp2f(-2.f * d * L2E)) - 1.f;
            float xv = th * sg;
            int nD = n0 + rt * 16 + lg * 4 + r;
            size_t oa = ((size_t)b * NN + nD) * 64 + ot * 16 + lr;
            XDF[oa] = xv;
            XDFb[oa] = brne(xv);
        }
    }
}

// ---------------- MFMA qkv ----------------
__global__ __launch_bounds__(256) void k_qkvm(const ushort_t* __restrict__ XDFb,
                                              const ushort_t* __restrict__ Wqkvb,
                                              ushort_t* __restrict__ qb,
                                              ushort_t* __restrict__ kb,
                                              ushort_t* __restrict__ vbt) {
    __shared__ ushort_t Wl[192][72];
    __shared__ float vt[4][64][17];
    int tid = threadIdx.x;
    for (int i = tid; i < 12288; i += 256) Wl[i >> 6][i & 63] = Wqkvb[i];
    int blk = blockIdx.x;
    size_t row0 = (size_t)blk * 64;
    int b = (int)(row0 >> 11), nbase = (int)(row0 & 2047);
    int lane = tid & 63, rt = tid >> 6;
    int lr = lane & 15, lg = lane >> 4;
    int nl = rt * 16 + lr;
    const ushort_t* xr = XDFb + (row0 + nl) * 64 + lg * 8;
    bf16x8 a0 = *(const bf16x8*)(xr);
    bf16x8 a1 = *(const bf16x8*)(xr + 32);
    __syncthreads();
#pragma unroll
    for (int ot = 0; ot < 12; ++ot) {
        f32x4 acc = {};
        const ushort_t* wp = &Wl[ot * 16 + lr][lg * 8];
        acc = __builtin_amdgcn_mfma_f32_16x16x32_bf16(a0, *(const bf16x8*)(wp),      acc, 0, 0, 0);
        acc = __builtin_amdgcn_mfma_f32_16x16x32_bf16(a1, *(const bf16x8*)(wp + 32), acc, 0, 0, 0);
        int kind = ot >> 2, h = ot & 3;
        int nD = rt * 16 + lg * 4;
        if (kind < 2) {
            ushort_t* dst = (kind == 0 ? qb : kb) + (((size_t)(b * 4 + h) * NN + nbase + nD) * 16 + lr);
#pragma unroll
            for (int r = 0; r < 4; ++r) dst[r * 16] = brne(acc[r]);
        } else {
#pragma unroll
            for (int r = 0; r < 4; ++r) vt[h][nD + r][lr] = acc[r];
        }
    }
    __syncthreads();
    if (tid < 128) {
        int h = tid >> 5, d = (tid >> 1) & 15, half = tid & 1;
        ushort_t* dst = vbt + ((size_t)(b * 4 + h) * 32 + d) * NN + nbase + half * 32;
#pragma unroll
        for (int g = 0; g < 4; ++g) {
            uint4 u;
            int i0 = half * 32 + g * 8;
            u.x = (unsigned)brne(vt[h][i0 + 0][d]) | ((unsigned)brne(vt[h][i0 + 1][d]) << 16);
            u.y = (unsigned)brne(vt[h][i0 + 2][d]) | ((unsigned)brne(vt[h][i0 + 3][d]) << 16);
            u.z = (unsigned)brne(vt[h][i0 + 4][d]) | ((unsigned)brne(vt[h][i0 + 5][d]) << 16);
            u.w = (unsigned)brne(vt[h][i0 + 6][d]) | ((unsigned)brne(vt[h][i0 + 7][d]) << 16);
            ((uint4*)dst)[g] = u;
        }
    } else {
        int t2 = tid - 128;
        int h = t2 >> 5, dz = 16 + ((t2 >> 1) & 15), half = t2 & 1;
        unsigned pv = (dz == 16) ? 0x3F803F80u : 0u;   // row16 = ones (ssum trick)
        uint4 z; z.x = pv; z.y = pv; z.z = pv; z.w = pv;
        ushort_t* dst = vbt + ((size_t)(b * 4 + h) * 32 + dz) * NN + nbase + half * 32;
#pragma unroll
        for (int g = 0; g < 4; ++g) ((uint4*)dst)[g] = z;
    }
}

// ---------------- MFMA flash attention -> ctx bf16 ----------------
__global__ __launch_bounds__(256) void k_attn_mf(const ushort_t* __restrict__ qb,
                                                 const ushort_t* __restrict__ kb,
                                                 const ushort_t* __restrict__ vbt,
                                                 ushort_t* __restrict__ ctx) {
    __shared__ float cpart[4][32][33];
    int bh = blockIdx.y, n0 = blockIdx.x * 64;
    int tid = threadIdx.x, w = tid >> 6, l = tid & 63;
    int lc = l & 31, hi = l >> 5;
    int qsub = w & 1, mhalf = w >> 1;
    const ushort_t* Q  = qb + ((size_t)bh * NN + n0 + qsub * 32) * 16;
    const ushort_t* K  = kb + (size_t)bh * NN * 16;
    const ushort_t* VT = vbt + ((size_t)bh * 32 + lc) * NN;
    bf16x8 qf = *(const bf16x8*)(Q + lc * 16 + hi * 8);
    f32x16 zero = {};
    f32x16 acc = {};
    for (int m0 = mhalf * 32; m0 < NN; m0 += 64) {
        bf16x8 kf = *(const bf16x8*)(K + (size_t)(m0 + lc) * 16 + hi * 8);
        bf16x8 v0 = *(const bf16x8*)(VT + m0 + hi * 8);
        bf16x8 v1 = *(const bf16x8*)(VT + m0 + 16 + hi * 8);
        f32x16 st = __builtin_amdgcn_mfma_f32_32x32x16_bf16(kf, qf, zero, 0, 0, 0);
        float p[16];
#pragma unroll
        for (int r = 0; r < 16; ++r) p[r] = exp2f(st[r]);
        unsigned d[8];
#pragma unroll
        for (int j = 0; j < 8; ++j)
            asm("v_cvt_pk_bf16_f32 %0, %1, %2" : "=v"(d[j]) : "v"(p[2 * j]), "v"(p[2 * j + 1]));
        // cross-half exchange: one shfl covers both halves' needs via pre-select
        unsigned z0 = hi ? d[0] : d[2];
        unsigned z1 = hi ? d[1] : d[3];
        unsigned z2 = hi ? d[4] : d[6];
        unsigned z3 = hi ? d[5] : d[7];
        unsigned r0 = (unsigned)__shfl_xor((int)z0, 32);
        unsigned r1 = (unsigned)__shfl_xor((int)z1, 32);
        unsigned r2 = (unsigned)__shfl_xor((int)z2, 32);
        unsigned r3 = (unsigned)__shfl_xor((int)z3, 32);
        union { bf16x8 v; unsigned u[4]; } fa, fb;
        if (hi == 0) {
            fa.u[0] = d[0]; fa.u[1] = d[1]; fa.u[2] = r0; fa.u[3] = r1;
            fb.u[0] = d[4]; fb.u[1] = d[5]; fb.u[2] = r2; fb.u[3] = r3;
        } else {
            fa.u[0] = r0; fa.u[1] = r1; fa.u[2] = d[2]; fa.u[3] = d[3];
            fb.u[0] = r2; fb.u[1] = r3; fb.u[2] = d[6]; fb.u[3] = d[7];
        }
        acc = __builtin_amdgcn_mfma_f32_32x32x16_bf16(fa.v, v0, acc, 0, 0, 0);
        acc = __builtin_amdgcn_mfma_f32_32x32x16_bf16(fb.v, v1, acc, 0, 0, 0);
    }
#pragma unroll
    for (int r = 0; r < 16; ++r)
        cpart[w][(r & 3) + 8 * (r >> 2) + 4 * hi][lc] = acc[r];
    __syncthreads();
    int q = tid >> 2, d4 = (tid & 3) * 4;
    int qs = q >> 5, q32 = q & 31;
    float sst = cpart[qs][q32][16] + cpart[2 + qs][q32][16];
    float inv = 1.f / sst;
    ushortx4 ob;
    ob[0] = brne((cpart[qs][q32][d4]     + cpart[2 + qs][q32][d4])     * inv);
    ob[1] = brne((cpart[qs][q32][d4 + 1] + cpart[2 + qs][q32][d4 + 1]) * inv);
    ob[2] = brne((cpart[qs][q32][d4 + 2] + cpart[2 + qs][q32][d4 + 2]) * inv);
    ob[3] = brne((cpart[qs][q32][d4 + 3] + cpart[2 + qs][q32][d4 + 3]) * inv);
    int b = bh >> 2, h = bh & 3;
    *(ushortx4*)&ctx[((size_t)b * NN + n0 + q) * 64 + h * 16 + d4] = ob;
}

// ---------------- fused tail: x1 = LN(ctx@wo^T + bo + XDF); FFN; out = LN ----------------
__global__ __launch_bounds__(256) void k_tail(const ushort_t* __restrict__ ctxb,
                                              const float* __restrict__ XDF,
                                              const ushort_t* __restrict__ wob,
                                              const float* __restrict__ bo,
                                              const float* __restrict__ g2,
                                              const float* __restrict__ be2,
                                              const ushort_t* __restrict__ f1wb,
                                              const float* __restrict__ f1b,
                                              const ushort_t* __restrict__ f2wb,
                                              const float* __restrict__ f2b,
                                              const float* __restrict__ g3,
                                              const float* __restrict__ be3,
                                              float* __restrict__ out) {
    __shared__ ushort_t xs[64][72];
    __shared__ ushort_t tl[64][264];
    int tid = threadIdx.x;
    size_t row0 = (size_t)blockIdx.x * 64;
    int lane = tid & 63, rt = tid >> 6;
    int lr = lane & 15, lg = lane >> 4;
    // stage 1: att_out + residual + LN
    const ushort_t* cr = ctxb + (row0 + rt * 16 + lr) * 64 + lg * 8;
    bf16x8 c0 = *(const bf16x8*)(cr);
    bf16x8 c1 = *(const bf16x8*)(cr + 32);
    f32x4 acc1[4];
#pragma unroll
    for (int ot = 0; ot < 4; ++ot) {
        f32x4 a = {};
        const ushort_t* wp = wob + (size_t)(ot * 16 + lr) * 64 + lg * 8;
        a = __builtin_amdgcn_mfma_f32_16x16x32_bf16(c0, *(const bf16x8*)(wp),      a, 0, 0, 0);
        a = __builtin_amdgcn_mfma_f32_16x16x32_bf16(c1, *(const bf16x8*)(wp + 32), a, 0, 0, 0);
        acc1[ot] = a;
    }
    float bov[4], g2v[4], be2v[4];
#pragma unroll
    for (int ot = 0; ot < 4; ++ot) {
        int ch = ot * 16 + lr;
        bov[ot] = bo[ch]; g2v[ot] = g2[ch]; be2v[ot] = be2[ch];
    }
    float x1k[4][4];
#pragma unroll
    for (int r = 0; r < 4; ++r) {
        int rowL = rt * 16 + lg * 4 + r;
        float y[4]; float s = 0.f;
#pragma unroll
        for (int ot = 0; ot < 4; ++ot) {
            y[ot] = acc1[ot][r] + bov[ot] + XDF[(row0 + rowL) * 64 + ot * 16 + lr];
            s += y[ot];
        }
        s += __shfl_xor(s, 1); s += __shfl_xor(s, 2);
        s += __shfl_xor(s, 4); s += __shfl_xor(s, 8);
        float mean = s * (1.f / 64.f);
        float vs = 0.f;
#pragma unroll
        for (int ot = 0; ot < 4; ++ot) { float dd = y[ot] - mean; vs += dd * dd; }
        vs += __shfl_xor(vs, 1); vs += __shfl_xor(vs, 2);
        vs += __shfl_xor(vs, 4); vs += __shfl_xor(vs, 8);
        float rstd = rsqrtf(vs * (1.f / 64.f) + 1e-5f);
#pragma unroll
        for (int ot = 0; ot < 4; ++ot) {
            float v = (y[ot] - mean) * rstd * g2v[ot] + be2v[ot];
            x1k[r][ot] = v;
            xs[rowL][ot * 16 + lr] = brne(v);
        }
    }
    __syncthreads();
    // stage 2: FFN
    bf16x8 a0 = *(const bf16x8*)&xs[rt * 16 + lr][lg * 8];
    bf16x8 a1 = *(const bf16x8*)&xs[rt * 16 + lr][32 + lg * 8];
#pragma unroll
    for (int jt = 0; jt < 16; ++jt) {
        f32x4 acc = {};
        const ushort_t* wp = f1wb + (size_t)(jt * 16 + lr) * 64 + lg * 8;
        acc = __builtin_amdgcn_mfma_f32_16x16x32_bf16(a0, *(const bf16x8*)(wp),      acc, 0, 0, 0);
        acc = __builtin_amdgcn_mfma_f32_16x16x32_bf16(a1, *(const bf16x8*)(wp + 32), acc, 0, 0, 0);
        float bj = f1b[jt * 16 + lr];
#pragma unroll
        for (int r = 0; r < 4; ++r)
            tl[rt * 16 + lg * 4 + r][jt * 16 + lr] = brne(fmaxf(acc[r] + bj, 0.f));
    }
    __syncthreads();
    bf16x8 af[8];
#pragma unroll
    for (int kc = 0; kc < 8; ++kc)
        af[kc] = *(const bf16x8*)&tl[rt * 16 + lr][kc * 32 + lg * 8];
    f32x4 acc2[4];
#pragma unroll
    for (int ot = 0; ot < 4; ++ot) {
        f32x4 a = {};
#pragma unroll
        for (int kc = 0; kc < 8; ++kc) {
            bf16x8 bf = *(const bf16x8*)(f2wb + (size_t)(ot * 16 + lr) * 256 + kc * 32 + lg * 8);
            a = __builtin_amdgcn_mfma_f32_16x16x32_bf16(af[kc], bf, a, 0, 0, 0);
        }
        acc2[ot] = a;
    }
    float g3v[4], be3v[4], f2bv[4];
#pragma unroll
    for (int ot = 0; ot < 4; ++ot) {
        int o = ot * 16 + lr;
        g3v[ot] = g3[o]; be3v[ot] = be3[o]; f2bv[ot] = f2b[o];
    }
#pragma unroll
    for (int r = 0; r < 4; ++r) {
        int rowL = rt * 16 + lg * 4 + r;
        float y[4]; float s = 0.f;
#pragma unroll
        for (int ot = 0; ot < 4; ++ot) {
            y[ot] = acc2[ot][r] + f2bv[ot] + x1k[r][ot];
            s += y[ot];
        }
        s += __shfl_xor(s, 1); s += __shfl_xor(s, 2);
        s += __shfl_xor(s, 4); s += __shfl_xor(s, 8);
        float mean = s * (1.f / 64.f);
        float vs = 0.f;
#pragma unroll
        for (int ot = 0; ot < 4; ++ot) { float dd = y[ot] - mean; vs += dd * dd; }
        vs += __shfl_xor(vs, 1); vs += __shfl_xor(vs, 2);
        vs += __shfl_xor(vs, 4); vs += __shfl_xor(vs, 8);
        float rstd = rsqrtf(vs * (1.f / 64.f) + 1e-5f);
#pragma unroll
        for (int ot = 0; ot < 4; ++ot)
            out[(row0 + rowL) * 64 + ot * 16 + lr] = (y[ot] - mean) * rstd * g3v[ot] + be3v[ot];
    }
}

extern "C" void kernel_launch(void* const* d_in, const int* in_sizes, int n_in,
                              void* d_out, int out_size, void* d_ws, size_t ws_size,
                              hipStream_t stream) {
    const float* query = (const float*)d_in[0];
    const float* adj   = (const float*)d_in[1];
    const float* WF    = (const float*)d_in[2];
    const float* bF    = (const float*)d_in[3];
    const float* WD    = (const float*)d_in[4];
    const float* bD    = (const float*)d_in[5];
    const float* ffw1  = (const float*)d_in[6];
    const float* ffb1  = (const float*)d_in[7];
    const float* ffw2  = (const float*)d_in[8];
    const float* ffb2  = (const float*)d_in[9];
    const float* wq    = (const float*)d_in[10];
    const float* wk    = (const float*)d_in[11];
    const float* wv    = (const float*)d_in[12];
    const float* wo    = (const float*)d_in[13];
    const float* bo    = (const float*)d_in[14];
    const float* g2    = (const float*)d_in[15];
    const float* be2   = (const float*)d_in[16];
    const float* g3    = (const float*)d_in[17];
    const float* be3   = (const float*)d_in[18];
    const float* f1w   = (const float*)d_in[19];
    const float* f1b   = (const float*)d_in[20];
    const float* f2w   = (const float*)d_in[21];
    const float* f2b   = (const float*)d_in[22];
    float* out = (float*)d_out;

    // Arena (float units). Total 13,408,512 floats — round-7 proven layout.
    float* w = (float*)d_ws;
    float*    Qcat  = w;                                   // 1,048,576 -> qb/kb later
    float*    Qsum  = w + 1048576;                         // 131,072
    float*    Wc    = w + 1179648;                         // 4,096
    float*    bc    = w + 1183744;                         // 256
    ushort_t* Wfb   = (ushort_t*)(w + 1184000);            // 12,288 u16
    ushort_t* Wdb   = (ushort_t*)(w + 1190144);
    ushort_t* Wqkvb = (ushort_t*)(w + 1196288);
    ushort_t* f1wb  = (ushort_t*)(w + 1202432);            // 16,384 u16
    ushort_t* f2wb  = (ushort_t*)(w + 1210624);
    ushort_t* Rsumb = (ushort_t*)(w + 1218816);            // 131,072 u16 (65,536 f)
    ushort_t* wob   = (ushort_t*)(w + 1284352);            // 4,096 u16 (2,048 f)
    float*    Amat  = w + 1349888;                         // 4,194,304 -> vbt/ctxb later
    ushort_t* adjT  = (ushort_t*)(w + 5544192);            // 2,097,152 f -> XDF later
    ushort_t* RmT   = (ushort_t*)(w + 7641344);            // 2,097,152 f -> XDFb later
    ushort_t* QcatT = (ushort_t*)(w + 9738496);            // 524,288 f -> X2Fb later
    ushort_t* Qcatb = (ushort_t*)(w + 10262784);           // 524,288 f
    ushort_t* X1FT  = (ushort_t*)(w + 10787072);           // 524,288 f
    ushort_t* X1DT  = (ushort_t*)(w + 11311360);
    ushort_t* X1Fb  = (ushort_t*)(w + 11835648);
    ushort_t* X1Db  = (ushort_t*)(w + 12359936);
    ushort_t* X2Db  = (ushort_t*)(w + 12884224);           // ends 13,408,512
    // reuses:
    ushort_t* X2Fb  = QcatT;                               // QcatT dead after hop1
    ushort_t* qb    = (ushort_t*)Qcat;                     // Qcat dead after QcatT made
    ushort_t* kb    = (ushort_t*)(Qcat + 524288);
    ushort_t* vbt   = (ushort_t*)Amat;                     // Amat dead after RmT made
    ushort_t* ctxb  = (ushort_t*)(Amat + 1048576);         // bf16 ctx
    float*    XDF   = (float*)adjT;                        // adjT dead after hop2
    ushort_t* XDFb  = RmT;                                 // RmT dead after hop2

    k_prep<<<64, 256, 0, stream>>>(ffw1, ffb1, ffw2, ffb2, WF, WD, wq, wk, wv, wo, f1w, f2w,
                                   Wc, bc, Wfb, Wdb, Wqkvb, wob, f1wb, f2wb);
    k_qprep<<<512, 256, 0, stream>>>(query, Qcat, Qcatb, Qsum);
    k_rsum<<<512, 256, 0, stream>>>(Qsum, Wc, bc, Rsumb);
    k_amat_m<<<dim3(32, 32), 256, 0, stream>>>(Rsumb, Amat);
    k_softmax<<<2048, 256, 0, stream>>>(Amat);

    k_t32to16<<<dim3(32, 32), 256, 0, stream>>>(adj, adjT, NN, NN);
    k_t32to16<<<dim3(32, 32), 256, 0, stream>>>(Amat, RmT, NN, NN);
    k_t32to16<<<dim3(8, 32), 256, 0, stream>>>(Qcat, QcatT, NN, 512);

    k_hop<<<dim3(8, 32, 2), 256, 0, stream>>>(adjT, RmT, QcatT, QcatT,
                                              nullptr, nullptr, X1FT, X1DT, X1Fb, X1Db);
    k_hop<<<dim3(8, 32, 2), 256, 0, stream>>>(adjT, RmT, X1FT, X1DT,
                                              nullptr, nullptr, nullptr, nullptr, X2Fb, X2Db);

    k_gcnz<<<256, 256, 0, stream>>>(Qcatb, X1Fb, X2Fb, X1Db, X2Db, Wfb, Wdb, bF, bD,
                                    XDF, XDFb);
    k_qkvm<<<256, 256, 0, stream>>>(XDFb, Wqkvb, qb, kb, vbt);
    k_attn_mf<<<dim3(32, 32), 256, 0, stream>>>(qb, kb, vbt, ctxb);
    k_tail<<<256, 256, 0, stream>>>(ctxb, XDF, wob, bo, g2, be2,
                                    f1wb, f1b, f2wb, f2b, g3, be3, out);
}

// Round 9
// 289.279 us; speedup vs baseline: 4.3571x; 1.0103x over previous
//
#include <hip/hip_runtime.h>
#include <math.h>

#define NN 2048
#define BB 8
#define HD 64

typedef __attribute__((ext_vector_type(8))) short bf16x8;
typedef __attribute__((ext_vector_type(4))) float f32x4;
typedef __attribute__((ext_vector_type(16))) float f32x16;
typedef __attribute__((ext_vector_type(4))) unsigned short ushortx4;
typedef unsigned short ushort_t;

static __device__ __forceinline__ float wsum64(float v) {
#pragma unroll
    for (int off = 32; off >= 1; off >>= 1) v += __shfl_xor(v, off);
    return v;
}
static __device__ __forceinline__ float wmax64(float v) {
#pragma unroll
    for (int off = 32; off >= 1; off >>= 1) v = fmaxf(v, __shfl_xor(v, off));
    return v;
}
static __device__ __forceinline__ unsigned short brne(float x) {
    unsigned u = __float_as_uint(x);
    return (unsigned short)((u + 0x7fffu + ((u >> 16) & 1u)) >> 16);
}

#define QSCL 0.36067376022224085f   // log2e / sqrt(16)

// ---------------- weight prep ----------------
__global__ void k_prep(const float* __restrict__ ffw1, const float* __restrict__ ffb1,
                       const float* __restrict__ ffw2, const float* __restrict__ ffb2,
                       const float* __restrict__ WF, const float* __restrict__ WD,
                       const float* __restrict__ wq, const float* __restrict__ wk,
                       const float* __restrict__ wv, const float* __restrict__ wo,
                       const float* __restrict__ f1w, const float* __restrict__ f2w,
                       float* __restrict__ Wc, float* __restrict__ bc,
                       ushort_t* __restrict__ Wfb, ushort_t* __restrict__ Wdb,
                       ushort_t* __restrict__ Wqkvb, ushort_t* __restrict__ wob,
                       ushort_t* __restrict__ f1wb, ushort_t* __restrict__ f2wb) {
    int idx = blockIdx.x * 256 + threadIdx.x;   // 0..16383
    if (idx < 4096) {
        int o = idx >> 6, c = idx & 63;
        float s = 0.f;
        for (int j = 0; j < 384; ++j) s += ffw2[o * 384 + j] * ffw1[j * 64 + c];
        Wc[idx] = s;
        wob[idx] = brne(wo[idx]);
    }
    if (idx < 64) {
        float s = ffb2[idx];
        for (int j = 0; j < 384; ++j) s += ffw2[idx * 384 + j] * ffb1[j];
        bc[idx] = s;
    }
    if (idx < 12288) {
        Wfb[idx] = brne(WF[idx]);
        Wdb[idx] = brne(WD[idx]);
        int o = idx >> 6, c = idx & 63;
        float v = o < 64 ? wq[o * 64 + c] * QSCL
                         : (o < 128 ? wk[(o - 64) * 64 + c] : wv[(o - 128) * 64 + c]);
        Wqkvb[idx] = brne(v);
    }
    if (idx < 16384) {
        f1wb[idx] = brne(f1w[idx]);
        f2wb[idx] = brne(f2w[idx]);
    }
}

// ---------------- fused: Qcat/Qcatb + Rsumb = bf16(Qsum.Wc + 8*bc) ----------------
__global__ __launch_bounds__(256) void k_qprep(const float* __restrict__ q,
                                               float* __restrict__ Qcat,
                                               ushort_t* __restrict__ Qcatb,
                                               const float* __restrict__ Wc,
                                               const float* __restrict__ bc,
                                               ushort_t* __restrict__ Rsumb) {
    __shared__ float W[64][65];
    __shared__ float qsum[4][64];
    int tid = threadIdx.x;
    for (int i = tid; i < 4096; i += 256) W[i >> 6][i & 63] = Wc[i];
    int nl = tid >> 6, c = tid & 63;
    int n = blockIdx.x * 4 + nl;
    float s = 0.f;
#pragma unroll
    for (int b = 0; b < BB; ++b) {
        float v = q[((size_t)b * NN + n) * 64 + c];
        s += v;
        Qcat[(size_t)n * 512 + b * 64 + c] = v;
        Qcatb[(size_t)n * 512 + b * 64 + c] = brne(v);
    }
    qsum[nl][c] = s;
    __syncthreads();
    int h = c;
    float r = 8.f * bc[h];
    const float* qs = qsum[nl];
    for (int c2 = 0; c2 < 64; ++c2) r += qs[c2] * W[h][c2];
    Rsumb[n * 64 + h] = brne(r);
}

// ---------------- A[n][m] = Rsumb[n] . Rsumb[m]  (MFMA, K=64) ----------------
__global__ __launch_bounds__(256) void k_amat_m(const ushort_t* __restrict__ Rb,
                                                float* __restrict__ A) {
    __shared__ __align__(16) ushort_t As[4096];
    __shared__ __align__(16) ushort_t Bs[4096];
    int n0 = blockIdx.y * 64, m0 = blockIdx.x * 64;
    int t = threadIdx.x;
    int srow = t >> 2, scb = (t & 3) * 2;
    int sw = srow & 7;
    const int lane = t & 63, w = t >> 6;
    const int wm = w >> 1, wj = w & 1;
    const int lg = lane >> 4, lr = lane & 15;
    const int ma = wm * 32 + lr, mb = ma + 16;
    const int ja = wj * 32 + lr, jb = ja + 16;
    const int swa = ma & 7, swb = ja & 7;
    bf16x8 g0 = *(const bf16x8*)(Rb + (size_t)(n0 + srow) * 64 + scb * 8);
    bf16x8 g1 = *(const bf16x8*)(Rb + (size_t)(n0 + srow) * 64 + scb * 8 + 8);
    bf16x8 x0 = *(const bf16x8*)(Rb + (size_t)(m0 + srow) * 64 + scb * 8);
    bf16x8 x1 = *(const bf16x8*)(Rb + (size_t)(m0 + srow) * 64 + scb * 8 + 8);
    *(bf16x8*)&As[srow * 64 + ((scb    ) ^ sw) * 8] = g0;
    *(bf16x8*)&As[srow * 64 + ((scb + 1) ^ sw) * 8] = g1;
    *(bf16x8*)&Bs[srow * 64 + ((scb    ) ^ sw) * 8] = x0;
    *(bf16x8*)&Bs[srow * 64 + ((scb + 1) ^ sw) * 8] = x1;
    __syncthreads();
    f32x4 acc00 = {}, acc01 = {}, acc10 = {}, acc11 = {};
#pragma unroll
    for (int kk = 0; kk < 2; ++kk) {
        int c = kk * 4 + lg;
        bf16x8 a0 = *(const bf16x8*)&As[ma * 64 + (c ^ swa) * 8];
        bf16x8 a1 = *(const bf16x8*)&As[mb * 64 + (c ^ swa) * 8];
        bf16x8 b0 = *(const bf16x8*)&Bs[ja * 64 + (c ^ swb) * 8];
        bf16x8 b1 = *(const bf16x8*)&Bs[jb * 64 + (c ^ swb) * 8];
        acc00 = __builtin_amdgcn_mfma_f32_16x16x32_bf16(a0, b0, acc00, 0, 0, 0);
        acc01 = __builtin_amdgcn_mfma_f32_16x16x32_bf16(a0, b1, acc01, 0, 0, 0);
        acc10 = __builtin_amdgcn_mfma_f32_16x16x32_bf16(a1, b0, acc10, 0, 0, 0);
        acc11 = __builtin_amdgcn_mfma_f32_16x16x32_bf16(a1, b1, acc11, 0, 0, 0);
    }
    int jA = m0 + wj * 32 + lr;
    int nA = n0 + wm * 32 + lg * 4;
#pragma unroll
    for (int r = 0; r < 4; ++r) {
        A[(size_t)(nA + r) * NN + jA]           = acc00[r];
        A[(size_t)(nA + r) * NN + jA + 16]      = acc01[r];
        A[(size_t)(nA + 16 + r) * NN + jA]      = acc10[r];
        A[(size_t)(nA + 16 + r) * NN + jA + 16] = acc11[r];
    }
}

// ---------------- in-place row softmax + identity ----------------
__global__ __launch_bounds__(256) void k_softmax(float* __restrict__ A) {
    __shared__ float red[8];
    int n = blockIdx.x, tid = threadIdx.x;
    float4* row = (float4*)&A[(size_t)n * NN];
    float4 a = row[tid * 2], b = row[tid * 2 + 1];
    float v[8] = {a.x, a.y, a.z, a.w, b.x, b.y, b.z, b.w};
    float mx = v[0];
#pragma unroll
    for (int i = 1; i < 8; ++i) mx = fmaxf(mx, v[i]);
    mx = wmax64(mx);
    int wid = tid >> 6, lane = tid & 63;
    if (lane == 0) red[wid] = mx;
    __syncthreads();
    mx = fmaxf(fmaxf(red[0], red[1]), fmaxf(red[2], red[3]));
    float s = 0.f;
#pragma unroll
    for (int i = 0; i < 8; ++i) { v[i] = exp2f((v[i] - mx) * 1.44269504f); s += v[i]; }
    s = wsum64(s);
    if (lane == 0) red[4 + wid] = s;
    __syncthreads();
    s = red[4] + red[5] + red[6] + red[7];
    float inv = 1.f / s;
    int col = tid * 8;
#pragma unroll
    for (int i = 0; i < 8; ++i) v[i] = v[i] * inv + ((col + i) == n ? 1.f : 0.f);
    row[tid * 2]     = make_float4(v[0], v[1], v[2], v[3]);
    row[tid * 2 + 1] = make_float4(v[4], v[5], v[6], v[7]);
}

// ---------------- transpose + fp32->bf16 ----------------
__global__ __launch_bounds__(256) void k_t32to16(const float* __restrict__ in,
                                                 ushort_t* __restrict__ out,
                                                 int R, int C) {
    __shared__ float tile[64][65];
    int r0 = blockIdx.y * 64, c0 = blockIdx.x * 64;
    int t = threadIdx.x;
    int tr = t >> 6, tc = t & 63;
#pragma unroll
    for (int i = 0; i < 16; ++i) {
        int r = tr + i * 4;
        tile[r][tc] = in[(size_t)(r0 + r) * C + c0 + tc];
    }
    __syncthreads();
#pragma unroll
    for (int i = 0; i < 16; ++i) {
        int cc = tr + i * 4;
        out[(size_t)(c0 + cc) * R + r0 + tc] = brne(tile[tc][cc]);
    }
}

// ---------------- MFMA propagation hop (prefetched K-pipeline) ----------------
__global__ __launch_bounds__(256) void k_hop(const ushort_t* __restrict__ G0t,
                                             const ushort_t* __restrict__ G1t,
                                             const ushort_t* __restrict__ B0t,
                                             const ushort_t* __restrict__ B1t,
                                             ushort_t* __restrict__ T0, ushort_t* __restrict__ T1,
                                             ushort_t* __restrict__ R0, ushort_t* __restrict__ R1) {
    __shared__ __align__(16) ushort_t As[4096];
    __shared__ __align__(16) ushort_t Bs[4096];
    int z = blockIdx.z;
    const ushort_t* Gt = z ? G1t : G0t;
    const ushort_t* Xt = z ? B1t : B0t;
    ushort_t* T = z ? T1 : T0;
    ushort_t* R = z ? R1 : R0;
    int m0 = blockIdx.y * 64, j0 = blockIdx.x * 64;
    int t = threadIdx.x;
    int srow = t >> 2, scb = (t & 3) * 2;
    int sw = srow & 7;
    const int lane = t & 63, w = t >> 6;
    const int wm = w >> 1, wj = w & 1;
    const int lg = lane >> 4, lr = lane & 15;
    const int ma = wm * 32 + lr, mb = ma + 16;
    const int ja = wj * 32 + lr, jb = ja + 16;
    const int swa = ma & 7, swb = ja & 7;
    f32x4 acc00 = {}, acc01 = {}, acc10 = {}, acc11 = {};
    const ushort_t* Gp = Gt + (size_t)(m0 + srow) * NN + scb * 8;
    const ushort_t* Xp = Xt + (size_t)(j0 + srow) * NN + scb * 8;
    bf16x8 g0 = *(const bf16x8*)(Gp);
    bf16x8 g1 = *(const bf16x8*)(Gp + 8);
    bf16x8 x0 = *(const bf16x8*)(Xp);
    bf16x8 x1 = *(const bf16x8*)(Xp + 8);
    for (int k0 = 0; k0 < NN; k0 += 64) {
        __syncthreads();
        *(bf16x8*)&As[srow * 64 + ((scb    ) ^ sw) * 8] = g0;
        *(bf16x8*)&As[srow * 64 + ((scb + 1) ^ sw) * 8] = g1;
        *(bf16x8*)&Bs[srow * 64 + ((scb    ) ^ sw) * 8] = x0;
        *(bf16x8*)&Bs[srow * 64 + ((scb + 1) ^ sw) * 8] = x1;
        __syncthreads();
        int kn = (k0 + 64) & (NN - 1);      // wraps; last-iter loads unused
        g0 = *(const bf16x8*)(Gp + kn);
        g1 = *(const bf16x8*)(Gp + kn + 8);
        x0 = *(const bf16x8*)(Xp + kn);
        x1 = *(const bf16x8*)(Xp + kn + 8);
#pragma unroll
        for (int kk = 0; kk < 2; ++kk) {
            int c = kk * 4 + lg;
            bf16x8 a0 = *(const bf16x8*)&As[ma * 64 + (c ^ swa) * 8];
            bf16x8 a1 = *(const bf16x8*)&As[mb * 64 + (c ^ swa) * 8];
            bf16x8 b0 = *(const bf16x8*)&Bs[ja * 64 + (c ^ swb) * 8];
            bf16x8 b1 = *(const bf16x8*)&Bs[jb * 64 + (c ^ swb) * 8];
            acc00 = __builtin_amdgcn_mfma_f32_16x16x32_bf16(a0, b0, acc00, 0, 0, 0);
            acc01 = __builtin_amdgcn_mfma_f32_16x16x32_bf16(a0, b1, acc01, 0, 0, 0);
            acc10 = __builtin_amdgcn_mfma_f32_16x16x32_bf16(a1, b0, acc10, 0, 0, 0);
            acc11 = __builtin_amdgcn_mfma_f32_16x16x32_bf16(a1, b1, acc11, 0, 0, 0);
        }
    }
    int jA = j0 + wj * 32 + lr;
    int mA = m0 + wm * 32 + lg * 4;
    ushortx4 p0, p1, p2, p3;
#pragma unroll
    for (int r = 0; r < 4; ++r) {
        p0[r] = brne(acc00[r]);
        p1[r] = brne(acc01[r]);
        p2[r] = brne(acc10[r]);
        p3[r] = brne(acc11[r]);
    }
    if (T) {
        *(ushortx4*)&T[(size_t)jA * NN + mA]             = p0;
        *(ushortx4*)&T[(size_t)(jA + 16) * NN + mA]      = p1;
        *(ushortx4*)&T[(size_t)jA * NN + mA + 16]        = p2;
        *(ushortx4*)&T[(size_t)(jA + 16) * NN + mA + 16] = p3;
    }
    if (R) {
#pragma unroll
        for (int r = 0; r < 4; ++r) {
            R[(size_t)(mA + r) * 512 + jA]           = p0[r];
            R[(size_t)(mA + r) * 512 + jA + 16]      = p1[r];
            R[(size_t)(mA + 16 + r) * 512 + jA]      = p2[r];
            R[(size_t)(mA + 16 + r) * 512 + jA + 16] = p3[r];
        }
    }
}

// ---------------- fused GCN 1x1 convs (F,D) + gate -> XDF fp32 + bf16 ----------------
__global__ __launch_bounds__(256) void k_gcnz(const ushort_t* __restrict__ Qcatb,
                                              const ushort_t* __restrict__ X1Fb,
                                              const ushort_t* __restrict__ X2Fb,
                                              const ushort_t* __restrict__ X1Db,
                                              const ushort_t* __restrict__ X2Db,
                                              const ushort_t* __restrict__ Wfb,
                                              const ushort_t* __restrict__ Wdb,
                                              const float* __restrict__ bF,
                                              const float* __restrict__ bD,
                                              float* __restrict__ XDF,
                                              ushort_t* __restrict__ XDFb) {
    __shared__ ushort_t Wl[2][64][200];
    int tid = threadIdx.x;
    for (int i = tid; i < 12288; i += 256) {
        int o = i / 192, k = i % 192;
        Wl[0][o][k] = Wfb[i];
        Wl[1][o][k] = Wdb[i];
    }
    int blk = blockIdx.x;
    int b = blk >> 5, n0 = (blk & 31) * 64;
    int lane = tid & 63, rt = tid >> 6;
    int lr = lane & 15, lg = lane >> 4;
    int nA = n0 + rt * 16 + lr;
    const size_t rb = (size_t)nA * 512 + b * 64 + lg * 8;
    bf16x8 aQ0  = *(const bf16x8*)(Qcatb + rb);
    bf16x8 aQ1  = *(const bf16x8*)(Qcatb + rb + 32);
    bf16x8 a1F0 = *(const bf16x8*)(X1Fb + rb);
    bf16x8 a1F1 = *(const bf16x8*)(X1Fb + rb + 32);
    bf16x8 a2F0 = *(const bf16x8*)(X2Fb + rb);
    bf16x8 a2F1 = *(const bf16x8*)(X2Fb + rb + 32);
    bf16x8 a1D0 = *(const bf16x8*)(X1Db + rb);
    bf16x8 a1D1 = *(const bf16x8*)(X1Db + rb + 32);
    bf16x8 a2D0 = *(const bf16x8*)(X2Db + rb);
    bf16x8 a2D1 = *(const bf16x8*)(X2Db + rb + 32);
    float bFv[4], bDv[4];
#pragma unroll
    for (int ot = 0; ot < 4; ++ot) { bFv[ot] = bF[ot * 16 + lr]; bDv[ot] = bD[ot * 16 + lr]; }
    __syncthreads();
    f32x4 accF[4], accD[4];
#pragma unroll
    for (int ot = 0; ot < 4; ++ot) {
        int o = ot * 16 + lr;
        const ushort_t* wf = &Wl[0][o][lg * 8];
        const ushort_t* wd = &Wl[1][o][lg * 8];
        f32x4 aF = {}, aD = {};
        aF = __builtin_amdgcn_mfma_f32_16x16x32_bf16(aQ0,  *(const bf16x8*)(wf),       aF, 0, 0, 0);
        aF = __builtin_amdgcn_mfma_f32_16x16x32_bf16(aQ1,  *(const bf16x8*)(wf + 32),  aF, 0, 0, 0);
        aF = __builtin_amdgcn_mfma_f32_16x16x32_bf16(a1F0, *(const bf16x8*)(wf + 64),  aF, 0, 0, 0);
        aF = __builtin_amdgcn_mfma_f32_16x16x32_bf16(a1F1, *(const bf16x8*)(wf + 96),  aF, 0, 0, 0);
        aF = __builtin_amdgcn_mfma_f32_16x16x32_bf16(a2F0, *(const bf16x8*)(wf + 128), aF, 0, 0, 0);
        aF = __builtin_amdgcn_mfma_f32_16x16x32_bf16(a2F1, *(const bf16x8*)(wf + 160), aF, 0, 0, 0);
        aD = __builtin_amdgcn_mfma_f32_16x16x32_bf16(aQ0,  *(const bf16x8*)(wd),       aD, 0, 0, 0);
        aD = __builtin_amdgcn_mfma_f32_16x16x32_bf16(aQ1,  *(const bf16x8*)(wd + 32),  aD, 0, 0, 0);
        aD = __builtin_amdgcn_mfma_f32_16x16x32_bf16(a1D0, *(const bf16x8*)(wd + 64),  aD, 0, 0, 0);
        aD = __builtin_amdgcn_mfma_f32_16x16x32_bf16(a1D1, *(const bf16x8*)(wd + 96),  aD, 0, 0, 0);
        aD = __builtin_amdgcn_mfma_f32_16x16x32_bf16(a2D0, *(const bf16x8*)(wd + 128), aD, 0, 0, 0);
        aD = __builtin_amdgcn_mfma_f32_16x16x32_bf16(a2D1, *(const bf16x8*)(wd + 160), aD, 0, 0, 0);
        accF[ot] = aF; accD[ot] = aD;
    }
    const float L2E = 1.44269504f;
#pragma unroll
    for (int ot = 0; ot < 4; ++ot) {
#pragma unroll
        for (int r = 0; r < 4; ++r) {
            float f = accF[ot][r] + bFv[ot];
            float d = accD[ot][r] + bDv[ot];
            float sg = 1.f / (1.f + exp2f(-f * L2E));
            float th = 2.f / (1.f + exp2f(-2.f * d * L2E)) - 1.f;
            float xv = th * sg;
            int nD = n0 + rt * 16 + lg * 4 + r;
            size_t oa = ((size_t)b * NN + nD) * 64 + ot * 16 + lr;
            XDF[oa] = xv;
            XDFb[oa] = brne(xv);
        }
    }
}

// ---------------- MFMA qkv ----------------
__global__ __launch_bounds__(256) void k_qkvm(const ushort_t* __restrict__ XDFb,
                                              const ushort_t* __restrict__ Wqkvb,
                                              ushort_t* __restrict__ qb,
                                              ushort_t* __restrict__ kb,
                                              ushort_t* __restrict__ vbt) {
    __shared__ ushort_t Wl[192][72];
    __shared__ float vt[4][64][17];
    int tid = threadIdx.x;
    for (int i = tid; i < 12288; i += 256) Wl[i >> 6][i & 63] = Wqkvb[i];
    int blk = blockIdx.x;
    size_t row0 = (size_t)blk * 64;
    int b = (int)(row0 >> 11), nbase = (int)(row0 & 2047);
    int lane = tid & 63, rt = tid >> 6;
    int lr = lane & 15, lg = lane >> 4;
    int nl = rt * 16 + lr;
    const ushort_t* xr = XDFb + (row0 + nl) * 64 + lg * 8;
    bf16x8 a0 = *(const bf16x8*)(xr);
    bf16x8 a1 = *(const bf16x8*)(xr + 32);
    __syncthreads();
#pragma unroll
    for (int ot = 0; ot < 12; ++ot) {
        f32x4 acc = {};
        const ushort_t* wp = &Wl[ot * 16 + lr][lg * 8];
        acc = __builtin_amdgcn_mfma_f32_16x16x32_bf16(a0, *(const bf16x8*)(wp),      acc, 0, 0, 0);
        acc = __builtin_amdgcn_mfma_f32_16x16x32_bf16(a1, *(const bf16x8*)(wp + 32), acc, 0, 0, 0);
        int kind = ot >> 2, h = ot & 3;
        int nD = rt * 16 + lg * 4;
        if (kind < 2) {
            ushort_t* dst = (kind == 0 ? qb : kb) + (((size_t)(b * 4 + h) * NN + nbase + nD) * 16 + lr);
#pragma unroll
            for (int r = 0; r < 4; ++r) dst[r * 16] = brne(acc[r]);
        } else {
#pragma unroll
            for (int r = 0; r < 4; ++r) vt[h][nD + r][lr] = acc[r];
        }
    }
    __syncthreads();
    if (tid < 128) {
        int h = tid >> 5, d = (tid >> 1) & 15, half = tid & 1;
        ushort_t* dst = vbt + ((size_t)(b * 4 + h) * 32 + d) * NN + nbase + half * 32;
#pragma unroll
        for (int g = 0; g < 4; ++g) {
            uint4 u;
            int i0 = half * 32 + g * 8;
            u.x = (unsigned)brne(vt[h][i0 + 0][d]) | ((unsigned)brne(vt[h][i0 + 1][d]) << 16);
            u.y = (unsigned)brne(vt[h][i0 + 2][d]) | ((unsigned)brne(vt[h][i0 + 3][d]) << 16);
            u.z = (unsigned)brne(vt[h][i0 + 4][d]) | ((unsigned)brne(vt[h][i0 + 5][d]) << 16);
            u.w = (unsigned)brne(vt[h][i0 + 6][d]) | ((unsigned)brne(vt[h][i0 + 7][d]) << 16);
            ((uint4*)dst)[g] = u;
        }
    } else {
        int t2 = tid - 128;
        int h = t2 >> 5, dz = 16 + ((t2 >> 1) & 15), half = t2 & 1;
        unsigned pv = (dz == 16) ? 0x3F803F80u : 0u;   // row16 = ones (ssum trick)
        uint4 z; z.x = pv; z.y = pv; z.z = pv; z.w = pv;
        ushort_t* dst = vbt + ((size_t)(b * 4 + h) * 32 + dz) * NN + nbase + half * 32;
#pragma unroll
        for (int g = 0; g < 4; ++g) ((uint4*)dst)[g] = z;
    }
}

// ---------------- MFMA flash attention, split-K x2 -> bf16 partials + fp32 ssum ----
__global__ __launch_bounds__(256) void k_attn_mf(const ushort_t* __restrict__ qb,
                                                 const ushort_t* __restrict__ kb,
                                                 const ushort_t* __restrict__ vbt,
                                                 ushort_t* __restrict__ P0,
                                                 ushort_t* __restrict__ P1,
                                                 float* __restrict__ ssumA) {
    __shared__ float cpart[4][32][33];
    int bh = blockIdx.y, n0 = blockIdx.x * 64, sp = blockIdx.z;
    int tid = threadIdx.x, w = tid >> 6, l = tid & 63;
    int lc = l & 31, hi = l >> 5;
    int qsub = w & 1, mhalf = w >> 1;
    const ushort_t* Q  = qb + ((size_t)bh * NN + n0 + qsub * 32) * 16;
    const ushort_t* K  = kb + (size_t)bh * NN * 16;
    const ushort_t* VT = vbt + ((size_t)bh * 32 + lc) * NN;
    bf16x8 qf = *(const bf16x8*)(Q + lc * 16 + hi * 8);
    f32x16 zero = {};
    f32x16 acc = {};
    int kbeg = sp * (NN / 2), kend = kbeg + NN / 2;
    for (int m0 = kbeg + mhalf * 32; m0 < kend; m0 += 64) {
        bf16x8 kf = *(const bf16x8*)(K + (size_t)(m0 + lc) * 16 + hi * 8);
        bf16x8 v0 = *(const bf16x8*)(VT + m0 + hi * 8);
        bf16x8 v1 = *(const bf16x8*)(VT + m0 + 16 + hi * 8);
        f32x16 st = __builtin_amdgcn_mfma_f32_32x32x16_bf16(kf, qf, zero, 0, 0, 0);
        float p[16];
#pragma unroll
        for (int r = 0; r < 16; ++r) p[r] = exp2f(st[r]);
        unsigned d[8];
#pragma unroll
        for (int j = 0; j < 8; ++j)
            asm("v_cvt_pk_bf16_f32 %0, %1, %2" : "=v"(d[j]) : "v"(p[2 * j]), "v"(p[2 * j + 1]));
        unsigned z0 = hi ? d[0] : d[2];
        unsigned z1 = hi ? d[1] : d[3];
        unsigned z2 = hi ? d[4] : d[6];
        unsigned z3 = hi ? d[5] : d[7];
        unsigned r0 = (unsigned)__shfl_xor((int)z0, 32);
        unsigned r1 = (unsigned)__shfl_xor((int)z1, 32);
        unsigned r2 = (unsigned)__shfl_xor((int)z2, 32);
        unsigned r3 = (unsigned)__shfl_xor((int)z3, 32);
        union { bf16x8 v; unsigned u[4]; } fa, fb;
        if (hi == 0) {
            fa.u[0] = d[0]; fa.u[1] = d[1]; fa.u[2] = r0; fa.u[3] = r1;
            fb.u[0] = d[4]; fb.u[1] = d[5]; fb.u[2] = r2; fb.u[3] = r3;
        } else {
            fa.u[0] = r0; fa.u[1] = r1; fa.u[2] = d[2]; fa.u[3] = d[3];
            fb.u[0] = r2; fb.u[1] = r3; fb.u[2] = d[6]; fb.u[3] = d[7];
        }
        acc = __builtin_amdgcn_mfma_f32_32x32x16_bf16(fa.v, v0, acc, 0, 0, 0);
        acc = __builtin_amdgcn_mfma_f32_32x32x16_bf16(fb.v, v1, acc, 0, 0, 0);
    }
#pragma unroll
    for (int r = 0; r < 16; ++r)
        cpart[w][(r & 3) + 8 * (r >> 2) + 4 * hi][lc] = acc[r];
    __syncthreads();
    int q = tid >> 2, d4 = (tid & 3) * 4;
    int qs = q >> 5, q32 = q & 31;
    float sst = cpart[qs][q32][16] + cpart[2 + qs][q32][16];
    ushortx4 ob;
    ob[0] = brne(cpart[qs][q32][d4]     + cpart[2 + qs][q32][d4]);
    ob[1] = brne(cpart[qs][q32][d4 + 1] + cpart[2 + qs][q32][d4 + 1]);
    ob[2] = brne(cpart[qs][q32][d4 + 2] + cpart[2 + qs][q32][d4 + 2]);
    ob[3] = brne(cpart[qs][q32][d4 + 3] + cpart[2 + qs][q32][d4 + 3]);
    int b = bh >> 2, h = bh & 3;
    ushort_t* P = sp ? P1 : P0;
    *(ushortx4*)&P[((size_t)b * NN + n0 + q) * 64 + h * 16 + d4] = ob;
    if ((tid & 3) == 0)
        ssumA[(size_t)sp * 32 * NN + (size_t)bh * NN + n0 + q] = sst;
}

// ---------------- fused tail: combine attn splits; x1 = LN(ctx@wo^T+bo+XDF); FFN; LN ----
__global__ __launch_bounds__(256) void k_tail(const ushort_t* __restrict__ P0,
                                              const ushort_t* __restrict__ P1,
                                              const float* __restrict__ ssumA,
                                              const float* __restrict__ XDF,
                                              const ushort_t* __restrict__ wob,
                                              const float* __restrict__ bo,
                                              const float* __restrict__ g2,
                                              const float* __restrict__ be2,
                                              const ushort_t* __restrict__ f1wb,
                                              const float* __restrict__ f1b,
                                              const ushort_t* __restrict__ f2wb,
                                              const float* __restrict__ f2b,
                                              const float* __restrict__ g3,
                                              const float* __restrict__ be3,
                                              float* __restrict__ out) {
    __shared__ ushort_t xs[64][72];
    __shared__ ushort_t tl[64][264];
    int tid = threadIdx.x;
    size_t row0 = (size_t)blockIdx.x * 64;
    int lane = tid & 63, rt = tid >> 6;
    int lr = lane & 15, lg = lane >> 4;
    // stage 0: combine attention splits -> ctx bf16 in xs
    {
        int r2 = tid >> 2, hh = tid & 3;
        size_t rowG = row0 + r2;
        int bb = (int)(rowG >> 11), nn = (int)(rowG & 2047);
        size_t si = (size_t)(bb * 4 + hh) * NN + nn;
        float inv = 1.f / (ssumA[si] + ssumA[(size_t)32 * NN + si]);
        const ushort_t* p0 = P0 + rowG * 64 + hh * 16;
        const ushort_t* p1 = P1 + rowG * 64 + hh * 16;
#pragma unroll
        for (int g = 0; g < 4; ++g) {
            ushortx4 u0 = *(const ushortx4*)(p0 + g * 4);
            ushortx4 u1 = *(const ushortx4*)(p1 + g * 4);
#pragma unroll
            for (int j = 0; j < 4; ++j) {
                float v0 = __uint_as_float((unsigned)u0[j] << 16);
                float v1 = __uint_as_float((unsigned)u1[j] << 16);
                xs[r2][hh * 16 + g * 4 + j] = brne((v0 + v1) * inv);
            }
        }
    }
    __syncthreads();
    // stage 1: att_out + residual + LN
    bf16x8 c0 = *(const bf16x8*)&xs[rt * 16 + lr][lg * 8];
    bf16x8 c1 = *(const bf16x8*)&xs[rt * 16 + lr][32 + lg * 8];
    __syncthreads();   // all ctx reads done before xs is rewritten below
    f32x4 acc1[4];
#pragma unroll
    for (int ot = 0; ot < 4; ++ot) {
        f32x4 a = {};
        const ushort_t* wp = wob + (size_t)(ot * 16 + lr) * 64 + lg * 8;
        a = __builtin_amdgcn_mfma_f32_16x16x32_bf16(c0, *(const bf16x8*)(wp),      a, 0, 0, 0);
        a = __builtin_amdgcn_mfma_f32_16x16x32_bf16(c1, *(const bf16x8*)(wp + 32), a, 0, 0, 0);
        acc1[ot] = a;
    }
    float bov[4], g2v[4], be2v[4];
#pragma unroll
    for (int ot = 0; ot < 4; ++ot) {
        int ch = ot * 16 + lr;
        bov[ot] = bo[ch]; g2v[ot] = g2[ch]; be2v[ot] = be2[ch];
    }
    float x1k[4][4];
#pragma unroll
    for (int r = 0; r < 4; ++r) {
        int rowL = rt * 16 + lg * 4 + r;
        float y[4]; float s = 0.f;
#pragma unroll
        for (int ot = 0; ot < 4; ++ot) {
            y[ot] = acc1[ot][r] + bov[ot] + XDF[(row0 + rowL) * 64 + ot * 16 + lr];
            s += y[ot];
        }
        s += __shfl_xor(s, 1); s += __shfl_xor(s, 2);
        s += __shfl_xor(s, 4); s += __shfl_xor(s, 8);
        float mean = s * (1.f / 64.f);
        float vs = 0.f;
#pragma unroll
        for (int ot = 0; ot < 4; ++ot) { float dd = y[ot] - mean; vs += dd * dd; }
        vs += __shfl_xor(vs, 1); vs += __shfl_xor(vs, 2);
        vs += __shfl_xor(vs, 4); vs += __shfl_xor(vs, 8);
        float rstd = rsqrtf(vs * (1.f / 64.f) + 1e-5f);
#pragma unroll
        for (int ot = 0; ot < 4; ++ot) {
            float v = (y[ot] - mean) * rstd * g2v[ot] + be2v[ot];
            x1k[r][ot] = v;
            xs[rowL][ot * 16 + lr] = brne(v);
        }
    }
    __syncthreads();
    // stage 2: FFN
    bf16x8 a0 = *(const bf16x8*)&xs[rt * 16 + lr][lg * 8];
    bf16x8 a1 = *(const bf16x8*)&xs[rt * 16 + lr][32 + lg * 8];
#pragma unroll
    for (int jt = 0; jt < 16; ++jt) {
        f32x4 acc = {};
        const ushort_t* wp = f1wb + (size_t)(jt * 16 + lr) * 64 + lg * 8;
        acc = __builtin_amdgcn_mfma_f32_16x16x32_bf16(a0, *(const bf16x8*)(wp),      acc, 0, 0, 0);
        acc = __builtin_amdgcn_mfma_f32_16x16x32_bf16(a1, *(const bf16x8*)(wp + 32), acc, 0, 0, 0);
        float bj = f1b[jt * 16 + lr];
#pragma unroll
        for (int r = 0; r < 4; ++r)
            tl[rt * 16 + lg * 4 + r][jt * 16 + lr] = brne(fmaxf(acc[r] + bj, 0.f));
    }
    __syncthreads();
    bf16x8 af[8];
#pragma unroll
    for (int kc = 0; kc < 8; ++kc)
        af[kc] = *(const bf16x8*)&tl[rt * 16 + lr][kc * 32 + lg * 8];
    f32x4 acc2[4];
#pragma unroll
    for (int ot = 0; ot < 4; ++ot) {
        f32x4 a = {};
#pragma unroll
        for (int kc = 0; kc < 8; ++kc) {
            bf16x8 bf = *(const bf16x8*)(f2wb + (size_t)(ot * 16 + lr) * 256 + kc * 32 + lg * 8);
            a = __builtin_amdgcn_mfma_f32_16x16x32_bf16(af[kc], bf, a, 0, 0, 0);
        }
        acc2[ot] = a;
    }
    float g3v[4], be3v[4], f2bv[4];
#pragma unroll
    for (int ot = 0; ot < 4; ++ot) {
        int o = ot * 16 + lr;
        g3v[ot] = g3[o]; be3v[ot] = be3[o]; f2bv[ot] = f2b[o];
    }
#pragma unroll
    for (int r = 0; r < 4; ++r) {
        int rowL = rt * 16 + lg * 4 + r;
        float y[4]; float s = 0.f;
#pragma unroll
        for (int ot = 0; ot < 4; ++ot) {
            y[ot] = acc2[ot][r] + f2bv[ot] + x1k[r][ot];
            s += y[ot];
        }
        s += __shfl_xor(s, 1); s += __shfl_xor(s, 2);
        s += __shfl_xor(s, 4); s += __shfl_xor(s, 8);
        float mean = s * (1.f / 64.f);
        float vs = 0.f;
#pragma unroll
        for (int ot = 0; ot < 4; ++ot) { float dd = y[ot] - mean; vs += dd * dd; }
        vs += __shfl_xor(vs, 1); vs += __shfl_xor(vs, 2);
        vs += __shfl_xor(vs, 4); vs += __shfl_xor(vs, 8);
        float rstd = rsqrtf(vs * (1.f / 64.f) + 1e-5f);
#pragma unroll
        for (int ot = 0; ot < 4; ++ot)
            out[(row0 + rowL) * 64 + ot * 16 + lr] = (y[ot] - mean) * rstd * g3v[ot] + be3v[ot];
    }
}

extern "C" void kernel_launch(void* const* d_in, const int* in_sizes, int n_in,
                              void* d_out, int out_size, void* d_ws, size_t ws_size,
                              hipStream_t stream) {
    const float* query = (const float*)d_in[0];
    const float* adj   = (const float*)d_in[1];
    const float* WF    = (const float*)d_in[2];
    const float* bF    = (const float*)d_in[3];
    const float* WD    = (const float*)d_in[4];
    const float* bD    = (const float*)d_in[5];
    const float* ffw1  = (const float*)d_in[6];
    const float* ffb1  = (const float*)d_in[7];
    const float* ffw2  = (const float*)d_in[8];
    const float* ffb2  = (const float*)d_in[9];
    const float* wq    = (const float*)d_in[10];
    const float* wk    = (const float*)d_in[11];
    const float* wv    = (const float*)d_in[12];
    const float* wo    = (const float*)d_in[13];
    const float* bo    = (const float*)d_in[14];
    const float* g2    = (const float*)d_in[15];
    const float* be2   = (const float*)d_in[16];
    const float* g3    = (const float*)d_in[17];
    const float* be3   = (const float*)d_in[18];
    const float* f1w   = (const float*)d_in[19];
    const float* f1b   = (const float*)d_in[20];
    const float* f2w   = (const float*)d_in[21];
    const float* f2b   = (const float*)d_in[22];
    float* out = (float*)d_out;

    // Arena (float units). Total 13,408,512 floats — round-7/8 proven layout.
    float* w = (float*)d_ws;
    float*    Qcat  = w;                                   // 1,048,576 -> qb/kb later
    // w+1048576 .. +1179648: former Qsum region (unused now)
    float*    Wc    = w + 1179648;                         // 4,096
    float*    bc    = w + 1183744;                         // 256
    ushort_t* Wfb   = (ushort_t*)(w + 1184000);            // 12,288 u16
    ushort_t* Wdb   = (ushort_t*)(w + 1190144);
    ushort_t* Wqkvb = (ushort_t*)(w + 1196288);
    ushort_t* f1wb  = (ushort_t*)(w + 1202432);            // 16,384 u16
    ushort_t* f2wb  = (ushort_t*)(w + 1210624);
    ushort_t* Rsumb = (ushort_t*)(w + 1218816);            // 131,072 u16
    ushort_t* wob   = (ushort_t*)(w + 1284352);            // 4,096 u16
    float*    Amat  = w + 1349888;                         // 4,194,304 -> vbt/P0/P1/ssum later
    ushort_t* adjT  = (ushort_t*)(w + 5544192);            // 2,097,152 f -> XDF later
    ushort_t* RmT   = (ushort_t*)(w + 7641344);            // 2,097,152 f -> XDFb later
    ushort_t* QcatT = (ushort_t*)(w + 9738496);            // 524,288 f -> X2Fb later
    ushort_t* Qcatb = (ushort_t*)(w + 10262784);           // 524,288 f
    ushort_t* X1FT  = (ushort_t*)(w + 10787072);           // 524,288 f
    ushort_t* X1DT  = (ushort_t*)(w + 11311360);
    ushort_t* X1Fb  = (ushort_t*)(w + 11835648);
    ushort_t* X1Db  = (ushort_t*)(w + 12359936);
    ushort_t* X2Db  = (ushort_t*)(w + 12884224);           // ends 13,408,512
    // reuses:
    ushort_t* X2Fb  = QcatT;                               // QcatT dead after hop1
    ushort_t* qb    = (ushort_t*)Qcat;                     // Qcat fp32 dead after QcatT made
    ushort_t* kb    = (ushort_t*)(Qcat + 524288);
    ushort_t* vbt   = (ushort_t*)Amat;                     // Amat dead after RmT made
    ushort_t* P0    = (ushort_t*)(Amat + 1048576);         // [8][2048][64] bf16 partial
    ushort_t* P1    = (ushort_t*)(Amat + 1572864);
    float*    ssumA = Amat + 2097152;                      // [2][32][2048] fp32
    float*    XDF   = (float*)adjT;                        // adjT dead after hop2
    ushort_t* XDFb  = RmT;                                 // RmT dead after hop2

    k_prep<<<64, 256, 0, stream>>>(ffw1, ffb1, ffw2, ffb2, WF, WD, wq, wk, wv, wo, f1w, f2w,
                                   Wc, bc, Wfb, Wdb, Wqkvb, wob, f1wb, f2wb);
    k_qprep<<<512, 256, 0, stream>>>(query, Qcat, Qcatb, Wc, bc, Rsumb);
    k_amat_m<<<dim3(32, 32), 256, 0, stream>>>(Rsumb, Amat);
    k_softmax<<<2048, 256, 0, stream>>>(Amat);

    k_t32to16<<<dim3(32, 32), 256, 0, stream>>>(adj, adjT, NN, NN);
    k_t32to16<<<dim3(32, 32), 256, 0, stream>>>(Amat, RmT, NN, NN);
    k_t32to16<<<dim3(8, 32), 256, 0, stream>>>(Qcat, QcatT, NN, 512);

    k_hop<<<dim3(8, 32, 2), 256, 0, stream>>>(adjT, RmT, QcatT, QcatT,
                                              X1FT, X1DT, X1Fb, X1Db);
    k_hop<<<dim3(8, 32, 2), 256, 0, stream>>>(adjT, RmT, X1FT, X1DT,
                                              nullptr, nullptr, X2Fb, X2Db);

    k_gcnz<<<256, 256, 0, stream>>>(Qcatb, X1Fb, X2Fb, X1Db, X2Db, Wfb, Wdb, bF, bD,
                                    XDF, XDFb);
    k_qkvm<<<256, 256, 0, stream>>>(XDFb, Wqkvb, qb, kb, vbt);
    k_attn_mf<<<dim3(32, 32, 2), 256, 0, stream>>>(qb, kb, vbt, P0, P1, ssumA);
    k_tail<<<256, 256, 0, stream>>>(P0, P1, ssumA, XDF, wob, bo, g2, be2,
                                    f1wb, f1b, f2wb, f2b, g3, be3, out);
}